// Round 1
// baseline (912.571 us; speedup 1.0000x reference)
//
#include <hip/hip_runtime.h>

#define AS1 __attribute__((address_space(1)))
#define AS3 __attribute__((address_space(3)))

typedef float    f32x4  __attribute__((ext_vector_type(4)));
typedef __bf16   bf16x8 __attribute__((ext_vector_type(8)));
typedef __bf16   bf16x4 __attribute__((ext_vector_type(4)));
typedef unsigned int u32x4 __attribute__((ext_vector_type(4)));

static constexpr int SEQ = 4096, NBATCH = 2, DMODEL = 1024, NHEADS = 16, HDIM = 64;
static constexpr int LHEADS = 8, LDIM = 512, NLAT = 64, WIN = 256;
static constexpr int BSROWS = NBATCH * SEQ; // 8192

// ---------------- f32 -> bf16 convert (vectorized) ----------------
__global__ __launch_bounds__(256) void cvt_f32_to_bf16(const float* __restrict__ in,
                                                       __bf16* __restrict__ out, int n4) {
    int i = blockIdx.x * 256 + threadIdx.x;
    if (i >= n4) return;
    f32x4 v = ((const f32x4*)in)[i];
    bf16x4 r;
    r[0] = (__bf16)v[0]; r[1] = (__bf16)v[1]; r[2] = (__bf16)v[2]; r[3] = (__bf16)v[3];
    ((bf16x4*)out)[i] = r;
}

// ---------------- transpose + convert: out[n*K+k] = (bf16)in[k*N+n] ----------------
__global__ void transpose_cvt(const float* __restrict__ in, __bf16* __restrict__ out,
                              int K, int N) {
    __shared__ float t[32][33];
    int k0 = blockIdx.x * 32, n0 = blockIdx.y * 32;
    int tx = threadIdx.x, ty = threadIdx.y; // (32, 8)
    #pragma unroll
    for (int i = ty; i < 32; i += 8) t[i][tx] = in[(size_t)(k0 + i) * N + n0 + tx];
    __syncthreads();
    #pragma unroll
    for (int i = ty; i < 32; i += 8) out[(size_t)(n0 + i) * K + k0 + tx] = (__bf16)t[tx][i];
}

// ---------------- pool x over chunks of 64 rows -> bf16 [128][1024] ----------------
__global__ __launch_bounds__(256) void pool_x_kernel(const float* __restrict__ x,
                                                     __bf16* __restrict__ xpool) {
    int c  = blockIdx.x * 256 + threadIdx.x; // 0..1023
    int bn = blockIdx.y;                     // b*64+n, rows bn*64..bn*64+63 of x
    const float* p = x + (size_t)bn * 64 * 1024 + c;
    float s = 0.f;
    #pragma unroll 8
    for (int j = 0; j < 64; ++j) s += p[(size_t)j * 1024];
    xpool[(size_t)bn * 1024 + c] = (__bf16)(s * 0.015625f);
}

// ---------------- bf16 MFMA GEMM: C[M,N] = A[M,K] @ Bt[N,K]^T ----------------
// 128x128 tile, BK=64, 4 waves (2x2 of 64x64), mfma_f32_16x16x32_bf16.
// EPI: C = local_scaled + gr[row, col>>6] * C   (N must be 1024)
template <bool EPI, bool OUTBF>
__global__ __launch_bounds__(256) void gemm_bf16(const __bf16* __restrict__ A,
                                                 const __bf16* __restrict__ Bt,
                                                 int M, int N, int K,
                                                 __bf16* __restrict__ outb,
                                                 float* __restrict__ outf,
                                                 const __bf16* __restrict__ lcl,
                                                 const float* __restrict__ grb) {
    __shared__ alignas(16) __bf16 sA[128 * 64];
    __shared__ alignas(16) __bf16 sB[128 * 64];
    int t = threadIdx.x, w = t >> 6, l = t & 63;
    int m0 = blockIdx.x * 128, n0 = blockIdx.y * 128;
    int wr = w >> 1, wc = w & 1;
    int lr = l & 15, lk = (l >> 4) * 8;

    f32x4 zero = {0.f, 0.f, 0.f, 0.f};
    f32x4 acc[4][4];
    #pragma unroll
    for (int a = 0; a < 4; ++a)
        #pragma unroll
        for (int b2 = 0; b2 < 4; ++b2) acc[a][b2] = zero;

    for (int kt = 0; kt < K; kt += 64) {
        #pragma unroll
        for (int c = 0; c < 4; ++c) {
            int lin  = w * 64 + c * 256;   // wave-uniform 16B-chunk base
            int linl = lin + l;
            int row = linl >> 3, c8 = (linl & 7) * 8;
            __builtin_amdgcn_global_load_lds(
                (const AS1 void*)(A + (size_t)(m0 + row) * K + kt + c8),
                (AS3 void*)((char*)sA + (size_t)lin * 16), 16, 0, 0);
            __builtin_amdgcn_global_load_lds(
                (const AS1 void*)(Bt + (size_t)(n0 + row) * K + kt + c8),
                (AS3 void*)((char*)sB + (size_t)lin * 16), 16, 0, 0);
        }
        __syncthreads();
        #pragma unroll
        for (int ks = 0; ks < 2; ++ks) {
            bf16x8 av[4], bv[4];
            #pragma unroll
            for (int mi = 0; mi < 4; ++mi)
                av[mi] = *(const bf16x8*)(sA + (wr * 64 + mi * 16 + lr) * 64 + ks * 32 + lk);
            #pragma unroll
            for (int ni = 0; ni < 4; ++ni)
                bv[ni] = *(const bf16x8*)(sB + (wc * 64 + ni * 16 + lr) * 64 + ks * 32 + lk);
            #pragma unroll
            for (int mi = 0; mi < 4; ++mi)
                #pragma unroll
                for (int ni = 0; ni < 4; ++ni)
                    acc[mi][ni] = __builtin_amdgcn_mfma_f32_16x16x32_bf16(
                        av[mi], bv[ni], acc[mi][ni], 0, 0, 0);
        }
        __syncthreads();
    }

    int cr = (l >> 4) * 4, cc = l & 15;
    #pragma unroll
    for (int mi = 0; mi < 4; ++mi) {
        #pragma unroll
        for (int ni = 0; ni < 4; ++ni) {
            int col = n0 + wc * 64 + ni * 16 + cc;
            #pragma unroll
            for (int r = 0; r < 4; ++r) {
                int row = m0 + wr * 64 + mi * 16 + cr + r;
                float v = acc[mi][ni][r];
                if constexpr (EPI) {
                    v = (float)lcl[(size_t)row * 1024 + col] +
                        grb[(size_t)row * 16 + (col >> 6)] * v;
                }
                if constexpr (OUTBF) outb[(size_t)row * N + col] = (__bf16)v;
                else                 outf[(size_t)row * N + col] = v;
            }
        }
    }
}

// ---------------- local sliding-window attention + gates ----------------
// grid (16 blocks, 16 heads, 2 batch), 256 threads. Query i=tid, wave w owns
// queries [64w, 64w+63]; keys iterated uniformly per wave -> LDS broadcast.
__global__ __launch_bounds__(256) void local_attn(const __bf16* __restrict__ Qb,
                                                  const __bf16* __restrict__ Kb,
                                                  const __bf16* __restrict__ Vb,
                                                  const float* __restrict__ glw,
                                                  const float* __restrict__ grw,
                                                  __bf16* __restrict__ outl,
                                                  float* __restrict__ grbuf) {
    int blk = blockIdx.x, h = blockIdx.y, b = blockIdx.z;
    int t = threadIdx.x, w = t >> 6;
    __shared__ alignas(16) __bf16 sK[512 * 64];
    __shared__ alignas(16) __bf16 sV[512 * 64];
    __shared__ float sgl[64], sgr[64];
    if (t < 64) sgl[t] = glw[h * 64 + t];
    else if (t < 128) sgr[t - 64] = grw[h * 64 + t - 64];

    long g0 = (long)b * SEQ + (long)(blk - 1) * WIN; // global row of window key jw=0
    int rlo = (blk == 0) ? 256 : 0;
    for (int rep = 0; rep < 16; ++rep) {
        int ci = rep * 256 + t;       // 16B-chunk index, 4096 per buffer
        int row = ci >> 3, c8 = (ci & 7) * 8;
        if (row >= rlo) {
            size_t g = (size_t)(g0 + row) * DMODEL + h * 64 + c8;
            *(u32x4*)(sK + row * 64 + c8) = *(const u32x4*)(Kb + g);
            *(u32x4*)(sV + row * 64 + c8) = *(const u32x4*)(Vb + g);
        }
    }
    __syncthreads();

    int i = t;
    long qrow = (long)b * SEQ + (long)blk * WIN + i;
    float q[64];
    {
        const bf16x8* qp = (const bf16x8*)(Qb + (size_t)qrow * DMODEL + h * 64);
        #pragma unroll
        for (int c = 0; c < 8; ++c) {
            bf16x8 v = qp[c];
            #pragma unroll
            for (int j = 0; j < 8; ++j) q[c * 8 + j] = (float)v[j];
        }
    }
    // gates
    float dl = 0.f, dr = 0.f;
    #pragma unroll
    for (int d = 0; d < 64; ++d) { dl += q[d] * sgl[d]; dr += q[d] * sgr[d]; }
    float gl = 1.f / (1.f + __expf(-dl));
    float grv = 1.f / (1.f + __expf(-dr));
    grbuf[(size_t)qrow * 16 + h] = grv;

    float acc[64], lsum = 0.f;
    #pragma unroll
    for (int d = 0; d < 64; ++d) acc[d] = 0.f;

    int jstart = 64 * w + 1;
    if (blk == 0 && jstart < 256) jstart = 256;
    int jend = 64 * w + 320; if (jend > 511) jend = 511;

    for (int jw = jstart; jw <= jend; ++jw) {
        const bf16x8* kr = (const bf16x8*)(sK + jw * 64);
        float sc = 0.f;
        #pragma unroll
        for (int c = 0; c < 8; ++c) {
            bf16x8 kv = kr[c];
            #pragma unroll
            for (int j = 0; j < 8; ++j) sc += q[c * 8 + j] * (float)kv[j];
        }
        bool act = (jw > i) & (jw <= i + 256);
        // scores are tightly bounded (|s|<~5) -> exp without max tracking is safe
        float pp = act ? __expf(sc * 0.125f) : 0.f;
        lsum += pp;
        const bf16x8* vr = (const bf16x8*)(sV + jw * 64);
        #pragma unroll
        for (int c = 0; c < 8; ++c) {
            bf16x8 vv = vr[c];
            #pragma unroll
            for (int j = 0; j < 8; ++j) acc[c * 8 + j] += pp * (float)vv[j];
        }
    }
    float scale = gl / lsum;
    #pragma unroll
    for (int c = 0; c < 8; ++c) {
        bf16x8 v;
        #pragma unroll
        for (int j = 0; j < 8; ++j) v[j] = (__bf16)(acc[c * 8 + j] * scale);
        *(bf16x8*)(outl + (size_t)qrow * DMODEL + h * 64 + c * 8) = v;
    }
}

// ---------------- latent (remote) attention ----------------
// grid (16 s-blocks, 8 latent heads, 2 batch), 256 threads, thread = one s.
__global__ __launch_bounds__(256) void latent_attn(const __bf16* __restrict__ GQ,
                                                   const __bf16* __restrict__ GK,
                                                   const __bf16* __restrict__ GV,
                                                   __bf16* __restrict__ rem) {
    int sb = blockIdx.x, lh = blockIdx.y, b = blockIdx.z;
    int t = threadIdx.x;
    __shared__ alignas(16) float sKl[64 * 64];
    __shared__ alignas(16) float sVl[64 * 64];
    for (int rep = 0; rep < 16; ++rep) {
        int idx = rep * 256 + t;
        int n = idx >> 6, d = idx & 63;
        size_t g = (size_t)(b * 64 + n) * LDIM + lh * 64 + d;
        sKl[idx] = (float)GK[g];
        sVl[idx] = (float)GV[g];
    }
    __syncthreads();

    int s = sb * 256 + t;
    float q[64];
    {
        const bf16x8* qp = (const bf16x8*)(GQ + ((size_t)b * SEQ + s) * LDIM + lh * 64);
        #pragma unroll
        for (int c = 0; c < 8; ++c) {
            bf16x8 v = qp[c];
            #pragma unroll
            for (int j = 0; j < 8; ++j) q[c * 8 + j] = (float)v[j];
        }
    }
    int nv = s / 64 + 1;        // latents valid: n < nv
    int nmax = sb * 4 + 4;      // uniform per block, >= nv for all threads
    if (nmax > 64) nmax = 64;

    float l = 0.f, o[64];
    #pragma unroll
    for (int d = 0; d < 64; ++d) o[d] = 0.f;
    for (int n = 0; n < nmax; ++n) {
        const f32x4* kr = (const f32x4*)(sKl + n * 64);
        float sc = 0.f;
        #pragma unroll
        for (int c = 0; c < 16; ++c) {
            f32x4 kv = kr[c];
            sc += q[c*4]*kv[0] + q[c*4+1]*kv[1] + q[c*4+2]*kv[2] + q[c*4+3]*kv[3];
        }
        float pp = (n < nv) ? __expf(sc * 0.125f) : 0.f;
        l += pp;
        const f32x4* vr = (const f32x4*)(sVl + n * 64);
        #pragma unroll
        for (int c = 0; c < 16; ++c) {
            f32x4 vv = vr[c];
            o[c*4]   += pp * vv[0]; o[c*4+1] += pp * vv[1];
            o[c*4+2] += pp * vv[2]; o[c*4+3] += pp * vv[3];
        }
    }
    float inv = 1.f / l;
    #pragma unroll
    for (int c = 0; c < 8; ++c) {
        bf16x8 v;
        #pragma unroll
        for (int j = 0; j < 8; ++j) v[j] = (__bf16)(o[c * 8 + j] * inv);
        *(bf16x8*)(rem + ((size_t)b * SEQ + s) * LDIM + lh * 64 + c * 8) = v;
    }
}

// ---------------- host launcher ----------------
extern "C" void kernel_launch(void* const* d_in, const int* in_sizes, int n_in,
                              void* d_out, int out_size, void* d_ws, size_t ws_size,
                              hipStream_t stream) {
    (void)in_sizes; (void)n_in; (void)out_size; (void)ws_size;
    const float* x    = (const float*)d_in[0];
    const float* wq   = (const float*)d_in[1];
    const float* wk   = (const float*)d_in[2];
    const float* wv   = (const float*)d_in[3];
    const float* wgq  = (const float*)d_in[4];
    const float* wgk  = (const float*)d_in[5];
    const float* wgv  = (const float*)d_in[6];
    const float* rout = (const float*)d_in[7];
    const float* glw  = (const float*)d_in[8];
    const float* grw  = (const float*)d_in[9];
    const float* wout = (const float*)d_in[10];

    char* p = (char*)d_ws;
    auto alloc = [&](size_t bytes) {
        char* r = p;
        p += (bytes + 255) & ~(size_t)255;
        return r;
    };
    __bf16* xb    = (__bf16*)alloc((size_t)BSROWS * DMODEL * 2);
    __bf16* Qb    = (__bf16*)alloc((size_t)BSROWS * DMODEL * 2);
    __bf16* Kb    = (__bf16*)alloc((size_t)BSROWS * DMODEL * 2);
    __bf16* Vb    = (__bf16*)alloc((size_t)BSROWS * DMODEL * 2);
    __bf16* GQb   = (__bf16*)alloc((size_t)BSROWS * LDIM * 2);
    __bf16* wqT   = (__bf16*)alloc((size_t)DMODEL * DMODEL * 2);
    __bf16* wkT   = (__bf16*)alloc((size_t)DMODEL * DMODEL * 2);
    __bf16* wvT   = (__bf16*)alloc((size_t)DMODEL * DMODEL * 2);
    __bf16* woutT = (__bf16*)alloc((size_t)DMODEL * DMODEL * 2);
    __bf16* wgqT  = (__bf16*)alloc((size_t)LDIM * DMODEL * 2);
    __bf16* wgkT  = (__bf16*)alloc((size_t)LDIM * DMODEL * 2);
    __bf16* wgvT  = (__bf16*)alloc((size_t)LDIM * DMODEL * 2);
    __bf16* routT = (__bf16*)alloc((size_t)DMODEL * LDIM * 2);
    __bf16* xpool = (__bf16*)alloc((size_t)128 * DMODEL * 2);
    __bf16* GKb   = (__bf16*)alloc((size_t)128 * LDIM * 2);
    __bf16* GVb   = (__bf16*)alloc((size_t)128 * LDIM * 2);
    __bf16* localg= (__bf16*)alloc((size_t)BSROWS * DMODEL * 2);
    float*  grbuf = (float*) alloc((size_t)BSROWS * 16 * 4);
    __bf16* remb  = (__bf16*)alloc((size_t)BSROWS * LDIM * 2);
    __bf16* outpre = Kb; // alias: Kb is dead after local_attn

    // 1. x -> bf16
    cvt_f32_to_bf16<<<dim3((BSROWS * DMODEL / 4 + 255) / 256), 256, 0, stream>>>(
        x, xb, BSROWS * DMODEL / 4);
    // 2. weight transposes -> bf16 [N][K]
    dim3 tb(32, 8);
    transpose_cvt<<<dim3(32, 32), tb, 0, stream>>>(wq,   wqT,   DMODEL, DMODEL);
    transpose_cvt<<<dim3(32, 32), tb, 0, stream>>>(wk,   wkT,   DMODEL, DMODEL);
    transpose_cvt<<<dim3(32, 32), tb, 0, stream>>>(wv,   wvT,   DMODEL, DMODEL);
    transpose_cvt<<<dim3(32, 32), tb, 0, stream>>>(wout, woutT, DMODEL, DMODEL);
    transpose_cvt<<<dim3(32, 16), tb, 0, stream>>>(wgq,  wgqT,  DMODEL, LDIM);
    transpose_cvt<<<dim3(32, 16), tb, 0, stream>>>(wgk,  wgkT,  DMODEL, LDIM);
    transpose_cvt<<<dim3(32, 16), tb, 0, stream>>>(wgv,  wgvT,  DMODEL, LDIM);
    transpose_cvt<<<dim3(16, 32), tb, 0, stream>>>(rout, routT, LDIM, DMODEL);
    // 3. pooled x
    pool_x_kernel<<<dim3(4, 128), 256, 0, stream>>>(x, xpool);
    // 4. projections
    gemm_bf16<false, true><<<dim3(64, 8), 256, 0, stream>>>(xb, wqT, BSROWS, DMODEL, DMODEL, Qb, nullptr, nullptr, nullptr);
    gemm_bf16<false, true><<<dim3(64, 8), 256, 0, stream>>>(xb, wkT, BSROWS, DMODEL, DMODEL, Kb, nullptr, nullptr, nullptr);
    gemm_bf16<false, true><<<dim3(64, 8), 256, 0, stream>>>(xb, wvT, BSROWS, DMODEL, DMODEL, Vb, nullptr, nullptr, nullptr);
    gemm_bf16<false, true><<<dim3(64, 4), 256, 0, stream>>>(xb, wgqT, BSROWS, LDIM, DMODEL, GQb, nullptr, nullptr, nullptr);
    gemm_bf16<false, true><<<dim3(1, 4), 256, 0, stream>>>(xpool, wgkT, 128, LDIM, DMODEL, GKb, nullptr, nullptr, nullptr);
    gemm_bf16<false, true><<<dim3(1, 4), 256, 0, stream>>>(xpool, wgvT, 128, LDIM, DMODEL, GVb, nullptr, nullptr, nullptr);
    // 5. attentions
    local_attn<<<dim3(16, 16, 2), 256, 0, stream>>>(Qb, Kb, Vb, glw, grw, localg, grbuf);
    latent_attn<<<dim3(16, 8, 2), 256, 0, stream>>>(GQb, GKb, GVb, remb);
    // 6. rem @ r_out_w, fused combine: outpre = localg + gr * (rem @ r_out_w)
    gemm_bf16<true, true><<<dim3(64, 8), 256, 0, stream>>>(remb, routT, BSROWS, DMODEL, LDIM, outpre, nullptr, localg, grbuf);
    // 7. final projection -> f32 d_out
    gemm_bf16<false, false><<<dim3(64, 8), 256, 0, stream>>>(outpre, woutT, BSROWS, DMODEL, DMODEL, nullptr, (float*)d_out, nullptr, nullptr);
}

// Round 3
// 376.769 us; speedup vs baseline: 2.4221x; 2.4221x over previous
//
#include <hip/hip_runtime.h>

#define AS1 __attribute__((address_space(1)))
#define AS3 __attribute__((address_space(3)))

typedef float    f32x4  __attribute__((ext_vector_type(4)));
typedef __bf16   bf16x8 __attribute__((ext_vector_type(8)));
typedef __bf16   bf16x4 __attribute__((ext_vector_type(4)));
typedef unsigned int u32x4 __attribute__((ext_vector_type(4)));

static constexpr int SEQ = 4096, NBATCH = 2, DMODEL = 1024, NHEADS = 16, HDIM = 64;
static constexpr int LHEADS = 8, LDIM = 512, NLAT = 64, WIN = 256;
static constexpr int BSROWS = NBATCH * SEQ; // 8192

// ---------------- f32 -> bf16 convert (vectorized) ----------------
__global__ __launch_bounds__(256) void cvt_f32_to_bf16(const float* __restrict__ in,
                                                       __bf16* __restrict__ out, int n4) {
    int i = blockIdx.x * 256 + threadIdx.x;
    if (i >= n4) return;
    f32x4 v = ((const f32x4*)in)[i];
    bf16x4 r;
    r[0] = (__bf16)v[0]; r[1] = (__bf16)v[1]; r[2] = (__bf16)v[2]; r[3] = (__bf16)v[3];
    ((bf16x4*)out)[i] = r;
}

// ---------------- transpose + convert: out[n*K+k] = (bf16)in[k*N+n] ----------------
__global__ void transpose_cvt(const float* __restrict__ in, __bf16* __restrict__ out,
                              int K, int N) {
    __shared__ float t[32][33];
    int k0 = blockIdx.x * 32, n0 = blockIdx.y * 32;
    int tx = threadIdx.x, ty = threadIdx.y; // (32, 8)
    #pragma unroll
    for (int i = ty; i < 32; i += 8) t[i][tx] = in[(size_t)(k0 + i) * N + n0 + tx];
    __syncthreads();
    #pragma unroll
    for (int i = ty; i < 32; i += 8) out[(size_t)(n0 + i) * K + k0 + tx] = (__bf16)t[tx][i];
}

// ---------------- bf16 transpose per batch: Vt[b][c][s] = V[b][s][c] ----------------
__global__ __launch_bounds__(256) void transpose_v_bf16(const __bf16* __restrict__ V,
                                                        __bf16* __restrict__ Vt) {
    __shared__ __bf16 tl[64][65];
    int s0 = blockIdx.x * 64, c0 = blockIdx.y * 64, b = blockIdx.z;
    int tx = threadIdx.x & 63, ty = threadIdx.x >> 6;
    #pragma unroll
    for (int i = ty; i < 64; i += 4)
        tl[i][tx] = V[(size_t)(b * SEQ + s0 + i) * DMODEL + c0 + tx];
    __syncthreads();
    #pragma unroll
    for (int i = ty; i < 64; i += 4)
        Vt[(size_t)(b * DMODEL + c0 + i) * SEQ + s0 + tx] = tl[tx][i];
}

// ---------------- pool x over chunks of 64 rows -> bf16 [128][1024] ----------------
__global__ __launch_bounds__(256) void pool_x_kernel(const float* __restrict__ x,
                                                     __bf16* __restrict__ xpool) {
    int c  = blockIdx.x * 256 + threadIdx.x; // 0..1023
    int bn = blockIdx.y;                     // b*64+n
    const float* p = x + (size_t)bn * 64 * 1024 + c;
    float s = 0.f;
    #pragma unroll 8
    for (int j = 0; j < 64; ++j) s += p[(size_t)j * 1024];
    xpool[(size_t)bn * 1024 + c] = (__bf16)(s * 0.015625f);
}

// ---------------- bf16 MFMA GEMM: C[M,N] = A[M,K] @ Bt[N,K]^T ----------------
template <bool EPI, bool OUTBF>
__global__ __launch_bounds__(256) void gemm_bf16(const __bf16* __restrict__ A,
                                                 const __bf16* __restrict__ Bt,
                                                 int M, int N, int K,
                                                 __bf16* __restrict__ outb,
                                                 float* __restrict__ outf,
                                                 const __bf16* __restrict__ lcl,
                                                 const float* __restrict__ grb) {
    __shared__ alignas(16) __bf16 sA[128 * 64];
    __shared__ alignas(16) __bf16 sB[128 * 64];
    int t = threadIdx.x, w = t >> 6, l = t & 63;
    int m0 = blockIdx.x * 128, n0 = blockIdx.y * 128;
    int wr = w >> 1, wc = w & 1;
    int lr = l & 15, lk = (l >> 4) * 8;

    f32x4 zero = {0.f, 0.f, 0.f, 0.f};
    f32x4 acc[4][4];
    #pragma unroll
    for (int a = 0; a < 4; ++a)
        #pragma unroll
        for (int b2 = 0; b2 < 4; ++b2) acc[a][b2] = zero;

    for (int kt = 0; kt < K; kt += 64) {
        #pragma unroll
        for (int c = 0; c < 4; ++c) {
            int lin  = w * 64 + c * 256;
            int linl = lin + l;
            int row = linl >> 3, c8 = (linl & 7) * 8;
            __builtin_amdgcn_global_load_lds(
                (const AS1 void*)(A + (size_t)(m0 + row) * K + kt + c8),
                (AS3 void*)((char*)sA + (size_t)lin * 16), 16, 0, 0);
            __builtin_amdgcn_global_load_lds(
                (const AS1 void*)(Bt + (size_t)(n0 + row) * K + kt + c8),
                (AS3 void*)((char*)sB + (size_t)lin * 16), 16, 0, 0);
        }
        __syncthreads();
        #pragma unroll
        for (int ks = 0; ks < 2; ++ks) {
            bf16x8 av[4], bv[4];
            #pragma unroll
            for (int mi = 0; mi < 4; ++mi)
                av[mi] = *(const bf16x8*)(sA + (wr * 64 + mi * 16 + lr) * 64 + ks * 32 + lk);
            #pragma unroll
            for (int ni = 0; ni < 4; ++ni)
                bv[ni] = *(const bf16x8*)(sB + (wc * 64 + ni * 16 + lr) * 64 + ks * 32 + lk);
            #pragma unroll
            for (int mi = 0; mi < 4; ++mi)
                #pragma unroll
                for (int ni = 0; ni < 4; ++ni)
                    acc[mi][ni] = __builtin_amdgcn_mfma_f32_16x16x32_bf16(
                        av[mi], bv[ni], acc[mi][ni], 0, 0, 0);
        }
        __syncthreads();
    }

    int cr = (l >> 4) * 4, cc = l & 15;
    #pragma unroll
    for (int mi = 0; mi < 4; ++mi) {
        #pragma unroll
        for (int ni = 0; ni < 4; ++ni) {
            int col = n0 + wc * 64 + ni * 16 + cc;
            #pragma unroll
            for (int r = 0; r < 4; ++r) {
                int row = m0 + wr * 64 + mi * 16 + cr + r;
                float v = acc[mi][ni][r];
                if constexpr (EPI) {
                    v = (float)lcl[(size_t)row * 1024 + col] +
                        grb[(size_t)row * 16 + (col >> 6)] * v;
                }
                if constexpr (OUTBF) outb[(size_t)row * N + col] = (__bf16)v;
                else                 outf[(size_t)row * N + col] = v;
            }
        }
    }
}

// ---------------- local sliding-window attention, MFMA version ----------------
// grid (16 blk, 16 h, 2 b), 256 threads = 4 waves, wave w owns 64 queries.
// Swapped QK^T: S^T = mfma(K_frag, Q_frag) -> softmax sum is lane-local + 2-shfl
// butterfly. P via per-wave LDS (no barriers in main loop). V from pre-transposed
// Vt global, staged with XOR-swizzle (G4) like K.
// NOTE: P rows are 64B -> swizzle must be (row&3)<<4 (a (row&7)<<4 swizzle sets
// bit 6 = +64B and collides with the next row; that was round 2's bug).
__global__ __launch_bounds__(256, 1) void local_attn_mfma(
    const __bf16* __restrict__ Qb, const __bf16* __restrict__ Kb,
    const __bf16* __restrict__ Vt, const float* __restrict__ glw,
    const float* __restrict__ grw, __bf16* __restrict__ outl,
    float* __restrict__ grbuf) {
    int blk = blockIdx.x, h = blockIdx.y, b = blockIdx.z;
    int t = threadIdx.x, w = t >> 6, l = t & 63;
    int l15 = l & 15, l4 = l >> 4;

    __shared__ alignas(16) char sKb[512 * 128];   // K  [key 512][d 64] bf16, XOR-swz
    __shared__ alignas(16) char sVb[64 * 1024];   // V^T [d 64][key 512] bf16, XOR-swz
    __shared__ alignas(16) char sPb[4 * 64 * 64]; // per-wave P [q 64][k 32] bf16, XOR-swz

    // Q fragments (B-operand): qf[qq][ks] = Q[q0+qq*16+l15][ks*32 + l4*8 .. +8]
    bf16x8 qf[4][2];
    long qbase = (long)b * SEQ + blk * 256 + 64 * w;
    #pragma unroll
    for (int qq = 0; qq < 4; ++qq)
        #pragma unroll
        for (int ks = 0; ks < 2; ++ks)
            qf[qq][ks] = *(const bf16x8*)(Qb + (size_t)(qbase + qq * 16 + l15) * DMODEL
                                          + h * 64 + ks * 32 + l4 * 8);

    // stage K rows and Vt rows (zero the invalid pad region for blk==0)
    long g0 = (long)b * SEQ + (long)(blk - 1) * WIN;
    #pragma unroll
    for (int rep = 0; rep < 16; ++rep) {
        int ci = rep * 256 + t;
        {   // K: row=key (512 rows x 128B)
            int row = ci >> 3, c8 = (ci & 7) * 8;
            u32x4 kv = {0u, 0u, 0u, 0u};
            if (!(blk == 0 && row < 256))
                kv = *(const u32x4*)(Kb + (size_t)(g0 + row) * DMODEL + h * 64 + c8);
            *(u32x4*)(sKb + row * 128 + ((c8 * 2) ^ ((row & 7) << 4))) = kv;
        }
        {   // Vt: row=d (64 rows x 1024B), key chunk kc..kc+7
            int d = ci >> 6, kc = (ci & 63) * 8;
            u32x4 vv = {0u, 0u, 0u, 0u};
            if (!(blk == 0 && kc < 256))
                vv = *(const u32x4*)(Vt + (size_t)(b * DMODEL + h * 64 + d) * SEQ
                                     + (long)(blk - 1) * WIN + kc);
            *(u32x4*)(sVb + d * 1024 + ((kc * 2) ^ ((d & 7) << 4))) = vv;
        }
    }

    // gate dot-products from Q fragments (full 64-d via butterfly)
    float dlp[4], drp[4];
    #pragma unroll
    for (int qq = 0; qq < 4; ++qq) {
        float dl = 0.f, dr = 0.f;
        #pragma unroll
        for (int ks = 0; ks < 2; ++ks) {
            const float* gp = glw + h * 64 + ks * 32 + l4 * 8;
            const float* rp = grw + h * 64 + ks * 32 + l4 * 8;
            #pragma unroll
            for (int j = 0; j < 8; ++j) {
                float qv = (float)qf[qq][ks][j];
                dl += qv * gp[j];
                dr += qv * rp[j];
            }
        }
        dlp[qq] = dl; drp[qq] = dr;
    }
    float glv[4], grv[4];
    #pragma unroll
    for (int qq = 0; qq < 4; ++qq) {
        float dl = dlp[qq] + __shfl_xor(dlp[qq], 16);
        dl += __shfl_xor(dl, 32);
        float dr = drp[qq] + __shfl_xor(drp[qq], 16);
        dr += __shfl_xor(dr, 32);
        glv[qq] = 1.f / (1.f + __expf(-dl));
        grv[qq] = 1.f / (1.f + __expf(-dr));
    }
    if (l4 == 0) {
        #pragma unroll
        for (int qq = 0; qq < 4; ++qq)
            grbuf[(size_t)(qbase + qq * 16 + l15) * 16 + h] = grv[qq];
    }
    __syncthreads();

    f32x4 zero = {0.f, 0.f, 0.f, 0.f};
    f32x4 acc[4][4];
    #pragma unroll
    for (int a = 0; a < 4; ++a)
        #pragma unroll
        for (int d = 0; d < 4; ++d) acc[a][d] = zero;
    float psum[4] = {0.f, 0.f, 0.f, 0.f};

    char* sPw = sPb + w * 4096;
    int nsteps = (w == 3) ? 10 : 11;
    int kk0 = 64 * w;

    for (int stp = 0; stp < nsteps; ++stp) {
        int kk = kk0 + 32 * stp;
        // S^T tiles: sacc[kt2][qq], key=(l4*4+r)+kt2*16+kk, q=qq*16+l15
        f32x4 sacc[2][4];
        #pragma unroll
        for (int kt2 = 0; kt2 < 2; ++kt2) {
            int krow = kk + kt2 * 16 + l15;
            int swz = (krow & 7) << 4;
            bf16x8 af0 = *(const bf16x8*)(sKb + krow * 128 + ((l4 * 16) ^ swz));
            bf16x8 af1 = *(const bf16x8*)(sKb + krow * 128 + ((64 + l4 * 16) ^ swz));
            #pragma unroll
            for (int qq = 0; qq < 4; ++qq) {
                f32x4 s = __builtin_amdgcn_mfma_f32_16x16x32_bf16(af0, qf[qq][0], zero, 0, 0, 0);
                sacc[kt2][qq] = __builtin_amdgcn_mfma_f32_16x16x32_bf16(af1, qf[qq][1], s, 0, 0, 0);
            }
        }
        // mask + exp + pack P (bf16) into per-wave LDS
        #pragma unroll
        for (int qq = 0; qq < 4; ++qq) {
            int qloc = 64 * w + qq * 16 + l15;
            int prow = qq * 16 + l15;
            #pragma unroll
            for (int kt2 = 0; kt2 < 2; ++kt2) {
                int jb = kk + kt2 * 16 + l4 * 4;
                bf16x4 pb;
                #pragma unroll
                for (int r = 0; r < 4; ++r) {
                    int jw = jb + r;
                    bool act = (jw > qloc) && (jw <= qloc + 256) && (blk > 0 || jw >= 256);
                    float pv = act ? __expf(sacc[kt2][qq][r] * 0.125f) : 0.f;
                    psum[qq] += pv;
                    pb[r] = (__bf16)pv;
                }
                *(bf16x4*)(sPw + prow * 64 + ((kt2 * 32 + l4 * 8) ^ ((prow & 3) << 4))) = pb;
            }
        }
        // PV: pa[qq] = P[qq*16+l15][l4*8..+8]; bv[dt] = V^T[dt*16+l15][kk+l4*8..+8]
        bf16x8 pa[4], bv[4];
        #pragma unroll
        for (int qq = 0; qq < 4; ++qq) {
            int prow = qq * 16 + l15;
            pa[qq] = *(const bf16x8*)(sPw + prow * 64 + ((l4 * 16) ^ ((prow & 3) << 4)));
        }
        #pragma unroll
        for (int dt = 0; dt < 4; ++dt) {
            int d = dt * 16 + l15;
            bv[dt] = *(const bf16x8*)(sVb + d * 1024 + ((kk * 2 + l4 * 16) ^ ((d & 7) << 4)));
        }
        #pragma unroll
        for (int qq = 0; qq < 4; ++qq)
            #pragma unroll
            for (int dt = 0; dt < 4; ++dt)
                acc[qq][dt] = __builtin_amdgcn_mfma_f32_16x16x32_bf16(pa[qq], bv[dt], acc[qq][dt], 0, 0, 0);
    }

    // combine: scale by gl / lsum (redistribute across lane mapping), store
    float cmb[4];
    #pragma unroll
    for (int qq = 0; qq < 4; ++qq) {
        float s = psum[qq] + __shfl_xor(psum[qq], 16);
        s += __shfl_xor(s, 32);
        cmb[qq] = glv[qq] / s;
    }
    #pragma unroll
    for (int qq = 0; qq < 4; ++qq) {
        #pragma unroll
        for (int r = 0; r < 4; ++r) {
            float sc = __shfl(cmb[qq], l4 * 4 + r, 64);
            size_t row = (size_t)(qbase + qq * 16 + l4 * 4 + r);
            __bf16* op = outl + row * DMODEL + h * 64 + l15;
            #pragma unroll
            for (int dt = 0; dt < 4; ++dt)
                op[dt * 16] = (__bf16)(acc[qq][dt][r] * sc);
        }
    }
}

// ---------------- latent (remote) attention ----------------
__global__ __launch_bounds__(256) void latent_attn(const __bf16* __restrict__ GQ,
                                                   const __bf16* __restrict__ GK,
                                                   const __bf16* __restrict__ GV,
                                                   __bf16* __restrict__ rem) {
    int sb = blockIdx.x, lh = blockIdx.y, b = blockIdx.z;
    int t = threadIdx.x;
    __shared__ alignas(16) float sKl[64 * 64];
    __shared__ alignas(16) float sVl[64 * 64];
    for (int rep = 0; rep < 16; ++rep) {
        int idx = rep * 256 + t;
        int n = idx >> 6, d = idx & 63;
        size_t g = (size_t)(b * 64 + n) * LDIM + lh * 64 + d;
        sKl[idx] = (float)GK[g];
        sVl[idx] = (float)GV[g];
    }
    __syncthreads();

    int s = sb * 256 + t;
    float q[64];
    {
        const bf16x8* qp = (const bf16x8*)(GQ + ((size_t)b * SEQ + s) * LDIM + lh * 64);
        #pragma unroll
        for (int c = 0; c < 8; ++c) {
            bf16x8 v = qp[c];
            #pragma unroll
            for (int j = 0; j < 8; ++j) q[c * 8 + j] = (float)v[j];
        }
    }
    int nv = s / 64 + 1;
    int nmax = sb * 4 + 4;
    if (nmax > 64) nmax = 64;

    float lsum = 0.f, o[64];
    #pragma unroll
    for (int d = 0; d < 64; ++d) o[d] = 0.f;
    for (int n = 0; n < nmax; ++n) {
        const f32x4* kr = (const f32x4*)(sKl + n * 64);
        float sc = 0.f;
        #pragma unroll
        for (int c = 0; c < 16; ++c) {
            f32x4 kv = kr[c];
            sc += q[c*4]*kv[0] + q[c*4+1]*kv[1] + q[c*4+2]*kv[2] + q[c*4+3]*kv[3];
        }
        float pp = (n < nv) ? __expf(sc * 0.125f) : 0.f;
        lsum += pp;
        const f32x4* vr = (const f32x4*)(sVl + n * 64);
        #pragma unroll
        for (int c = 0; c < 16; ++c) {
            f32x4 vv = vr[c];
            o[c*4]   += pp * vv[0]; o[c*4+1] += pp * vv[1];
            o[c*4+2] += pp * vv[2]; o[c*4+3] += pp * vv[3];
        }
    }
    float inv = 1.f / lsum;
    #pragma unroll
    for (int c = 0; c < 8; ++c) {
        bf16x8 v;
        #pragma unroll
        for (int j = 0; j < 8; ++j) v[j] = (__bf16)(o[c * 8 + j] * inv);
        *(bf16x8*)(rem + ((size_t)b * SEQ + s) * LDIM + lh * 64 + c * 8) = v;
    }
}

// ---------------- host launcher ----------------
extern "C" void kernel_launch(void* const* d_in, const int* in_sizes, int n_in,
                              void* d_out, int out_size, void* d_ws, size_t ws_size,
                              hipStream_t stream) {
    (void)in_sizes; (void)n_in; (void)out_size; (void)ws_size;
    const float* x    = (const float*)d_in[0];
    const float* wq   = (const float*)d_in[1];
    const float* wk   = (const float*)d_in[2];
    const float* wv   = (const float*)d_in[3];
    const float* wgq  = (const float*)d_in[4];
    const float* wgk  = (const float*)d_in[5];
    const float* wgv  = (const float*)d_in[6];
    const float* rout = (const float*)d_in[7];
    const float* glw  = (const float*)d_in[8];
    const float* grw  = (const float*)d_in[9];
    const float* wout = (const float*)d_in[10];

    char* p = (char*)d_ws;
    auto alloc = [&](size_t bytes) {
        char* r = p;
        p += (bytes + 255) & ~(size_t)255;
        return r;
    };
    __bf16* xb    = (__bf16*)alloc((size_t)BSROWS * DMODEL * 2);
    __bf16* Qb    = (__bf16*)alloc((size_t)BSROWS * DMODEL * 2);
    __bf16* Kb    = (__bf16*)alloc((size_t)BSROWS * DMODEL * 2);
    __bf16* Vb    = (__bf16*)alloc((size_t)BSROWS * DMODEL * 2);
    __bf16* VtG   = (__bf16*)alloc((size_t)BSROWS * DMODEL * 2);
    __bf16* GQb   = (__bf16*)alloc((size_t)BSROWS * LDIM * 2);
    __bf16* wqT   = (__bf16*)alloc((size_t)DMODEL * DMODEL * 2);
    __bf16* wkT   = (__bf16*)alloc((size_t)DMODEL * DMODEL * 2);
    __bf16* wvT   = (__bf16*)alloc((size_t)DMODEL * DMODEL * 2);
    __bf16* woutT = (__bf16*)alloc((size_t)DMODEL * DMODEL * 2);
    __bf16* wgqT  = (__bf16*)alloc((size_t)LDIM * DMODEL * 2);
    __bf16* wgkT  = (__bf16*)alloc((size_t)LDIM * DMODEL * 2);
    __bf16* wgvT  = (__bf16*)alloc((size_t)LDIM * DMODEL * 2);
    __bf16* routT = (__bf16*)alloc((size_t)DMODEL * LDIM * 2);
    __bf16* xpool = (__bf16*)alloc((size_t)128 * DMODEL * 2);
    __bf16* GKb   = (__bf16*)alloc((size_t)128 * LDIM * 2);
    __bf16* GVb   = (__bf16*)alloc((size_t)128 * LDIM * 2);
    __bf16* localg= (__bf16*)alloc((size_t)BSROWS * DMODEL * 2);
    float*  grbuf = (float*) alloc((size_t)BSROWS * 16 * 4);
    __bf16* remb  = (__bf16*)alloc((size_t)BSROWS * LDIM * 2);
    __bf16* outpre = Kb; // alias: Kb is dead after local_attn

    cvt_f32_to_bf16<<<dim3((BSROWS * DMODEL / 4 + 255) / 256), 256, 0, stream>>>(
        x, xb, BSROWS * DMODEL / 4);
    dim3 tb(32, 8);
    transpose_cvt<<<dim3(32, 32), tb, 0, stream>>>(wq,   wqT,   DMODEL, DMODEL);
    transpose_cvt<<<dim3(32, 32), tb, 0, stream>>>(wk,   wkT,   DMODEL, DMODEL);
    transpose_cvt<<<dim3(32, 32), tb, 0, stream>>>(wv,   wvT,   DMODEL, DMODEL);
    transpose_cvt<<<dim3(32, 32), tb, 0, stream>>>(wout, woutT, DMODEL, DMODEL);
    transpose_cvt<<<dim3(32, 16), tb, 0, stream>>>(wgq,  wgqT,  DMODEL, LDIM);
    transpose_cvt<<<dim3(32, 16), tb, 0, stream>>>(wgk,  wgkT,  DMODEL, LDIM);
    transpose_cvt<<<dim3(32, 16), tb, 0, stream>>>(wgv,  wgvT,  DMODEL, LDIM);
    transpose_cvt<<<dim3(16, 32), tb, 0, stream>>>(rout, routT, LDIM, DMODEL);
    pool_x_kernel<<<dim3(4, 128), 256, 0, stream>>>(x, xpool);

    gemm_bf16<false, true><<<dim3(64, 8), 256, 0, stream>>>(xb, wqT, BSROWS, DMODEL, DMODEL, Qb, nullptr, nullptr, nullptr);
    gemm_bf16<false, true><<<dim3(64, 8), 256, 0, stream>>>(xb, wkT, BSROWS, DMODEL, DMODEL, Kb, nullptr, nullptr, nullptr);
    gemm_bf16<false, true><<<dim3(64, 8), 256, 0, stream>>>(xb, wvT, BSROWS, DMODEL, DMODEL, Vb, nullptr, nullptr, nullptr);
    gemm_bf16<false, true><<<dim3(64, 4), 256, 0, stream>>>(xb, wgqT, BSROWS, LDIM, DMODEL, GQb, nullptr, nullptr, nullptr);
    gemm_bf16<false, true><<<dim3(1, 4), 256, 0, stream>>>(xpool, wgkT, 128, LDIM, DMODEL, GKb, nullptr, nullptr, nullptr);
    gemm_bf16<false, true><<<dim3(1, 4), 256, 0, stream>>>(xpool, wgvT, 128, LDIM, DMODEL, GVb, nullptr, nullptr, nullptr);

    transpose_v_bf16<<<dim3(64, 16, 2), 256, 0, stream>>>(Vb, VtG);

    local_attn_mfma<<<dim3(16, 16, 2), 256, 0, stream>>>(Qb, Kb, VtG, glw, grw, localg, grbuf);
    latent_attn<<<dim3(16, 8, 2), 256, 0, stream>>>(GQb, GKb, GVb, remb);

    gemm_bf16<true, true><<<dim3(64, 8), 256, 0, stream>>>(remb, routT, BSROWS, DMODEL, LDIM, outpre, nullptr, localg, grbuf);
    gemm_bf16<false, false><<<dim3(64, 8), 256, 0, stream>>>(outpre, woutT, BSROWS, DMODEL, DMODEL, nullptr, (float*)d_out, nullptr, nullptr);
}

// Round 4
// 315.390 us; speedup vs baseline: 2.8935x; 1.1946x over previous
//
#include <hip/hip_runtime.h>

#define AS1 __attribute__((address_space(1)))
#define AS3 __attribute__((address_space(3)))

typedef float    f32x4  __attribute__((ext_vector_type(4)));
typedef __bf16   bf16x8 __attribute__((ext_vector_type(8)));
typedef __bf16   bf16x4 __attribute__((ext_vector_type(4)));
typedef unsigned int u32x4 __attribute__((ext_vector_type(4)));

static constexpr int SEQ = 4096, NBATCH = 2, DMODEL = 1024, NHEADS = 16, HDIM = 64;
static constexpr int LHEADS = 8, LDIM = 512, NLAT = 64, WIN = 256;
static constexpr int BSROWS = NBATCH * SEQ; // 8192

// ---------------- f32 -> bf16 convert (vectorized) ----------------
__global__ __launch_bounds__(256) void cvt_f32_to_bf16(const float* __restrict__ in,
                                                       __bf16* __restrict__ out, int n4) {
    int i = blockIdx.x * 256 + threadIdx.x;
    if (i >= n4) return;
    f32x4 v = ((const f32x4*)in)[i];
    bf16x4 r;
    r[0] = (__bf16)v[0]; r[1] = (__bf16)v[1]; r[2] = (__bf16)v[2]; r[3] = (__bf16)v[3];
    ((bf16x4*)out)[i] = r;
}

// ---------------- transpose + convert: out[n*K+k] = (bf16)in[k*N+n] ----------------
__global__ void transpose_cvt(const float* __restrict__ in, __bf16* __restrict__ out,
                              int K, int N) {
    __shared__ float t[32][33];
    int k0 = blockIdx.x * 32, n0 = blockIdx.y * 32;
    int tx = threadIdx.x, ty = threadIdx.y; // (32, 8)
    #pragma unroll
    for (int i = ty; i < 32; i += 8) t[i][tx] = in[(size_t)(k0 + i) * N + n0 + tx];
    __syncthreads();
    #pragma unroll
    for (int i = ty; i < 32; i += 8) out[(size_t)(n0 + i) * K + k0 + tx] = (__bf16)t[tx][i];
}

// ---------------- bf16 transpose per batch: Vt[b][c][s] = V[b][s][c] ----------------
__global__ __launch_bounds__(256) void transpose_v_bf16(const __bf16* __restrict__ V,
                                                        __bf16* __restrict__ Vt) {
    __shared__ __bf16 tl[64][65];
    int s0 = blockIdx.x * 64, c0 = blockIdx.y * 64, b = blockIdx.z;
    int tx = threadIdx.x & 63, ty = threadIdx.x >> 6;
    #pragma unroll
    for (int i = ty; i < 64; i += 4)
        tl[i][tx] = V[(size_t)(b * SEQ + s0 + i) * DMODEL + c0 + tx];
    __syncthreads();
    #pragma unroll
    for (int i = ty; i < 64; i += 4)
        Vt[(size_t)(b * DMODEL + c0 + i) * SEQ + s0 + tx] = tl[tx][i];
}

// ---------------- pool x over chunks of 64 rows -> bf16 [128][1024] ----------------
__global__ __launch_bounds__(256) void pool_x_kernel(const float* __restrict__ x,
                                                     __bf16* __restrict__ xpool) {
    int c  = blockIdx.x * 256 + threadIdx.x; // 0..1023
    int bn = blockIdx.y;                     // b*64+n
    const float* p = x + (size_t)bn * 64 * 1024 + c;
    float s = 0.f;
    #pragma unroll 8
    for (int j = 0; j < 64; ++j) s += p[(size_t)j * 1024];
    xpool[(size_t)bn * 1024 + c] = (__bf16)(s * 0.015625f);
}

// ---------------- bf16 MFMA GEMM: C[M,N] = A[M,K] @ Bt[N,K]^T ----------------
template <bool EPI, bool OUTBF>
__global__ __launch_bounds__(256) void gemm_bf16(const __bf16* __restrict__ A,
                                                 const __bf16* __restrict__ Bt,
                                                 int M, int N, int K,
                                                 __bf16* __restrict__ outb,
                                                 float* __restrict__ outf,
                                                 const __bf16* __restrict__ lcl,
                                                 const float* __restrict__ grb) {
    __shared__ alignas(16) __bf16 sA[128 * 64];
    __shared__ alignas(16) __bf16 sB[128 * 64];
    int t = threadIdx.x, w = t >> 6, l = t & 63;
    int m0 = blockIdx.x * 128, n0 = blockIdx.y * 128;
    int wr = w >> 1, wc = w & 1;
    int lr = l & 15, lk = (l >> 4) * 8;

    f32x4 zero = {0.f, 0.f, 0.f, 0.f};
    f32x4 acc[4][4];
    #pragma unroll
    for (int a = 0; a < 4; ++a)
        #pragma unroll
        for (int b2 = 0; b2 < 4; ++b2) acc[a][b2] = zero;

    for (int kt = 0; kt < K; kt += 64) {
        #pragma unroll
        for (int c = 0; c < 4; ++c) {
            int lin  = w * 64 + c * 256;
            int linl = lin + l;
            int row = linl >> 3, c8 = (linl & 7) * 8;
            __builtin_amdgcn_global_load_lds(
                (const AS1 void*)(A + (size_t)(m0 + row) * K + kt + c8),
                (AS3 void*)((char*)sA + (size_t)lin * 16), 16, 0, 0);
            __builtin_amdgcn_global_load_lds(
                (const AS1 void*)(Bt + (size_t)(n0 + row) * K + kt + c8),
                (AS3 void*)((char*)sB + (size_t)lin * 16), 16, 0, 0);
        }
        __syncthreads();
        #pragma unroll
        for (int ks = 0; ks < 2; ++ks) {
            bf16x8 av[4], bv[4];
            #pragma unroll
            for (int mi = 0; mi < 4; ++mi)
                av[mi] = *(const bf16x8*)(sA + (wr * 64 + mi * 16 + lr) * 64 + ks * 32 + lk);
            #pragma unroll
            for (int ni = 0; ni < 4; ++ni)
                bv[ni] = *(const bf16x8*)(sB + (wc * 64 + ni * 16 + lr) * 64 + ks * 32 + lk);
            #pragma unroll
            for (int mi = 0; mi < 4; ++mi)
                #pragma unroll
                for (int ni = 0; ni < 4; ++ni)
                    acc[mi][ni] = __builtin_amdgcn_mfma_f32_16x16x32_bf16(
                        av[mi], bv[ni], acc[mi][ni], 0, 0, 0);
        }
        __syncthreads();
    }

    int cr = (l >> 4) * 4, cc = l & 15;
    #pragma unroll
    for (int mi = 0; mi < 4; ++mi) {
        #pragma unroll
        for (int ni = 0; ni < 4; ++ni) {
            int col = n0 + wc * 64 + ni * 16 + cc;
            #pragma unroll
            for (int r = 0; r < 4; ++r) {
                int row = m0 + wr * 64 + mi * 16 + cr + r;
                float v = acc[mi][ni][r];
                if constexpr (EPI) {
                    v = (float)lcl[(size_t)row * 1024 + col] +
                        grb[(size_t)row * 16 + (col >> 6)] * v;
                }
                if constexpr (OUTBF) outb[(size_t)row * N + col] = (__bf16)v;
                else                 outf[(size_t)row * N + col] = v;
            }
        }
    }
}

// ---------------- local sliding-window attention, MFMA version ----------------
// (verified round 3)
__global__ __launch_bounds__(256, 1) void local_attn_mfma(
    const __bf16* __restrict__ Qb, const __bf16* __restrict__ Kb,
    const __bf16* __restrict__ Vt, const float* __restrict__ glw,
    const float* __restrict__ grw, __bf16* __restrict__ outl,
    float* __restrict__ grbuf) {
    int blk = blockIdx.x, h = blockIdx.y, b = blockIdx.z;
    int t = threadIdx.x, w = t >> 6, l = t & 63;
    int l15 = l & 15, l4 = l >> 4;

    __shared__ alignas(16) char sKb[512 * 128];   // K  [key 512][d 64] bf16, XOR-swz
    __shared__ alignas(16) char sVb[64 * 1024];   // V^T [d 64][key 512] bf16, XOR-swz
    __shared__ alignas(16) char sPb[4 * 64 * 64]; // per-wave P [q 64][k 32] bf16, XOR-swz

    bf16x8 qf[4][2];
    long qbase = (long)b * SEQ + blk * 256 + 64 * w;
    #pragma unroll
    for (int qq = 0; qq < 4; ++qq)
        #pragma unroll
        for (int ks = 0; ks < 2; ++ks)
            qf[qq][ks] = *(const bf16x8*)(Qb + (size_t)(qbase + qq * 16 + l15) * DMODEL
                                          + h * 64 + ks * 32 + l4 * 8);

    long g0 = (long)b * SEQ + (long)(blk - 1) * WIN;
    #pragma unroll
    for (int rep = 0; rep < 16; ++rep) {
        int ci = rep * 256 + t;
        {   // K: row=key (512 rows x 128B)
            int row = ci >> 3, c8 = (ci & 7) * 8;
            u32x4 kv = {0u, 0u, 0u, 0u};
            if (!(blk == 0 && row < 256))
                kv = *(const u32x4*)(Kb + (size_t)(g0 + row) * DMODEL + h * 64 + c8);
            *(u32x4*)(sKb + row * 128 + ((c8 * 2) ^ ((row & 7) << 4))) = kv;
        }
        {   // Vt: row=d (64 rows x 1024B), key chunk kc..kc+7
            int d = ci >> 6, kc = (ci & 63) * 8;
            u32x4 vv = {0u, 0u, 0u, 0u};
            if (!(blk == 0 && kc < 256))
                vv = *(const u32x4*)(Vt + (size_t)(b * DMODEL + h * 64 + d) * SEQ
                                     + (long)(blk - 1) * WIN + kc);
            *(u32x4*)(sVb + d * 1024 + ((kc * 2) ^ ((d & 7) << 4))) = vv;
        }
    }

    float dlp[4], drp[4];
    #pragma unroll
    for (int qq = 0; qq < 4; ++qq) {
        float dl = 0.f, dr = 0.f;
        #pragma unroll
        for (int ks = 0; ks < 2; ++ks) {
            const float* gp = glw + h * 64 + ks * 32 + l4 * 8;
            const float* rp = grw + h * 64 + ks * 32 + l4 * 8;
            #pragma unroll
            for (int j = 0; j < 8; ++j) {
                float qv = (float)qf[qq][ks][j];
                dl += qv * gp[j];
                dr += qv * rp[j];
            }
        }
        dlp[qq] = dl; drp[qq] = dr;
    }
    float glv[4], grv[4];
    #pragma unroll
    for (int qq = 0; qq < 4; ++qq) {
        float dl = dlp[qq] + __shfl_xor(dlp[qq], 16);
        dl += __shfl_xor(dl, 32);
        float dr = drp[qq] + __shfl_xor(drp[qq], 16);
        dr += __shfl_xor(dr, 32);
        glv[qq] = 1.f / (1.f + __expf(-dl));
        grv[qq] = 1.f / (1.f + __expf(-dr));
    }
    if (l4 == 0) {
        #pragma unroll
        for (int qq = 0; qq < 4; ++qq)
            grbuf[(size_t)(qbase + qq * 16 + l15) * 16 + h] = grv[qq];
    }
    __syncthreads();

    f32x4 zero = {0.f, 0.f, 0.f, 0.f};
    f32x4 acc[4][4];
    #pragma unroll
    for (int a = 0; a < 4; ++a)
        #pragma unroll
        for (int d = 0; d < 4; ++d) acc[a][d] = zero;
    float psum[4] = {0.f, 0.f, 0.f, 0.f};

    char* sPw = sPb + w * 4096;
    int nsteps = (w == 3) ? 10 : 11;
    int kk0 = 64 * w;

    for (int stp = 0; stp < nsteps; ++stp) {
        int kk = kk0 + 32 * stp;
        f32x4 sacc[2][4];
        #pragma unroll
        for (int kt2 = 0; kt2 < 2; ++kt2) {
            int krow = kk + kt2 * 16 + l15;
            int swz = (krow & 7) << 4;
            bf16x8 af0 = *(const bf16x8*)(sKb + krow * 128 + ((l4 * 16) ^ swz));
            bf16x8 af1 = *(const bf16x8*)(sKb + krow * 128 + ((64 + l4 * 16) ^ swz));
            #pragma unroll
            for (int qq = 0; qq < 4; ++qq) {
                f32x4 s = __builtin_amdgcn_mfma_f32_16x16x32_bf16(af0, qf[qq][0], zero, 0, 0, 0);
                sacc[kt2][qq] = __builtin_amdgcn_mfma_f32_16x16x32_bf16(af1, qf[qq][1], s, 0, 0, 0);
            }
        }
        #pragma unroll
        for (int qq = 0; qq < 4; ++qq) {
            int qloc = 64 * w + qq * 16 + l15;
            int prow = qq * 16 + l15;
            #pragma unroll
            for (int kt2 = 0; kt2 < 2; ++kt2) {
                int jb = kk + kt2 * 16 + l4 * 4;
                bf16x4 pb;
                #pragma unroll
                for (int r = 0; r < 4; ++r) {
                    int jw = jb + r;
                    bool act = (jw > qloc) && (jw <= qloc + 256) && (blk > 0 || jw >= 256);
                    float pv = act ? __expf(sacc[kt2][qq][r] * 0.125f) : 0.f;
                    psum[qq] += pv;
                    pb[r] = (__bf16)pv;
                }
                *(bf16x4*)(sPw + prow * 64 + ((kt2 * 32 + l4 * 8) ^ ((prow & 3) << 4))) = pb;
            }
        }
        bf16x8 pa[4], bv[4];
        #pragma unroll
        for (int qq = 0; qq < 4; ++qq) {
            int prow = qq * 16 + l15;
            pa[qq] = *(const bf16x8*)(sPw + prow * 64 + ((l4 * 16) ^ ((prow & 3) << 4)));
        }
        #pragma unroll
        for (int dt = 0; dt < 4; ++dt) {
            int d = dt * 16 + l15;
            bv[dt] = *(const bf16x8*)(sVb + d * 1024 + ((kk * 2 + l4 * 16) ^ ((d & 7) << 4)));
        }
        #pragma unroll
        for (int qq = 0; qq < 4; ++qq)
            #pragma unroll
            for (int dt = 0; dt < 4; ++dt)
                acc[qq][dt] = __builtin_amdgcn_mfma_f32_16x16x32_bf16(pa[qq], bv[dt], acc[qq][dt], 0, 0, 0);
    }

    float cmb[4];
    #pragma unroll
    for (int qq = 0; qq < 4; ++qq) {
        float s = psum[qq] + __shfl_xor(psum[qq], 16);
        s += __shfl_xor(s, 32);
        cmb[qq] = glv[qq] / s;
    }
    #pragma unroll
    for (int qq = 0; qq < 4; ++qq) {
        #pragma unroll
        for (int r = 0; r < 4; ++r) {
            float sc = __shfl(cmb[qq], l4 * 4 + r, 64);
            size_t row = (size_t)(qbase + qq * 16 + l4 * 4 + r);
            __bf16* op = outl + row * DMODEL + h * 64 + l15;
            #pragma unroll
            for (int dt = 0; dt < 4; ++dt)
                op[dt * 16] = (__bf16)(acc[qq][dt][r] * sc);
        }
    }
}

// ---------------- latent (remote) attention, MFMA version ----------------
// Clone of local_attn_mfma structure: grid (16 sb, 8 lh, 2 b), 4 waves x 64 q.
// Keys = 64 latents, chunk-causal mask n <= q>>6. K staged swizzled; V^T built
// in-LDS by scalar transposed stage (64x64). P via per-wave LDS, (prow&3)<<4.
__global__ __launch_bounds__(256, 1) void latent_attn_mfma(
    const __bf16* __restrict__ GQ, const __bf16* __restrict__ GK,
    const __bf16* __restrict__ GV, __bf16* __restrict__ rem) {
    int sb = blockIdx.x, lh = blockIdx.y, b = blockIdx.z;
    int t = threadIdx.x, w = t >> 6, l = t & 63;
    int l15 = l & 15, l4 = l >> 4;

    __shared__ alignas(16) char sK[64 * 128];     // K  [n 64][d 64] bf16, swz (n&7)<<4
    __shared__ alignas(16) char sVt[64 * 128];    // V^T [d 64][n 64] bf16, swz (d&7)<<4
    __shared__ alignas(16) char sPb[4 * 64 * 64]; // per-wave P

    // Q fragments (B-operand)
    bf16x8 qf[4][2];
    long qbase = (long)b * SEQ + sb * 256 + 64 * w;
    #pragma unroll
    for (int qq = 0; qq < 4; ++qq)
        #pragma unroll
        for (int ks = 0; ks < 2; ++ks)
            qf[qq][ks] = *(const bf16x8*)(GQ + (size_t)(qbase + qq * 16 + l15) * LDIM
                                          + lh * 64 + ks * 32 + l4 * 8);

    // stage K (64 rows x 128B, vectorized) and V^T (scalar transposed)
    #pragma unroll
    for (int rep = 0; rep < 2; ++rep) {
        int ci = rep * 256 + t;
        int row = ci >> 3, c8 = (ci & 7) * 8;
        u32x4 kv = *(const u32x4*)(GK + (size_t)(b * 64 + row) * LDIM + lh * 64 + c8);
        *(u32x4*)(sK + row * 128 + ((c8 * 2) ^ ((row & 7) << 4))) = kv;
    }
    #pragma unroll
    for (int rep = 0; rep < 16; ++rep) {
        int idx = rep * 256 + t;
        int d = idx & 63, n = idx >> 6;
        __bf16 v = GV[(size_t)(b * 64 + n) * LDIM + lh * 64 + d];
        *(__bf16*)(sVt + d * 128 + ((n * 2) ^ ((d & 7) << 4))) = v;
    }
    __syncthreads();

    f32x4 zero = {0.f, 0.f, 0.f, 0.f};
    f32x4 acc[4][4];
    #pragma unroll
    for (int a = 0; a < 4; ++a)
        #pragma unroll
        for (int d = 0; d < 4; ++d) acc[a][d] = zero;
    float psum[4] = {0.f, 0.f, 0.f, 0.f};

    char* sPw = sPb + w * 4096;
    int qloc0 = sb * 256 + 64 * w;   // per-batch query base of this wave

    #pragma unroll
    for (int stp = 0; stp < 2; ++stp) {
        int kk = 32 * stp;
        f32x4 sacc[2][4];
        #pragma unroll
        for (int kt2 = 0; kt2 < 2; ++kt2) {
            int krow = kk + kt2 * 16 + l15;
            int swz = (krow & 7) << 4;
            bf16x8 af0 = *(const bf16x8*)(sK + krow * 128 + ((l4 * 16) ^ swz));
            bf16x8 af1 = *(const bf16x8*)(sK + krow * 128 + ((64 + l4 * 16) ^ swz));
            #pragma unroll
            for (int qq = 0; qq < 4; ++qq) {
                f32x4 s = __builtin_amdgcn_mfma_f32_16x16x32_bf16(af0, qf[qq][0], zero, 0, 0, 0);
                sacc[kt2][qq] = __builtin_amdgcn_mfma_f32_16x16x32_bf16(af1, qf[qq][1], s, 0, 0, 0);
            }
        }
        #pragma unroll
        for (int qq = 0; qq < 4; ++qq) {
            int qdv = (qloc0 + qq * 16 + l15) >> 6;  // latents valid: n <= qdv
            int prow = qq * 16 + l15;
            #pragma unroll
            for (int kt2 = 0; kt2 < 2; ++kt2) {
                int nb = kk + kt2 * 16 + l4 * 4;
                bf16x4 pb;
                #pragma unroll
                for (int r = 0; r < 4; ++r) {
                    int n = nb + r;
                    float pv = (n <= qdv) ? __expf(sacc[kt2][qq][r] * 0.125f) : 0.f;
                    psum[qq] += pv;
                    pb[r] = (__bf16)pv;
                }
                *(bf16x4*)(sPw + prow * 64 + ((kt2 * 32 + l4 * 8) ^ ((prow & 3) << 4))) = pb;
            }
        }
        bf16x8 pa[4], bv[4];
        #pragma unroll
        for (int qq = 0; qq < 4; ++qq) {
            int prow = qq * 16 + l15;
            pa[qq] = *(const bf16x8*)(sPw + prow * 64 + ((l4 * 16) ^ ((prow & 3) << 4)));
        }
        #pragma unroll
        for (int dt = 0; dt < 4; ++dt) {
            int d = dt * 16 + l15;
            bv[dt] = *(const bf16x8*)(sVt + d * 128 + ((kk * 2 + l4 * 16) ^ ((d & 7) << 4)));
        }
        #pragma unroll
        for (int qq = 0; qq < 4; ++qq)
            #pragma unroll
            for (int dt = 0; dt < 4; ++dt)
                acc[qq][dt] = __builtin_amdgcn_mfma_f32_16x16x32_bf16(pa[qq], bv[dt], acc[qq][dt], 0, 0, 0);
    }

    float cmb[4];
    #pragma unroll
    for (int qq = 0; qq < 4; ++qq) {
        float s = psum[qq] + __shfl_xor(psum[qq], 16);
        s += __shfl_xor(s, 32);
        cmb[qq] = 1.f / s;
    }
    #pragma unroll
    for (int qq = 0; qq < 4; ++qq) {
        #pragma unroll
        for (int r = 0; r < 4; ++r) {
            float sc = __shfl(cmb[qq], l4 * 4 + r, 64);
            size_t row = (size_t)(qbase + qq * 16 + l4 * 4 + r);
            __bf16* op = rem + row * LDIM + lh * 64 + l15;
            #pragma unroll
            for (int dt = 0; dt < 4; ++dt)
                op[dt * 16] = (__bf16)(acc[qq][dt][r] * sc);
        }
    }
}

// ---------------- host launcher ----------------
extern "C" void kernel_launch(void* const* d_in, const int* in_sizes, int n_in,
                              void* d_out, int out_size, void* d_ws, size_t ws_size,
                              hipStream_t stream) {
    (void)in_sizes; (void)n_in; (void)out_size; (void)ws_size;
    const float* x    = (const float*)d_in[0];
    const float* wq   = (const float*)d_in[1];
    const float* wk   = (const float*)d_in[2];
    const float* wv   = (const float*)d_in[3];
    const float* wgq  = (const float*)d_in[4];
    const float* wgk  = (const float*)d_in[5];
    const float* wgv  = (const float*)d_in[6];
    const float* rout = (const float*)d_in[7];
    const float* glw  = (const float*)d_in[8];
    const float* grw  = (const float*)d_in[9];
    const float* wout = (const float*)d_in[10];

    char* p = (char*)d_ws;
    auto alloc = [&](size_t bytes) {
        char* r = p;
        p += (bytes + 255) & ~(size_t)255;
        return r;
    };
    __bf16* xb    = (__bf16*)alloc((size_t)BSROWS * DMODEL * 2);
    __bf16* Qb    = (__bf16*)alloc((size_t)BSROWS * DMODEL * 2);
    __bf16* Kb    = (__bf16*)alloc((size_t)BSROWS * DMODEL * 2);
    __bf16* Vb    = (__bf16*)alloc((size_t)BSROWS * DMODEL * 2);
    __bf16* VtG   = (__bf16*)alloc((size_t)BSROWS * DMODEL * 2);
    __bf16* GQb   = (__bf16*)alloc((size_t)BSROWS * LDIM * 2);
    __bf16* wqT   = (__bf16*)alloc((size_t)DMODEL * DMODEL * 2);
    __bf16* wkT   = (__bf16*)alloc((size_t)DMODEL * DMODEL * 2);
    __bf16* wvT   = (__bf16*)alloc((size_t)DMODEL * DMODEL * 2);
    __bf16* woutT = (__bf16*)alloc((size_t)DMODEL * DMODEL * 2);
    __bf16* wgqT  = (__bf16*)alloc((size_t)LDIM * DMODEL * 2);
    __bf16* wgkT  = (__bf16*)alloc((size_t)LDIM * DMODEL * 2);
    __bf16* wgvT  = (__bf16*)alloc((size_t)LDIM * DMODEL * 2);
    __bf16* routT = (__bf16*)alloc((size_t)DMODEL * LDIM * 2);
    __bf16* xpool = (__bf16*)alloc((size_t)128 * DMODEL * 2);
    __bf16* GKb   = (__bf16*)alloc((size_t)128 * LDIM * 2);
    __bf16* GVb   = (__bf16*)alloc((size_t)128 * LDIM * 2);
    __bf16* localg= (__bf16*)alloc((size_t)BSROWS * DMODEL * 2);
    float*  grbuf = (float*) alloc((size_t)BSROWS * 16 * 4);
    __bf16* remb  = (__bf16*)alloc((size_t)BSROWS * LDIM * 2);
    __bf16* outpre = Kb; // alias: Kb is dead after local_attn

    cvt_f32_to_bf16<<<dim3((BSROWS * DMODEL / 4 + 255) / 256), 256, 0, stream>>>(
        x, xb, BSROWS * DMODEL / 4);
    dim3 tb(32, 8);
    transpose_cvt<<<dim3(32, 32), tb, 0, stream>>>(wq,   wqT,   DMODEL, DMODEL);
    transpose_cvt<<<dim3(32, 32), tb, 0, stream>>>(wk,   wkT,   DMODEL, DMODEL);
    transpose_cvt<<<dim3(32, 32), tb, 0, stream>>>(wv,   wvT,   DMODEL, DMODEL);
    transpose_cvt<<<dim3(32, 32), tb, 0, stream>>>(wout, woutT, DMODEL, DMODEL);
    transpose_cvt<<<dim3(32, 16), tb, 0, stream>>>(wgq,  wgqT,  DMODEL, LDIM);
    transpose_cvt<<<dim3(32, 16), tb, 0, stream>>>(wgk,  wgkT,  DMODEL, LDIM);
    transpose_cvt<<<dim3(32, 16), tb, 0, stream>>>(wgv,  wgvT,  DMODEL, LDIM);
    transpose_cvt<<<dim3(16, 32), tb, 0, stream>>>(rout, routT, LDIM, DMODEL);
    pool_x_kernel<<<dim3(4, 128), 256, 0, stream>>>(x, xpool);

    gemm_bf16<false, true><<<dim3(64, 8), 256, 0, stream>>>(xb, wqT, BSROWS, DMODEL, DMODEL, Qb, nullptr, nullptr, nullptr);
    gemm_bf16<false, true><<<dim3(64, 8), 256, 0, stream>>>(xb, wkT, BSROWS, DMODEL, DMODEL, Kb, nullptr, nullptr, nullptr);
    gemm_bf16<false, true><<<dim3(64, 8), 256, 0, stream>>>(xb, wvT, BSROWS, DMODEL, DMODEL, Vb, nullptr, nullptr, nullptr);
    gemm_bf16<false, true><<<dim3(64, 4), 256, 0, stream>>>(xb, wgqT, BSROWS, LDIM, DMODEL, GQb, nullptr, nullptr, nullptr);
    gemm_bf16<false, true><<<dim3(1, 4), 256, 0, stream>>>(xpool, wgkT, 128, LDIM, DMODEL, GKb, nullptr, nullptr, nullptr);
    gemm_bf16<false, true><<<dim3(1, 4), 256, 0, stream>>>(xpool, wgvT, 128, LDIM, DMODEL, GVb, nullptr, nullptr, nullptr);

    transpose_v_bf16<<<dim3(64, 16, 2), 256, 0, stream>>>(Vb, VtG);

    local_attn_mfma<<<dim3(16, 16, 2), 256, 0, stream>>>(Qb, Kb, VtG, glw, grw, localg, grbuf);
    latent_attn_mfma<<<dim3(16, 8, 2), 256, 0, stream>>>(GQb, GKb, GVb, remb);

    gemm_bf16<true, true><<<dim3(64, 8), 256, 0, stream>>>(remb, routT, BSROWS, DMODEL, LDIM, outpre, nullptr, localg, grbuf);
    gemm_bf16<false, false><<<dim3(64, 8), 256, 0, stream>>>(outpre, woutT, BSROWS, DMODEL, DMODEL, nullptr, (float*)d_out, nullptr, nullptr);
}

// Round 5
// 280.034 us; speedup vs baseline: 3.2588x; 1.1263x over previous
//
#include <hip/hip_runtime.h>

#define AS1 __attribute__((address_space(1)))
#define AS3 __attribute__((address_space(3)))

typedef float    f32x4  __attribute__((ext_vector_type(4)));
typedef __bf16   bf16x8 __attribute__((ext_vector_type(8)));
typedef __bf16   bf16x4 __attribute__((ext_vector_type(4)));
typedef unsigned int u32x4 __attribute__((ext_vector_type(4)));

static constexpr int SEQ = 4096, NBATCH = 2, DMODEL = 1024, NHEADS = 16, HDIM = 64;
static constexpr int LHEADS = 8, LDIM = 512, NLAT = 64, WIN = 256;
static constexpr int BSROWS = NBATCH * SEQ; // 8192
static constexpr int QKVN = 3584;           // fused [Q|K|V|GQ] column count
static constexpr int KOFF = 1024, VOFF = 2048, GQOFF = 3072;

// ---------------- f32 -> bf16 convert (vectorized) ----------------
__global__ __launch_bounds__(256) void cvt_f32_to_bf16(const float* __restrict__ in,
                                                       __bf16* __restrict__ out, int n4) {
    int i = blockIdx.x * 256 + threadIdx.x;
    if (i >= n4) return;
    f32x4 v = ((const f32x4*)in)[i];
    bf16x4 r;
    r[0] = (__bf16)v[0]; r[1] = (__bf16)v[1]; r[2] = (__bf16)v[2]; r[3] = (__bf16)v[3];
    ((bf16x4*)out)[i] = r;
}

// ---------------- transpose + convert: out[n*K+k] = (bf16)in[k*N+n] ----------------
__global__ void transpose_cvt(const float* __restrict__ in, __bf16* __restrict__ out,
                              int K, int N) {
    __shared__ float t[32][33];
    int k0 = blockIdx.x * 32, n0 = blockIdx.y * 32;
    int tx = threadIdx.x, ty = threadIdx.y; // (32, 8)
    #pragma unroll
    for (int i = ty; i < 32; i += 8) t[i][tx] = in[(size_t)(k0 + i) * N + n0 + tx];
    __syncthreads();
    #pragma unroll
    for (int i = ty; i < 32; i += 8) out[(size_t)(n0 + i) * K + k0 + tx] = (__bf16)t[tx][i];
}

// ---------------- bf16 transpose: Vt[b][c][s] = QKVG[b*S+s][VOFF+c] ----------------
__global__ __launch_bounds__(256) void transpose_v_bf16(const __bf16* __restrict__ V,
                                                        __bf16* __restrict__ Vt) {
    __shared__ __bf16 tl[64][65];
    int s0 = blockIdx.x * 64, c0 = blockIdx.y * 64, b = blockIdx.z;
    int tx = threadIdx.x & 63, ty = threadIdx.x >> 6;
    #pragma unroll
    for (int i = ty; i < 64; i += 4)
        tl[i][tx] = V[(size_t)(b * SEQ + s0 + i) * QKVN + VOFF + c0 + tx];
    __syncthreads();
    #pragma unroll
    for (int i = ty; i < 64; i += 4)
        Vt[(size_t)(b * DMODEL + c0 + i) * SEQ + s0 + tx] = tl[tx][i];
}

// ---------------- pool x over chunks of 64 rows -> bf16 [128][1024] ----------------
__global__ __launch_bounds__(256) void pool_x_kernel(const float* __restrict__ x,
                                                     __bf16* __restrict__ xpool) {
    int c  = blockIdx.x * 256 + threadIdx.x; // 0..1023
    int bn = blockIdx.y;                     // b*64+n
    const float* p = x + (size_t)bn * 64 * 1024 + c;
    float s = 0.f;
    #pragma unroll 8
    for (int j = 0; j < 64; ++j) s += p[(size_t)j * 1024];
    xpool[(size_t)bn * 1024 + c] = (__bf16)(s * 0.015625f);
}

// ---------------- bf16 MFMA GEMM: C[M,N] = A[M,K] @ Bt[N,K]^T ----------------
template <bool EPI, bool OUTBF>
__global__ __launch_bounds__(256) void gemm_bf16(const __bf16* __restrict__ A,
                                                 const __bf16* __restrict__ Bt,
                                                 int M, int N, int K,
                                                 __bf16* __restrict__ outb,
                                                 float* __restrict__ outf,
                                                 const __bf16* __restrict__ lcl,
                                                 const float* __restrict__ grb) {
    __shared__ alignas(16) __bf16 sA[128 * 64];
    __shared__ alignas(16) __bf16 sB[128 * 64];
    int t = threadIdx.x, w = t >> 6, l = t & 63;
    int m0 = blockIdx.x * 128, n0 = blockIdx.y * 128;
    int wr = w >> 1, wc = w & 1;
    int lr = l & 15, lk = (l >> 4) * 8;

    f32x4 zero = {0.f, 0.f, 0.f, 0.f};
    f32x4 acc[4][4];
    #pragma unroll
    for (int a = 0; a < 4; ++a)
        #pragma unroll
        for (int b2 = 0; b2 < 4; ++b2) acc[a][b2] = zero;

    for (int kt = 0; kt < K; kt += 64) {
        #pragma unroll
        for (int c = 0; c < 4; ++c) {
            int lin  = w * 64 + c * 256;
            int linl = lin + l;
            int row = linl >> 3, c8 = (linl & 7) * 8;
            __builtin_amdgcn_global_load_lds(
                (const AS1 void*)(A + (size_t)(m0 + row) * K + kt + c8),
                (AS3 void*)((char*)sA + (size_t)lin * 16), 16, 0, 0);
            __builtin_amdgcn_global_load_lds(
                (const AS1 void*)(Bt + (size_t)(n0 + row) * K + kt + c8),
                (AS3 void*)((char*)sB + (size_t)lin * 16), 16, 0, 0);
        }
        __syncthreads();
        #pragma unroll
        for (int ks = 0; ks < 2; ++ks) {
            bf16x8 av[4], bv[4];
            #pragma unroll
            for (int mi = 0; mi < 4; ++mi)
                av[mi] = *(const bf16x8*)(sA + (wr * 64 + mi * 16 + lr) * 64 + ks * 32 + lk);
            #pragma unroll
            for (int ni = 0; ni < 4; ++ni)
                bv[ni] = *(const bf16x8*)(sB + (wc * 64 + ni * 16 + lr) * 64 + ks * 32 + lk);
            #pragma unroll
            for (int mi = 0; mi < 4; ++mi)
                #pragma unroll
                for (int ni = 0; ni < 4; ++ni)
                    acc[mi][ni] = __builtin_amdgcn_mfma_f32_16x16x32_bf16(
                        av[mi], bv[ni], acc[mi][ni], 0, 0, 0);
        }
        __syncthreads();
    }

    int cr = (l >> 4) * 4, cc = l & 15;
    #pragma unroll
    for (int mi = 0; mi < 4; ++mi) {
        #pragma unroll
        for (int ni = 0; ni < 4; ++ni) {
            int col = n0 + wc * 64 + ni * 16 + cc;
            #pragma unroll
            for (int r = 0; r < 4; ++r) {
                int row = m0 + wr * 64 + mi * 16 + cr + r;
                float v = acc[mi][ni][r];
                if constexpr (EPI) {
                    v = (float)lcl[(size_t)row * 1024 + col] +
                        grb[(size_t)row * 16 + (col >> 6)] * v;
                }
                if constexpr (OUTBF) outb[(size_t)row * N + col] = (__bf16)v;
                else                 outf[(size_t)row * N + col] = v;
            }
        }
    }
}

// ---------------- local sliding-window attention, MFMA version ----------------
// Q,K from fused QKVG (stride QKVN); V^T fragments read DIRECT from global Vt
// (no sV LDS: per-block V slice is 64KB, L1/L2-resident; saves 64KB LDS ->
// 2 blocks/CU). LDS = sK 64K + sP 16K = 80K.
__global__ __launch_bounds__(256, 2) void local_attn_mfma(
    const __bf16* __restrict__ QKVG, const __bf16* __restrict__ Vt,
    const float* __restrict__ glw, const float* __restrict__ grw,
    __bf16* __restrict__ outl, float* __restrict__ grbuf) {
    int blk = blockIdx.x, h = blockIdx.y, b = blockIdx.z;
    int t = threadIdx.x, w = t >> 6, l = t & 63;
    int l15 = l & 15, l4 = l >> 4;

    __shared__ alignas(16) char sKb[512 * 128];   // K  [key 512][d 64] bf16, XOR-swz
    __shared__ alignas(16) char sPb[4 * 64 * 64]; // per-wave P [q 64][k 32] bf16, swz (row&3)<<4

    // Q fragments (B-operand)
    bf16x8 qf[4][2];
    long qbase = (long)b * SEQ + blk * 256 + 64 * w;
    #pragma unroll
    for (int qq = 0; qq < 4; ++qq)
        #pragma unroll
        for (int ks = 0; ks < 2; ++ks)
            qf[qq][ks] = *(const bf16x8*)(QKVG + (size_t)(qbase + qq * 16 + l15) * QKVN
                                          + h * 64 + ks * 32 + l4 * 8);

    // stage K rows (zero the invalid pad region for blk==0)
    long g0 = (long)b * SEQ + (long)(blk - 1) * WIN;
    #pragma unroll
    for (int rep = 0; rep < 16; ++rep) {
        int ci = rep * 256 + t;
        int row = ci >> 3, c8 = (ci & 7) * 8;
        u32x4 kv = {0u, 0u, 0u, 0u};
        if (!(blk == 0 && row < 256))
            kv = *(const u32x4*)(QKVG + (size_t)(g0 + row) * QKVN + KOFF + h * 64 + c8);
        *(u32x4*)(sKb + row * 128 + ((c8 * 2) ^ ((row & 7) << 4))) = kv;
    }

    // gate dot-products
    float dlp[4], drp[4];
    #pragma unroll
    for (int qq = 0; qq < 4; ++qq) {
        float dl = 0.f, dr = 0.f;
        #pragma unroll
        for (int ks = 0; ks < 2; ++ks) {
            const float* gp = glw + h * 64 + ks * 32 + l4 * 8;
            const float* rp = grw + h * 64 + ks * 32 + l4 * 8;
            #pragma unroll
            for (int j = 0; j < 8; ++j) {
                float qv = (float)qf[qq][ks][j];
                dl += qv * gp[j];
                dr += qv * rp[j];
            }
        }
        dlp[qq] = dl; drp[qq] = dr;
    }
    float glv[4], grv[4];
    #pragma unroll
    for (int qq = 0; qq < 4; ++qq) {
        float dl = dlp[qq] + __shfl_xor(dlp[qq], 16);
        dl += __shfl_xor(dl, 32);
        float dr = drp[qq] + __shfl_xor(drp[qq], 16);
        dr += __shfl_xor(dr, 32);
        glv[qq] = 1.f / (1.f + __expf(-dl));
        grv[qq] = 1.f / (1.f + __expf(-dr));
    }
    if (l4 == 0) {
        #pragma unroll
        for (int qq = 0; qq < 4; ++qq)
            grbuf[(size_t)(qbase + qq * 16 + l15) * 16 + h] = grv[qq];
    }
    __syncthreads();

    f32x4 zero = {0.f, 0.f, 0.f, 0.f};
    f32x4 acc[4][4];
    #pragma unroll
    for (int a = 0; a < 4; ++a)
        #pragma unroll
        for (int d = 0; d < 4; ++d) acc[a][d] = zero;
    float psum[4] = {0.f, 0.f, 0.f, 0.f};

    char* sPw = sPb + w * 4096;
    int nsteps = (w == 3) ? 10 : 11;
    int kk0 = 64 * w;
    const __bf16* vtb = Vt + (size_t)b * DMODEL * SEQ + (size_t)(h * 64) * SEQ;

    for (int stp = 0; stp < nsteps; ++stp) {
        int kk = kk0 + 32 * stp;
        f32x4 sacc[2][4];
        #pragma unroll
        for (int kt2 = 0; kt2 < 2; ++kt2) {
            int krow = kk + kt2 * 16 + l15;
            int swz = (krow & 7) << 4;
            bf16x8 af0 = *(const bf16x8*)(sKb + krow * 128 + ((l4 * 16) ^ swz));
            bf16x8 af1 = *(const bf16x8*)(sKb + krow * 128 + ((64 + l4 * 16) ^ swz));
            #pragma unroll
            for (int qq = 0; qq < 4; ++qq) {
                f32x4 s = __builtin_amdgcn_mfma_f32_16x16x32_bf16(af0, qf[qq][0], zero, 0, 0, 0);
                sacc[kt2][qq] = __builtin_amdgcn_mfma_f32_16x16x32_bf16(af1, qf[qq][1], s, 0, 0, 0);
            }
        }
        #pragma unroll
        for (int qq = 0; qq < 4; ++qq) {
            int qloc = 64 * w + qq * 16 + l15;
            int prow = qq * 16 + l15;
            #pragma unroll
            for (int kt2 = 0; kt2 < 2; ++kt2) {
                int jb = kk + kt2 * 16 + l4 * 4;
                bf16x4 pb;
                #pragma unroll
                for (int r = 0; r < 4; ++r) {
                    int jw = jb + r;
                    bool act = (jw > qloc) && (jw <= qloc + 256) && (blk > 0 || jw >= 256);
                    float pv = act ? __expf(sacc[kt2][qq][r] * 0.125f) : 0.f;
                    psum[qq] += pv;
                    pb[r] = (__bf16)pv;
                }
                *(bf16x4*)(sPw + prow * 64 + ((kt2 * 32 + l4 * 8) ^ ((prow & 3) << 4))) = pb;
            }
        }
        // PV: pa from per-wave LDS; bv DIRECT from global Vt (keys contiguous)
        int kglob = (blk - 1) * WIN + kk + l4 * 8;
        if (kglob < 0) kglob = 0;  // blk==0 invalid keys: P==0 exactly, value irrelevant
        bf16x8 pa[4], bv[4];
        #pragma unroll
        for (int qq = 0; qq < 4; ++qq) {
            int prow = qq * 16 + l15;
            pa[qq] = *(const bf16x8*)(sPw + prow * 64 + ((l4 * 16) ^ ((prow & 3) << 4)));
        }
        #pragma unroll
        for (int dt = 0; dt < 4; ++dt)
            bv[dt] = *(const bf16x8*)(vtb + (size_t)(dt * 16 + l15) * SEQ + kglob);
        #pragma unroll
        for (int qq = 0; qq < 4; ++qq)
            #pragma unroll
            for (int dt = 0; dt < 4; ++dt)
                acc[qq][dt] = __builtin_amdgcn_mfma_f32_16x16x32_bf16(pa[qq], bv[dt], acc[qq][dt], 0, 0, 0);
    }

    float cmb[4];
    #pragma unroll
    for (int qq = 0; qq < 4; ++qq) {
        float s = psum[qq] + __shfl_xor(psum[qq], 16);
        s += __shfl_xor(s, 32);
        cmb[qq] = glv[qq] / s;
    }
    #pragma unroll
    for (int qq = 0; qq < 4; ++qq) {
        #pragma unroll
        for (int r = 0; r < 4; ++r) {
            float sc = __shfl(cmb[qq], l4 * 4 + r, 64);
            size_t row = (size_t)(qbase + qq * 16 + l4 * 4 + r);
            __bf16* op = outl + row * DMODEL + h * 64 + l15;
            #pragma unroll
            for (int dt = 0; dt < 4; ++dt)
                op[dt * 16] = (__bf16)(acc[qq][dt][r] * sc);
        }
    }
}

// ---------------- latent (remote) attention, MFMA version (verified r4) ----------------
// GQ now read from fused QKVG at col GQOFF, stride QKVN.
__global__ __launch_bounds__(256, 1) void latent_attn_mfma(
    const __bf16* __restrict__ QKVG, const __bf16* __restrict__ GK,
    const __bf16* __restrict__ GV, __bf16* __restrict__ rem) {
    int sb = blockIdx.x, lh = blockIdx.y, b = blockIdx.z;
    int t = threadIdx.x, w = t >> 6, l = t & 63;
    int l15 = l & 15, l4 = l >> 4;

    __shared__ alignas(16) char sK[64 * 128];
    __shared__ alignas(16) char sVt[64 * 128];
    __shared__ alignas(16) char sPb[4 * 64 * 64];

    bf16x8 qf[4][2];
    long qbase = (long)b * SEQ + sb * 256 + 64 * w;
    #pragma unroll
    for (int qq = 0; qq < 4; ++qq)
        #pragma unroll
        for (int ks = 0; ks < 2; ++ks)
            qf[qq][ks] = *(const bf16x8*)(QKVG + (size_t)(qbase + qq * 16 + l15) * QKVN
                                          + GQOFF + lh * 64 + ks * 32 + l4 * 8);

    #pragma unroll
    for (int rep = 0; rep < 2; ++rep) {
        int ci = rep * 256 + t;
        int row = ci >> 3, c8 = (ci & 7) * 8;
        u32x4 kv = *(const u32x4*)(GK + (size_t)(b * 64 + row) * LDIM + lh * 64 + c8);
        *(u32x4*)(sK + row * 128 + ((c8 * 2) ^ ((row & 7) << 4))) = kv;
    }
    #pragma unroll
    for (int rep = 0; rep < 16; ++rep) {
        int idx = rep * 256 + t;
        int d = idx & 63, n = idx >> 6;
        __bf16 v = GV[(size_t)(b * 64 + n) * LDIM + lh * 64 + d];
        *(__bf16*)(sVt + d * 128 + ((n * 2) ^ ((d & 7) << 4))) = v;
    }
    __syncthreads();

    f32x4 zero = {0.f, 0.f, 0.f, 0.f};
    f32x4 acc[4][4];
    #pragma unroll
    for (int a = 0; a < 4; ++a)
        #pragma unroll
        for (int d = 0; d < 4; ++d) acc[a][d] = zero;
    float psum[4] = {0.f, 0.f, 0.f, 0.f};

    char* sPw = sPb + w * 4096;
    int qloc0 = sb * 256 + 64 * w;

    #pragma unroll
    for (int stp = 0; stp < 2; ++stp) {
        int kk = 32 * stp;
        f32x4 sacc[2][4];
        #pragma unroll
        for (int kt2 = 0; kt2 < 2; ++kt2) {
            int krow = kk + kt2 * 16 + l15;
            int swz = (krow & 7) << 4;
            bf16x8 af0 = *(const bf16x8*)(sK + krow * 128 + ((l4 * 16) ^ swz));
            bf16x8 af1 = *(const bf16x8*)(sK + krow * 128 + ((64 + l4 * 16) ^ swz));
            #pragma unroll
            for (int qq = 0; qq < 4; ++qq) {
                f32x4 s = __builtin_amdgcn_mfma_f32_16x16x32_bf16(af0, qf[qq][0], zero, 0, 0, 0);
                sacc[kt2][qq] = __builtin_amdgcn_mfma_f32_16x16x32_bf16(af1, qf[qq][1], s, 0, 0, 0);
            }
        }
        #pragma unroll
        for (int qq = 0; qq < 4; ++qq) {
            int qdv = (qloc0 + qq * 16 + l15) >> 6;
            int prow = qq * 16 + l15;
            #pragma unroll
            for (int kt2 = 0; kt2 < 2; ++kt2) {
                int nb = kk + kt2 * 16 + l4 * 4;
                bf16x4 pb;
                #pragma unroll
                for (int r = 0; r < 4; ++r) {
                    int n = nb + r;
                    float pv = (n <= qdv) ? __expf(sacc[kt2][qq][r] * 0.125f) : 0.f;
                    psum[qq] += pv;
                    pb[r] = (__bf16)pv;
                }
                *(bf16x4*)(sPw + prow * 64 + ((kt2 * 32 + l4 * 8) ^ ((prow & 3) << 4))) = pb;
            }
        }
        bf16x8 pa[4], bv[4];
        #pragma unroll
        for (int qq = 0; qq < 4; ++qq) {
            int prow = qq * 16 + l15;
            pa[qq] = *(const bf16x8*)(sPw + prow * 64 + ((l4 * 16) ^ ((prow & 3) << 4)));
        }
        #pragma unroll
        for (int dt = 0; dt < 4; ++dt) {
            int d = dt * 16 + l15;
            bv[dt] = *(const bf16x8*)(sVt + d * 128 + ((kk * 2 + l4 * 16) ^ ((d & 7) << 4)));
        }
        #pragma unroll
        for (int qq = 0; qq < 4; ++qq)
            #pragma unroll
            for (int dt = 0; dt < 4; ++dt)
                acc[qq][dt] = __builtin_amdgcn_mfma_f32_16x16x32_bf16(pa[qq], bv[dt], acc[qq][dt], 0, 0, 0);
    }

    float cmb[4];
    #pragma unroll
    for (int qq = 0; qq < 4; ++qq) {
        float s = psum[qq] + __shfl_xor(psum[qq], 16);
        s += __shfl_xor(s, 32);
        cmb[qq] = 1.f / s;
    }
    #pragma unroll
    for (int qq = 0; qq < 4; ++qq) {
        #pragma unroll
        for (int r = 0; r < 4; ++r) {
            float sc = __shfl(cmb[qq], l4 * 4 + r, 64);
            size_t row = (size_t)(qbase + qq * 16 + l4 * 4 + r);
            __bf16* op = rem + row * LDIM + lh * 64 + l15;
            #pragma unroll
            for (int dt = 0; dt < 4; ++dt)
                op[dt * 16] = (__bf16)(acc[qq][dt][r] * sc);
        }
    }
}

// ---------------- host launcher ----------------
extern "C" void kernel_launch(void* const* d_in, const int* in_sizes, int n_in,
                              void* d_out, int out_size, void* d_ws, size_t ws_size,
                              hipStream_t stream) {
    (void)in_sizes; (void)n_in; (void)out_size; (void)ws_size;
    const float* x    = (const float*)d_in[0];
    const float* wq   = (const float*)d_in[1];
    const float* wk   = (const float*)d_in[2];
    const float* wv   = (const float*)d_in[3];
    const float* wgq  = (const float*)d_in[4];
    const float* wgk  = (const float*)d_in[5];
    const float* wgv  = (const float*)d_in[6];
    const float* rout = (const float*)d_in[7];
    const float* glw  = (const float*)d_in[8];
    const float* grw  = (const float*)d_in[9];
    const float* wout = (const float*)d_in[10];

    char* p = (char*)d_ws;
    auto alloc = [&](size_t bytes) {
        char* r = p;
        p += (bytes + 255) & ~(size_t)255;
        return r;
    };
    __bf16* xb    = (__bf16*)alloc((size_t)BSROWS * DMODEL * 2);
    __bf16* QKVG  = (__bf16*)alloc((size_t)BSROWS * QKVN * 2);
    __bf16* VtG   = (__bf16*)alloc((size_t)BSROWS * DMODEL * 2);
    __bf16* wcatT = (__bf16*)alloc((size_t)QKVN * DMODEL * 2);  // [wqT|wkT|wvT|wgqT]
    __bf16* woutT = (__bf16*)alloc((size_t)DMODEL * DMODEL * 2);
    __bf16* wgkT  = (__bf16*)alloc((size_t)LDIM * DMODEL * 2);
    __bf16* wgvT  = (__bf16*)alloc((size_t)LDIM * DMODEL * 2);
    __bf16* routT = (__bf16*)alloc((size_t)DMODEL * LDIM * 2);
    __bf16* xpool = (__bf16*)alloc((size_t)128 * DMODEL * 2);
    __bf16* GKb   = (__bf16*)alloc((size_t)128 * LDIM * 2);
    __bf16* GVb   = (__bf16*)alloc((size_t)128 * LDIM * 2);
    __bf16* localg= (__bf16*)alloc((size_t)BSROWS * DMODEL * 2);
    float*  grbuf = (float*) alloc((size_t)BSROWS * 16 * 4);
    __bf16* remb  = (__bf16*)alloc((size_t)BSROWS * LDIM * 2);
    __bf16* outpre = xb; // alias: xb is dead after the fused projection GEMM

    cvt_f32_to_bf16<<<dim3((BSROWS * DMODEL / 4 + 255) / 256), 256, 0, stream>>>(
        x, xb, BSROWS * DMODEL / 4);
    dim3 tb(32, 8);
    transpose_cvt<<<dim3(32, 32), tb, 0, stream>>>(wq,   wcatT,                  DMODEL, DMODEL);
    transpose_cvt<<<dim3(32, 32), tb, 0, stream>>>(wk,   wcatT + 1024 * DMODEL,  DMODEL, DMODEL);
    transpose_cvt<<<dim3(32, 32), tb, 0, stream>>>(wv,   wcatT + 2048 * DMODEL,  DMODEL, DMODEL);
    transpose_cvt<<<dim3(32, 16), tb, 0, stream>>>(wgq,  wcatT + 3072 * DMODEL,  DMODEL, LDIM);
    transpose_cvt<<<dim3(32, 32), tb, 0, stream>>>(wout, woutT, DMODEL, DMODEL);
    transpose_cvt<<<dim3(32, 16), tb, 0, stream>>>(wgk,  wgkT,  DMODEL, LDIM);
    transpose_cvt<<<dim3(32, 16), tb, 0, stream>>>(wgv,  wgvT,  DMODEL, LDIM);
    transpose_cvt<<<dim3(16, 32), tb, 0, stream>>>(rout, routT, LDIM, DMODEL);
    pool_x_kernel<<<dim3(4, 128), 256, 0, stream>>>(x, xpool);

    // fused [Q|K|V|GQ] projection: M=8192, N=3584, K=1024
    gemm_bf16<false, true><<<dim3(64, 28), 256, 0, stream>>>(xb, wcatT, BSROWS, QKVN, DMODEL, QKVG, nullptr, nullptr, nullptr);
    gemm_bf16<false, true><<<dim3(1, 4), 256, 0, stream>>>(xpool, wgkT, 128, LDIM, DMODEL, GKb, nullptr, nullptr, nullptr);
    gemm_bf16<false, true><<<dim3(1, 4), 256, 0, stream>>>(xpool, wgvT, 128, LDIM, DMODEL, GVb, nullptr, nullptr, nullptr);

    transpose_v_bf16<<<dim3(64, 16, 2), 256, 0, stream>>>(QKVG, VtG);

    local_attn_mfma<<<dim3(16, 16, 2), 256, 0, stream>>>(QKVG, VtG, glw, grw, localg, grbuf);
    latent_attn_mfma<<<dim3(16, 8, 2), 256, 0, stream>>>(QKVG, GKb, GVb, remb);

    gemm_bf16<true, true><<<dim3(64, 8), 256, 0, stream>>>(remb, routT, BSROWS, DMODEL, LDIM, outpre, nullptr, localg, grbuf);
    gemm_bf16<false, false><<<dim3(64, 8), 256, 0, stream>>>(outpre, woutT, BSROWS, DMODEL, DMODEL, nullptr, (float*)d_out, nullptr, nullptr);
}

// Round 6
// 253.649 us; speedup vs baseline: 3.5978x; 1.1040x over previous
//
#include <hip/hip_runtime.h>

#define AS1 __attribute__((address_space(1)))
#define AS3 __attribute__((address_space(3)))

typedef float    f32x4  __attribute__((ext_vector_type(4)));
typedef __bf16   bf16x8 __attribute__((ext_vector_type(8)));
typedef __bf16   bf16x4 __attribute__((ext_vector_type(4)));
typedef unsigned int u32x4 __attribute__((ext_vector_type(4)));

static constexpr int SEQ = 4096, NBATCH = 2, DMODEL = 1024, NHEADS = 16, HDIM = 64;
static constexpr int LHEADS = 8, LDIM = 512, NLAT = 64, WIN = 256;
static constexpr int BSROWS = NBATCH * SEQ; // 8192
static constexpr int QKVN = 3584;           // fused [Q|K|V|GQ] column count
static constexpr int KOFF = 1024, VOFF = 2048, GQOFF = 3072;

// ---------------- f32 -> bf16 convert (vectorized) ----------------
__global__ __launch_bounds__(256) void cvt_f32_to_bf16(const float* __restrict__ in,
                                                       __bf16* __restrict__ out, int n4) {
    int i = blockIdx.x * 256 + threadIdx.x;
    if (i >= n4) return;
    f32x4 v = ((const f32x4*)in)[i];
    bf16x4 r;
    r[0] = (__bf16)v[0]; r[1] = (__bf16)v[1]; r[2] = (__bf16)v[2]; r[3] = (__bf16)v[3];
    ((bf16x4*)out)[i] = r;
}

// ---------------- all 8 weight transposes in ONE launch ----------------
struct TJ { const float* in; __bf16* out; int K; int N; };
struct TJ8 { TJ j[8]; };
__global__ void transpose_cvt_all(TJ8 jobs) {
    TJ jb = jobs.j[blockIdx.z];
    int k0 = blockIdx.x * 32, n0 = blockIdx.y * 32;
    if (k0 >= jb.K || n0 >= jb.N) return;
    __shared__ float tbuf[32][33];
    int tx = threadIdx.x, ty = threadIdx.y; // (32, 8)
    #pragma unroll
    for (int i = ty; i < 32; i += 8) tbuf[i][tx] = jb.in[(size_t)(k0 + i) * jb.N + n0 + tx];
    __syncthreads();
    #pragma unroll
    for (int i = ty; i < 32; i += 8) jb.out[(size_t)(n0 + i) * jb.K + k0 + tx] = (__bf16)tbuf[tx][i];
}

// ---------------- bf16 transpose: Vt[b][c][s] = QKVG[b*S+s][VOFF+c] ----------------
__global__ __launch_bounds__(256) void transpose_v_bf16(const __bf16* __restrict__ V,
                                                        __bf16* __restrict__ Vt) {
    __shared__ __bf16 tl[64][65];
    int s0 = blockIdx.x * 64, c0 = blockIdx.y * 64, b = blockIdx.z;
    int tx = threadIdx.x & 63, ty = threadIdx.x >> 6;
    #pragma unroll
    for (int i = ty; i < 64; i += 4)
        tl[i][tx] = V[(size_t)(b * SEQ + s0 + i) * QKVN + VOFF + c0 + tx];
    __syncthreads();
    #pragma unroll
    for (int i = ty; i < 64; i += 4)
        Vt[(size_t)(b * DMODEL + c0 + i) * SEQ + s0 + tx] = tl[tx][i];
}

// ---------------- pool x over chunks of 64 rows -> bf16 [128][1024] ----------------
__global__ __launch_bounds__(256) void pool_x_kernel(const float* __restrict__ x,
                                                     __bf16* __restrict__ xpool) {
    int c  = blockIdx.x * 256 + threadIdx.x;
    int bn = blockIdx.y;
    const float* p = x + (size_t)bn * 64 * 1024 + c;
    float s = 0.f;
    #pragma unroll 8
    for (int j = 0; j < 64; ++j) s += p[(size_t)j * 1024];
    xpool[(size_t)bn * 1024 + c] = (__bf16)(s * 0.015625f);
}

// ---------------- m97-style 128x128 GEMM (kept for small/N=1024 GEMMs) ----------------
template <bool EPI, bool OUTBF>
__global__ __launch_bounds__(256) void gemm_bf16(const __bf16* __restrict__ A,
                                                 const __bf16* __restrict__ Bt,
                                                 int M, int N, int K,
                                                 __bf16* __restrict__ outb,
                                                 float* __restrict__ outf,
                                                 const __bf16* __restrict__ lcl,
                                                 const float* __restrict__ grb) {
    __shared__ alignas(16) __bf16 sA[128 * 64];
    __shared__ alignas(16) __bf16 sB[128 * 64];
    int t = threadIdx.x, w = t >> 6, l = t & 63;
    int m0 = blockIdx.x * 128, n0 = blockIdx.y * 128;
    int wr = w >> 1, wc = w & 1;
    int lr = l & 15, lk = (l >> 4) * 8;

    f32x4 zero = {0.f, 0.f, 0.f, 0.f};
    f32x4 acc[4][4];
    #pragma unroll
    for (int a = 0; a < 4; ++a)
        #pragma unroll
        for (int b2 = 0; b2 < 4; ++b2) acc[a][b2] = zero;

    for (int kt = 0; kt < K; kt += 64) {
        #pragma unroll
        for (int c = 0; c < 4; ++c) {
            int lin  = w * 64 + c * 256;
            int linl = lin + l;
            int row = linl >> 3, c8 = (linl & 7) * 8;
            __builtin_amdgcn_global_load_lds(
                (const AS1 void*)(A + (size_t)(m0 + row) * K + kt + c8),
                (AS3 void*)((char*)sA + (size_t)lin * 16), 16, 0, 0);
            __builtin_amdgcn_global_load_lds(
                (const AS1 void*)(Bt + (size_t)(n0 + row) * K + kt + c8),
                (AS3 void*)((char*)sB + (size_t)lin * 16), 16, 0, 0);
        }
        __syncthreads();
        #pragma unroll
        for (int ks = 0; ks < 2; ++ks) {
            bf16x8 av[4], bv[4];
            #pragma unroll
            for (int mi = 0; mi < 4; ++mi)
                av[mi] = *(const bf16x8*)(sA + (wr * 64 + mi * 16 + lr) * 64 + ks * 32 + lk);
            #pragma unroll
            for (int ni = 0; ni < 4; ++ni)
                bv[ni] = *(const bf16x8*)(sB + (wc * 64 + ni * 16 + lr) * 64 + ks * 32 + lk);
            #pragma unroll
            for (int mi = 0; mi < 4; ++mi)
                #pragma unroll
                for (int ni = 0; ni < 4; ++ni)
                    acc[mi][ni] = __builtin_amdgcn_mfma_f32_16x16x32_bf16(
                        av[mi], bv[ni], acc[mi][ni], 0, 0, 0);
        }
        __syncthreads();
    }

    int cr = (l >> 4) * 4, cc = l & 15;
    #pragma unroll
    for (int mi = 0; mi < 4; ++mi) {
        #pragma unroll
        for (int ni = 0; ni < 4; ++ni) {
            int col = n0 + wc * 64 + ni * 16 + cc;
            #pragma unroll
            for (int r = 0; r < 4; ++r) {
                int row = m0 + wr * 64 + mi * 16 + cr + r;
                float v = acc[mi][ni][r];
                if constexpr (EPI) {
                    v = (float)lcl[(size_t)row * 1024 + col] +
                        grb[(size_t)row * 16 + (col >> 6)] * v;
                }
                if constexpr (OUTBF) outb[(size_t)row * N + col] = (__bf16)v;
                else                 outf[(size_t)row * N + col] = v;
            }
        }
    }
}

// ---------------- 256x256 8-phase GEMM (T2+T3+T4+T5), NT even, dims % 256 == 0 ----------------
// 512 threads = 8 waves (wm=w>>2, wn=w&3); per-wave out 128x64; BK=64; LDS 128KB (2 bufs).
// st_16x32 swizzle: byte ^= ((byte>>9)&1)<<5 — applied via pre-swizzled global source on
// stage (gload_lds writes linearly) and XOR on ds_read (both-sides involution).
// Stage schedule (freed-region proof in session notes): P1:Ao(t+1) P2:B0(t+1) P3:B1(t+1)
// P4:Ae(t+2) P5:Ao(t+2) P6:B0(t+2) P7:B1(t+2) P8:Ae(t+3); counted vmcnt(2) at P4/P8 only.
#define BAR() do { __builtin_amdgcn_sched_barrier(0); __builtin_amdgcn_s_barrier(); \
                   __builtin_amdgcn_sched_barrier(0); } while (0)
#define LGK0() do { asm volatile("s_waitcnt lgkmcnt(0)" ::: "memory"); \
                    __builtin_amdgcn_sched_barrier(0); } while (0)
#define VMC(n) do { asm volatile("s_waitcnt vmcnt(" #n ")" ::: "memory"); \
                    __builtin_amdgcn_sched_barrier(0); } while (0)
#define STG(gp, regionbase, rowbase, ktc) do { \
    int row_ = (rowbase) + (t >> 3); \
    int ts_ = t ^ (((t >> 5) & 1) << 1); \
    __builtin_amdgcn_global_load_lds( \
        (const AS1 void*)((gp) + (size_t)row_ * K + (ktc) + (ts_ & 7) * 8), \
        (AS3 void*)(lds + (regionbase) + (rowbase) * 128 + w * 1024), 16, 0, 0); \
} while (0)
#define LOADA(buf, qm) do { \
    _Pragma("unroll") for (int ai_ = 0; ai_ < 4; ++ai_) \
    _Pragma("unroll") for (int ks_ = 0; ks_ < 2; ++ks_) \
        a[ai_][ks_] = *(const bf16x8*)(lds + ((((buf) * 65536) + \
            (wm * 128 + (qm) * 64 + ai_ * 16 + l15) * 128 + ks_ * 64 + l4 * 16) ^ rswz)); \
} while (0)
#define LOADB2(buf, half) do { \
    _Pragma("unroll") for (int j_ = 0; j_ < 2; ++j_) \
    _Pragma("unroll") for (int ks_ = 0; ks_ < 2; ++ks_) \
        b2[j_][ks_] = *(const bf16x8*)(lds + ((((buf) * 65536 + 32768) + \
            (wn * 64 + ((half) * 2 + j_) * 16 + l15) * 128 + ks_ * 64 + l4 * 16) ^ rswz)); \
} while (0)
#define MFMA_PH(qm, half) do { \
    __builtin_amdgcn_s_setprio(1); \
    _Pragma("unroll") for (int ai_ = 0; ai_ < 4; ++ai_) \
    _Pragma("unroll") for (int j_ = 0; j_ < 2; ++j_) { \
        f32x4 c_ = acc[(qm) * 4 + ai_][(half) * 2 + j_]; \
        c_ = __builtin_amdgcn_mfma_f32_16x16x32_bf16(a[ai_][0], b2[j_][0], c_, 0, 0, 0); \
        c_ = __builtin_amdgcn_mfma_f32_16x16x32_bf16(a[ai_][1], b2[j_][1], c_, 0, 0, 0); \
        acc[(qm) * 4 + ai_][(half) * 2 + j_] = c_; \
    } \
    __builtin_amdgcn_s_setprio(0); \
} while (0)

__global__ __launch_bounds__(512, 2) void gemm256_bf16(
    const __bf16* __restrict__ A, const __bf16* __restrict__ Bt,
    int M, int N, int K, __bf16* __restrict__ outb) {
    __shared__ char lds[131072];
    const int t = threadIdx.x, w = t >> 6, l = t & 63;
    const int wm = w >> 2, wn = w & 3;
    const int l15 = l & 15, l4 = l >> 4;
    const int m0 = blockIdx.x * 256, n0 = blockIdx.y * 256;
    const int NT = K >> 6;
    const int rswz = ((l15 >> 2) & 1) << 5;

    f32x4 acc[8][4];
    #pragma unroll
    for (int i = 0; i < 8; ++i)
        #pragma unroll
        for (int j = 0; j < 4; ++j) acc[i][j] = (f32x4){0.f, 0.f, 0.f, 0.f};
    bf16x8 a[4][2], b2[2][2];

    const __bf16* Ab = A + (size_t)m0 * K;
    const __bf16* Bb = Bt + (size_t)n0 * K;

    // prologue: tile 0 -> buf0 (Ae,Ao,B0,B1), then Ae(1) -> buf1 (kept in flight)
    STG(Ab, 0, 0, 0);        STG(Ab, 0, 128, 0);
    STG(Ab, 0, 64, 0);       STG(Ab, 0, 192, 0);
    STG(Bb, 32768, 0, 0);    STG(Bb, 32768, 64, 0);
    STG(Bb, 32768, 128, 0);  STG(Bb, 32768, 192, 0);
    STG(Ab, 65536, 0, 64);   STG(Ab, 65536, 128, 64);
    VMC(2); BAR();

    int it = 0;
    for (; it + 3 < NT; it += 2) {
        const int kt1 = (it + 1) << 6, kt2 = (it + 2) << 6, kt3 = (it + 3) << 6;
        // P1
        LOADA(0, 0); LOADB2(0, 0);
        STG(Ab, 65536, 64, kt1); STG(Ab, 65536, 192, kt1);
        BAR(); LGK0(); MFMA_PH(0, 0); BAR();
        // P2
        LOADB2(0, 1);
        STG(Bb, 98304, 0, kt1); STG(Bb, 98304, 64, kt1);
        BAR(); LGK0(); MFMA_PH(0, 1); BAR();
        // P3
        LOADA(0, 1); LOADB2(0, 0);
        STG(Bb, 98304, 128, kt1); STG(Bb, 98304, 192, kt1);
        BAR(); LGK0(); MFMA_PH(1, 0); BAR();
        // P4
        LOADB2(0, 1);
        STG(Ab, 0, 0, kt2); STG(Ab, 0, 128, kt2);
        BAR(); LGK0(); MFMA_PH(1, 1); VMC(2); BAR();
        // P5
        LOADA(1, 0); LOADB2(1, 0);
        STG(Ab, 0, 64, kt2); STG(Ab, 0, 192, kt2);
        BAR(); LGK0(); MFMA_PH(0, 0); BAR();
        // P6
        LOADB2(1, 1);
        STG(Bb, 32768, 0, kt2); STG(Bb, 32768, 64, kt2);
        BAR(); LGK0(); MFMA_PH(0, 1); BAR();
        // P7
        LOADA(1, 1); LOADB2(1, 0);
        STG(Bb, 32768, 128, kt2); STG(Bb, 32768, 192, kt2);
        BAR(); LGK0(); MFMA_PH(1, 0); BAR();
        // P8
        LOADB2(1, 1);
        STG(Ab, 65536, 0, kt3); STG(Ab, 65536, 128, kt3);
        BAR(); LGK0(); MFMA_PH(1, 1); VMC(2); BAR();
    }
    // final iteration (t = NT-2, t+1 = NT-1): stage only t+1 (P1-P3), drain at P4
    {
        const int kt1 = (it + 1) << 6;
        LOADA(0, 0); LOADB2(0, 0);
        STG(Ab, 65536, 64, kt1); STG(Ab, 65536, 192, kt1);
        BAR(); LGK0(); MFMA_PH(0, 0); BAR();
        LOADB2(0, 1);
        STG(Bb, 98304, 0, kt1); STG(Bb, 98304, 64, kt1);
        BAR(); LGK0(); MFMA_PH(0, 1); BAR();
        LOADA(0, 1); LOADB2(0, 0);
        STG(Bb, 98304, 128, kt1); STG(Bb, 98304, 192, kt1);
        BAR(); LGK0(); MFMA_PH(1, 0); BAR();
        LOADB2(0, 1);
        BAR(); LGK0(); MFMA_PH(1, 1); VMC(0); BAR();
        LOADA(1, 0); LOADB2(1, 0);
        BAR(); LGK0(); MFMA_PH(0, 0); BAR();
        LOADB2(1, 1);
        BAR(); LGK0(); MFMA_PH(0, 1); BAR();
        LOADA(1, 1); LOADB2(1, 0);
        BAR(); LGK0(); MFMA_PH(1, 0); BAR();
        LOADB2(1, 1);
        LGK0(); MFMA_PH(1, 1);
    }

    // epilogue (same verified C/D mapping as gemm_bf16)
    int cr = l4 * 4, cc = l15;
    #pragma unroll
    for (int mi = 0; mi < 8; ++mi) {
        #pragma unroll
        for (int ni = 0; ni < 4; ++ni) {
            int col = n0 + wn * 64 + ni * 16 + cc;
            #pragma unroll
            for (int r = 0; r < 4; ++r) {
                int row = m0 + wm * 128 + mi * 16 + cr + r;
                outb[(size_t)row * N + col] = (__bf16)acc[mi][ni][r];
            }
        }
    }
}
#undef BAR
#undef LGK0
#undef VMC
#undef STG
#undef LOADA
#undef LOADB2
#undef MFMA_PH

// ---------------- local sliding-window attention, MFMA (verified r5) ----------------
__global__ __launch_bounds__(256, 2) void local_attn_mfma(
    const __bf16* __restrict__ QKVG, const __bf16* __restrict__ Vt,
    const float* __restrict__ glw, const float* __restrict__ grw,
    __bf16* __restrict__ outl, float* __restrict__ grbuf) {
    int blk = blockIdx.x, h = blockIdx.y, b = blockIdx.z;
    int t = threadIdx.x, w = t >> 6, l = t & 63;
    int l15 = l & 15, l4 = l >> 4;

    __shared__ alignas(16) char sKb[512 * 128];
    __shared__ alignas(16) char sPb[4 * 64 * 64];

    bf16x8 qf[4][2];
    long qbase = (long)b * SEQ + blk * 256 + 64 * w;
    #pragma unroll
    for (int qq = 0; qq < 4; ++qq)
        #pragma unroll
        for (int ks = 0; ks < 2; ++ks)
            qf[qq][ks] = *(const bf16x8*)(QKVG + (size_t)(qbase + qq * 16 + l15) * QKVN
                                          + h * 64 + ks * 32 + l4 * 8);

    long g0 = (long)b * SEQ + (long)(blk - 1) * WIN;
    #pragma unroll
    for (int rep = 0; rep < 16; ++rep) {
        int ci = rep * 256 + t;
        int row = ci >> 3, c8 = (ci & 7) * 8;
        u32x4 kv = {0u, 0u, 0u, 0u};
        if (!(blk == 0 && row < 256))
            kv = *(const u32x4*)(QKVG + (size_t)(g0 + row) * QKVN + KOFF + h * 64 + c8);
        *(u32x4*)(sKb + row * 128 + ((c8 * 2) ^ ((row & 7) << 4))) = kv;
    }

    float dlp[4], drp[4];
    #pragma unroll
    for (int qq = 0; qq < 4; ++qq) {
        float dl = 0.f, dr = 0.f;
        #pragma unroll
        for (int ks = 0; ks < 2; ++ks) {
            const float* gp = glw + h * 64 + ks * 32 + l4 * 8;
            const float* rp = grw + h * 64 + ks * 32 + l4 * 8;
            #pragma unroll
            for (int j = 0; j < 8; ++j) {
                float qv = (float)qf[qq][ks][j];
                dl += qv * gp[j];
                dr += qv * rp[j];
            }
        }
        dlp[qq] = dl; drp[qq] = dr;
    }
    float glv[4], grv[4];
    #pragma unroll
    for (int qq = 0; qq < 4; ++qq) {
        float dl = dlp[qq] + __shfl_xor(dlp[qq], 16);
        dl += __shfl_xor(dl, 32);
        float dr = drp[qq] + __shfl_xor(drp[qq], 16);
        dr += __shfl_xor(dr, 32);
        glv[qq] = 1.f / (1.f + __expf(-dl));
        grv[qq] = 1.f / (1.f + __expf(-dr));
    }
    if (l4 == 0) {
        #pragma unroll
        for (int qq = 0; qq < 4; ++qq)
            grbuf[(size_t)(qbase + qq * 16 + l15) * 16 + h] = grv[qq];
    }
    __syncthreads();

    f32x4 zero = {0.f, 0.f, 0.f, 0.f};
    f32x4 acc[4][4];
    #pragma unroll
    for (int a = 0; a < 4; ++a)
        #pragma unroll
        for (int d = 0; d < 4; ++d) acc[a][d] = zero;
    float psum[4] = {0.f, 0.f, 0.f, 0.f};

    char* sPw = sPb + w * 4096;
    int nsteps = (w == 3) ? 10 : 11;
    int kk0 = 64 * w;
    const __bf16* vtb = Vt + (size_t)b * DMODEL * SEQ + (size_t)(h * 64) * SEQ;

    for (int stp = 0; stp < nsteps; ++stp) {
        int kk = kk0 + 32 * stp;
        f32x4 sacc[2][4];
        #pragma unroll
        for (int kt2 = 0; kt2 < 2; ++kt2) {
            int krow = kk + kt2 * 16 + l15;
            int swz = (krow & 7) << 4;
            bf16x8 af0 = *(const bf16x8*)(sKb + krow * 128 + ((l4 * 16) ^ swz));
            bf16x8 af1 = *(const bf16x8*)(sKb + krow * 128 + ((64 + l4 * 16) ^ swz));
            #pragma unroll
            for (int qq = 0; qq < 4; ++qq) {
                f32x4 s = __builtin_amdgcn_mfma_f32_16x16x32_bf16(af0, qf[qq][0], zero, 0, 0, 0);
                sacc[kt2][qq] = __builtin_amdgcn_mfma_f32_16x16x32_bf16(af1, qf[qq][1], s, 0, 0, 0);
            }
        }
        #pragma unroll
        for (int qq = 0; qq < 4; ++qq) {
            int qloc = 64 * w + qq * 16 + l15;
            int prow = qq * 16 + l15;
            #pragma unroll
            for (int kt2 = 0; kt2 < 2; ++kt2) {
                int jb = kk + kt2 * 16 + l4 * 4;
                bf16x4 pb;
                #pragma unroll
                for (int r = 0; r < 4; ++r) {
                    int jw = jb + r;
                    bool act = (jw > qloc) && (jw <= qloc + 256) && (blk > 0 || jw >= 256);
                    float pv = act ? __expf(sacc[kt2][qq][r] * 0.125f) : 0.f;
                    psum[qq] += pv;
                    pb[r] = (__bf16)pv;
                }
                *(bf16x4*)(sPw + prow * 64 + ((kt2 * 32 + l4 * 8) ^ ((prow & 3) << 4))) = pb;
            }
        }
        int kglob = (blk - 1) * WIN + kk + l4 * 8;
        if (kglob < 0) kglob = 0;
        bf16x8 pa[4], bv[4];
        #pragma unroll
        for (int qq = 0; qq < 4; ++qq) {
            int prow = qq * 16 + l15;
            pa[qq] = *(const bf16x8*)(sPw + prow * 64 + ((l4 * 16) ^ ((prow & 3) << 4)));
        }
        #pragma unroll
        for (int dt = 0; dt < 4; ++dt)
            bv[dt] = *(const bf16x8*)(vtb + (size_t)(dt * 16 + l15) * SEQ + kglob);
        #pragma unroll
        for (int qq = 0; qq < 4; ++qq)
            #pragma unroll
            for (int dt = 0; dt < 4; ++dt)
                acc[qq][dt] = __builtin_amdgcn_mfma_f32_16x16x32_bf16(pa[qq], bv[dt], acc[qq][dt], 0, 0, 0);
    }

    float cmb[4];
    #pragma unroll
    for (int qq = 0; qq < 4; ++qq) {
        float s = psum[qq] + __shfl_xor(psum[qq], 16);
        s += __shfl_xor(s, 32);
        cmb[qq] = glv[qq] / s;
    }
    #pragma unroll
    for (int qq = 0; qq < 4; ++qq) {
        #pragma unroll
        for (int r = 0; r < 4; ++r) {
            float sc = __shfl(cmb[qq], l4 * 4 + r, 64);
            size_t row = (size_t)(qbase + qq * 16 + l4 * 4 + r);
            __bf16* op = outl + row * DMODEL + h * 64 + l15;
            #pragma unroll
            for (int dt = 0; dt < 4; ++dt)
                op[dt * 16] = (__bf16)(acc[qq][dt][r] * sc);
        }
    }
}

// ---------------- latent (remote) attention, MFMA (verified r4/r5) ----------------
__global__ __launch_bounds__(256, 1) void latent_attn_mfma(
    const __bf16* __restrict__ QKVG, const __bf16* __restrict__ GK,
    const __bf16* __restrict__ GV, __bf16* __restrict__ rem) {
    int sb = blockIdx.x, lh = blockIdx.y, b = blockIdx.z;
    int t = threadIdx.x, w = t >> 6, l = t & 63;
    int l15 = l & 15, l4 = l >> 4;

    __shared__ alignas(16) char sK[64 * 128];
    __shared__ alignas(16) char sVt[64 * 128];
    __shared__ alignas(16) char sPb[4 * 64 * 64];

    bf16x8 qf[4][2];
    long qbase = (long)b * SEQ + sb * 256 + 64 * w;
    #pragma unroll
    for (int qq = 0; qq < 4; ++qq)
        #pragma unroll
        for (int ks = 0; ks < 2; ++ks)
            qf[qq][ks] = *(const bf16x8*)(QKVG + (size_t)(qbase + qq * 16 + l15) * QKVN
                                          + GQOFF + lh * 64 + ks * 32 + l4 * 8);

    #pragma unroll
    for (int rep = 0; rep < 2; ++rep) {
        int ci = rep * 256 + t;
        int row = ci >> 3, c8 = (ci & 7) * 8;
        u32x4 kv = *(const u32x4*)(GK + (size_t)(b * 64 + row) * LDIM + lh * 64 + c8);
        *(u32x4*)(sK + row * 128 + ((c8 * 2) ^ ((row & 7) << 4))) = kv;
    }
    #pragma unroll
    for (int rep = 0; rep < 16; ++rep) {
        int idx = rep * 256 + t;
        int d = idx & 63, n = idx >> 6;
        __bf16 v = GV[(size_t)(b * 64 + n) * LDIM + lh * 64 + d];
        *(__bf16*)(sVt + d * 128 + ((n * 2) ^ ((d & 7) << 4))) = v;
    }
    __syncthreads();

    f32x4 zero = {0.f, 0.f, 0.f, 0.f};
    f32x4 acc[4][4];
    #pragma unroll
    for (int a = 0; a < 4; ++a)
        #pragma unroll
        for (int d = 0; d < 4; ++d) acc[a][d] = zero;
    float psum[4] = {0.f, 0.f, 0.f, 0.f};

    char* sPw = sPb + w * 4096;
    int qloc0 = sb * 256 + 64 * w;

    #pragma unroll
    for (int stp = 0; stp < 2; ++stp) {
        int kk = 32 * stp;
        f32x4 sacc[2][4];
        #pragma unroll
        for (int kt2 = 0; kt2 < 2; ++kt2) {
            int krow = kk + kt2 * 16 + l15;
            int swz = (krow & 7) << 4;
            bf16x8 af0 = *(const bf16x8*)(sK + krow * 128 + ((l4 * 16) ^ swz));
            bf16x8 af1 = *(const bf16x8*)(sK + krow * 128 + ((64 + l4 * 16) ^ swz));
            #pragma unroll
            for (int qq = 0; qq < 4; ++qq) {
                f32x4 s = __builtin_amdgcn_mfma_f32_16x16x32_bf16(af0, qf[qq][0], zero, 0, 0, 0);
                sacc[kt2][qq] = __builtin_amdgcn_mfma_f32_16x16x32_bf16(af1, qf[qq][1], s, 0, 0, 0);
            }
        }
        #pragma unroll
        for (int qq = 0; qq < 4; ++qq) {
            int qdv = (qloc0 + qq * 16 + l15) >> 6;
            int prow = qq * 16 + l15;
            #pragma unroll
            for (int kt2 = 0; kt2 < 2; ++kt2) {
                int nb = kk + kt2 * 16 + l4 * 4;
                bf16x4 pb;
                #pragma unroll
                for (int r = 0; r < 4; ++r) {
                    int n = nb + r;
                    float pv = (n <= qdv) ? __expf(sacc[kt2][qq][r] * 0.125f) : 0.f;
                    psum[qq] += pv;
                    pb[r] = (__bf16)pv;
                }
                *(bf16x4*)(sPw + prow * 64 + ((kt2 * 32 + l4 * 8) ^ ((prow & 3) << 4))) = pb;
            }
        }
        bf16x8 pa[4], bv[4];
        #pragma unroll
        for (int qq = 0; qq < 4; ++qq) {
            int prow = qq * 16 + l15;
            pa[qq] = *(const bf16x8*)(sPw + prow * 64 + ((l4 * 16) ^ ((prow & 3) << 4)));
        }
        #pragma unroll
        for (int dt = 0; dt < 4; ++dt) {
            int d = dt * 16 + l15;
            bv[dt] = *(const bf16x8*)(sVt + d * 128 + ((kk * 2 + l4 * 16) ^ ((d & 7) << 4)));
        }
        #pragma unroll
        for (int qq = 0; qq < 4; ++qq)
            #pragma unroll
            for (int dt = 0; dt < 4; ++dt)
                acc[qq][dt] = __builtin_amdgcn_mfma_f32_16x16x32_bf16(pa[qq], bv[dt], acc[qq][dt], 0, 0, 0);
    }

    float cmb[4];
    #pragma unroll
    for (int qq = 0; qq < 4; ++qq) {
        float s = psum[qq] + __shfl_xor(psum[qq], 16);
        s += __shfl_xor(s, 32);
        cmb[qq] = 1.f / s;
    }
    #pragma unroll
    for (int qq = 0; qq < 4; ++qq) {
        #pragma unroll
        for (int r = 0; r < 4; ++r) {
            float sc = __shfl(cmb[qq], l4 * 4 + r, 64);
            size_t row = (size_t)(qbase + qq * 16 + l4 * 4 + r);
            __bf16* op = rem + row * LDIM + lh * 64 + l15;
            #pragma unroll
            for (int dt = 0; dt < 4; ++dt)
                op[dt * 16] = (__bf16)(acc[qq][dt][r] * sc);
        }
    }
}

// ---------------- host launcher ----------------
extern "C" void kernel_launch(void* const* d_in, const int* in_sizes, int n_in,
                              void* d_out, int out_size, void* d_ws, size_t ws_size,
                              hipStream_t stream) {
    (void)in_sizes; (void)n_in; (void)out_size; (void)ws_size;
    const float* x    = (const float*)d_in[0];
    const float* wq   = (const float*)d_in[1];
    const float* wk   = (const float*)d_in[2];
    const float* wv   = (const float*)d_in[3];
    const float* wgq  = (const float*)d_in[4];
    const float* wgk  = (const float*)d_in[5];
    const float* wgv  = (const float*)d_in[6];
    const float* rout = (const float*)d_in[7];
    const float* glw  = (const float*)d_in[8];
    const float* grw  = (const float*)d_in[9];
    const float* wout = (const float*)d_in[10];

    char* p = (char*)d_ws;
    auto alloc = [&](size_t bytes) {
        char* r = p;
        p += (bytes + 255) & ~(size_t)255;
        return r;
    };
    __bf16* xb    = (__bf16*)alloc((size_t)BSROWS * DMODEL * 2);
    __bf16* QKVG  = (__bf16*)alloc((size_t)BSROWS * QKVN * 2);
    __bf16* VtG   = (__bf16*)alloc((size_t)BSROWS * DMODEL * 2);
    __bf16* wcatT = (__bf16*)alloc((size_t)QKVN * DMODEL * 2);
    __bf16* woutT = (__bf16*)alloc((size_t)DMODEL * DMODEL * 2);
    __bf16* wgkT  = (__bf16*)alloc((size_t)LDIM * DMODEL * 2);
    __bf16* wgvT  = (__bf16*)alloc((size_t)LDIM * DMODEL * 2);
    __bf16* routT = (__bf16*)alloc((size_t)DMODEL * LDIM * 2);
    __bf16* xpool = (__bf16*)alloc((size_t)128 * DMODEL * 2);
    __bf16* GKb   = (__bf16*)alloc((size_t)128 * LDIM * 2);
    __bf16* GVb   = (__bf16*)alloc((size_t)128 * LDIM * 2);
    __bf16* localg= (__bf16*)alloc((size_t)BSROWS * DMODEL * 2);
    float*  grbuf = (float*) alloc((size_t)BSROWS * 16 * 4);
    __bf16* remb  = (__bf16*)alloc((size_t)BSROWS * LDIM * 2);
    __bf16* outpre = xb; // alias: xb dead after fused projection

    cvt_f32_to_bf16<<<dim3((BSROWS * DMODEL / 4 + 255) / 256), 256, 0, stream>>>(
        x, xb, BSROWS * DMODEL / 4);

    TJ8 jobs;
    jobs.j[0] = {wq,   wcatT,                 DMODEL, DMODEL};
    jobs.j[1] = {wk,   wcatT + 1024 * DMODEL, DMODEL, DMODEL};
    jobs.j[2] = {wv,   wcatT + 2048 * DMODEL, DMODEL, DMODEL};
    jobs.j[3] = {wgq,  wcatT + 3072 * DMODEL, DMODEL, LDIM};
    jobs.j[4] = {wout, woutT,                 DMODEL, DMODEL};
    jobs.j[5] = {wgk,  wgkT,                  DMODEL, LDIM};
    jobs.j[6] = {wgv,  wgvT,                  DMODEL, LDIM};
    jobs.j[7] = {rout, routT,                 LDIM,   DMODEL};
    transpose_cvt_all<<<dim3(32, 32, 8), dim3(32, 8), 0, stream>>>(jobs);

    pool_x_kernel<<<dim3(4, 128), 256, 0, stream>>>(x, xpool);

    // fused [Q|K|V|GQ] projection via the 8-phase 256^2 GEMM
    gemm256_bf16<<<dim3(32, 14), 512, 0, stream>>>(xb, wcatT, BSROWS, QKVN, DMODEL, QKVG);
    gemm_bf16<false, true><<<dim3(1, 4), 256, 0, stream>>>(xpool, wgkT, 128, LDIM, DMODEL, GKb, nullptr, nullptr, nullptr);
    gemm_bf16<false, true><<<dim3(1, 4), 256, 0, stream>>>(xpool, wgvT, 128, LDIM, DMODEL, GVb, nullptr, nullptr, nullptr);

    transpose_v_bf16<<<dim3(64, 16, 2), 256, 0, stream>>>(QKVG, VtG);

    local_attn_mfma<<<dim3(16, 16, 2), 256, 0, stream>>>(QKVG, VtG, glw, grw, localg, grbuf);
    latent_attn_mfma<<<dim3(16, 8, 2), 256, 0, stream>>>(QKVG, GKb, GVb, remb);

    gemm_bf16<true, true><<<dim3(64, 8), 256, 0, stream>>>(remb, routT, BSROWS, DMODEL, LDIM, outpre, nullptr, localg, grbuf);
    gemm_bf16<false, false><<<dim3(64, 8), 256, 0, stream>>>(outpre, woutT, BSROWS, DMODEL, DMODEL, nullptr, (float*)d_out, nullptr, nullptr);
}

// Round 7
// 246.461 us; speedup vs baseline: 3.7027x; 1.0292x over previous
//
#include <hip/hip_runtime.h>

#define AS1 __attribute__((address_space(1)))
#define AS3 __attribute__((address_space(3)))

typedef float    f32x4  __attribute__((ext_vector_type(4)));
typedef __bf16   bf16x8 __attribute__((ext_vector_type(8)));
typedef __bf16   bf16x4 __attribute__((ext_vector_type(4)));
typedef unsigned int u32x4 __attribute__((ext_vector_type(4)));

static constexpr int SEQ = 4096, NBATCH = 2, DMODEL = 1024, NHEADS = 16, HDIM = 64;
static constexpr int LHEADS = 8, LDIM = 512, NLAT = 64, WIN = 256;
static constexpr int BSROWS = NBATCH * SEQ; // 8192
static constexpr int QKVN = 3584;           // fused [Q|K|V|GQ] column count
static constexpr int KOFF = 1024, VOFF = 2048, GQOFF = 3072;

// ---------------- f32 -> bf16 convert (vectorized) ----------------
__global__ __launch_bounds__(256) void cvt_f32_to_bf16(const float* __restrict__ in,
                                                       __bf16* __restrict__ out, int n4) {
    int i = blockIdx.x * 256 + threadIdx.x;
    if (i >= n4) return;
    f32x4 v = ((const f32x4*)in)[i];
    bf16x4 r;
    r[0] = (__bf16)v[0]; r[1] = (__bf16)v[1]; r[2] = (__bf16)v[2]; r[3] = (__bf16)v[3];
    ((bf16x4*)out)[i] = r;
}

// ---------------- all 8 weight transposes in ONE launch ----------------
struct TJ { const float* in; __bf16* out; int K; int N; };
struct TJ8 { TJ j[8]; };
__global__ void transpose_cvt_all(TJ8 jobs) {
    TJ jb = jobs.j[blockIdx.z];
    int k0 = blockIdx.x * 32, n0 = blockIdx.y * 32;
    if (k0 >= jb.K || n0 >= jb.N) return;
    __shared__ float tbuf[32][33];
    int tx = threadIdx.x, ty = threadIdx.y; // (32, 8)
    #pragma unroll
    for (int i = ty; i < 32; i += 8) tbuf[i][tx] = jb.in[(size_t)(k0 + i) * jb.N + n0 + tx];
    __syncthreads();
    #pragma unroll
    for (int i = ty; i < 32; i += 8) jb.out[(size_t)(n0 + i) * jb.K + k0 + tx] = (__bf16)tbuf[tx][i];
}

// ---------------- bf16 transpose: Vt[b][c][s] = QKVG[b*S+s][VOFF+c] ----------------
__global__ __launch_bounds__(256) void transpose_v_bf16(const __bf16* __restrict__ V,
                                                        __bf16* __restrict__ Vt) {
    __shared__ __bf16 tl[64][65];
    int s0 = blockIdx.x * 64, c0 = blockIdx.y * 64, b = blockIdx.z;
    int tx = threadIdx.x & 63, ty = threadIdx.x >> 6;
    #pragma unroll
    for (int i = ty; i < 64; i += 4)
        tl[i][tx] = V[(size_t)(b * SEQ + s0 + i) * QKVN + VOFF + c0 + tx];
    __syncthreads();
    #pragma unroll
    for (int i = ty; i < 64; i += 4)
        Vt[(size_t)(b * DMODEL + c0 + i) * SEQ + s0 + tx] = tl[tx][i];
}

// ---------------- pool xb (bf16) over chunks of 64 rows -> bf16 [128][1024] ----------------
__global__ __launch_bounds__(256) void pool_x_kernel(const __bf16* __restrict__ xb,
                                                     __bf16* __restrict__ xpool) {
    int c  = blockIdx.x * 256 + threadIdx.x;
    int bn = blockIdx.y;
    const __bf16* p = xb + (size_t)bn * 64 * 1024 + c;
    float s = 0.f;
    #pragma unroll 8
    for (int j = 0; j < 64; ++j) s += (float)p[(size_t)j * 1024];
    xpool[(size_t)bn * 1024 + c] = (__bf16)(s * 0.015625f);
}

// ---------------- m97-style 128x128 GEMM (kept for small/N=1024 GEMMs) ----------------
template <bool EPI, bool OUTBF>
__global__ __launch_bounds__(256) void gemm_bf16(const __bf16* __restrict__ A,
                                                 const __bf16* __restrict__ Bt,
                                                 int M, int N, int K,
                                                 __bf16* __restrict__ outb,
                                                 float* __restrict__ outf,
                                                 const __bf16* __restrict__ lcl,
                                                 const float* __restrict__ grb) {
    __shared__ alignas(16) __bf16 sA[128 * 64];
    __shared__ alignas(16) __bf16 sB[128 * 64];
    int t = threadIdx.x, w = t >> 6, l = t & 63;
    int m0 = blockIdx.x * 128, n0 = blockIdx.y * 128;
    int wr = w >> 1, wc = w & 1;
    int lr = l & 15, lk = (l >> 4) * 8;

    f32x4 zero = {0.f, 0.f, 0.f, 0.f};
    f32x4 acc[4][4];
    #pragma unroll
    for (int a = 0; a < 4; ++a)
        #pragma unroll
        for (int b2 = 0; b2 < 4; ++b2) acc[a][b2] = zero;

    for (int kt = 0; kt < K; kt += 64) {
        #pragma unroll
        for (int c = 0; c < 4; ++c) {
            int lin  = w * 64 + c * 256;
            int linl = lin + l;
            int row = linl >> 3, c8 = (linl & 7) * 8;
            __builtin_amdgcn_global_load_lds(
                (const AS1 void*)(A + (size_t)(m0 + row) * K + kt + c8),
                (AS3 void*)((char*)sA + (size_t)lin * 16), 16, 0, 0);
            __builtin_amdgcn_global_load_lds(
                (const AS1 void*)(Bt + (size_t)(n0 + row) * K + kt + c8),
                (AS3 void*)((char*)sB + (size_t)lin * 16), 16, 0, 0);
        }
        __syncthreads();
        #pragma unroll
        for (int ks = 0; ks < 2; ++ks) {
            bf16x8 av[4], bv[4];
            #pragma unroll
            for (int mi = 0; mi < 4; ++mi)
                av[mi] = *(const bf16x8*)(sA + (wr * 64 + mi * 16 + lr) * 64 + ks * 32 + lk);
            #pragma unroll
            for (int ni = 0; ni < 4; ++ni)
                bv[ni] = *(const bf16x8*)(sB + (wc * 64 + ni * 16 + lr) * 64 + ks * 32 + lk);
            #pragma unroll
            for (int mi = 0; mi < 4; ++mi)
                #pragma unroll
                for (int ni = 0; ni < 4; ++ni)
                    acc[mi][ni] = __builtin_amdgcn_mfma_f32_16x16x32_bf16(
                        av[mi], bv[ni], acc[mi][ni], 0, 0, 0);
        }
        __syncthreads();
    }

    int cr = (l >> 4) * 4, cc = l & 15;
    #pragma unroll
    for (int mi = 0; mi < 4; ++mi) {
        #pragma unroll
        for (int ni = 0; ni < 4; ++ni) {
            int col = n0 + wc * 64 + ni * 16 + cc;
            #pragma unroll
            for (int r = 0; r < 4; ++r) {
                int row = m0 + wr * 64 + mi * 16 + cr + r;
                float v = acc[mi][ni][r];
                if constexpr (EPI) {
                    v = (float)lcl[(size_t)row * 1024 + col] +
                        grb[(size_t)row * 16 + (col >> 6)] * v;
                }
                if constexpr (OUTBF) outb[(size_t)row * N + col] = (__bf16)v;
                else                 outf[(size_t)row * N + col] = v;
            }
        }
    }
}

// ---------------- 256x256 8-phase GEMM (T1+T2+T3+T4+T5), NT even, dims % 256 == 0 ----------------
// 512 threads = 8 waves (wm=w>>2, wn=w&3); per-wave out 128x64; BK=64; LDS 128KB (2 bufs).
// LDS swizzle: byte ^= (row&7)<<4 — full 8-slot spread per 128B row (exact 8 lanes/slot on
// every ds_read_b128; the 1-bit st_16x32 variant left a 2x conflict, r6 PMC 7.3e6).
// Write side (gload_lds linear dest): source chunk = (l&7) ^ ((l>>3)&7). Read side:
// rswz = (l15&7)<<4 (row&7 == l15&7 for both A and B fragments). Involution, row bits fixed.
// Stage schedule: P1:Ao(t+1) P2:B0(t+1) P3:B1(t+1) P4:Ae(t+2) P5:Ao(t+2) P6:B0(t+2)
// P7:B1(t+2) P8:Ae(t+3); counted vmcnt(2) at P4/P8 only.
#define BAR() do { __builtin_amdgcn_sched_barrier(0); __builtin_amdgcn_s_barrier(); \
                   __builtin_amdgcn_sched_barrier(0); } while (0)
#define LGK0() do { asm volatile("s_waitcnt lgkmcnt(0)" ::: "memory"); \
                    __builtin_amdgcn_sched_barrier(0); } while (0)
#define VMC(n) do { asm volatile("s_waitcnt vmcnt(" #n ")" ::: "memory"); \
                    __builtin_amdgcn_sched_barrier(0); } while (0)
#define STG(gp, regionbase, rowbase, ktc) do { \
    int row_ = (rowbase) + (t >> 3); \
    int tc_ = (t & 7) ^ ((t >> 3) & 7); \
    __builtin_amdgcn_global_load_lds( \
        (const AS1 void*)((gp) + (size_t)row_ * K + (ktc) + tc_ * 8), \
        (AS3 void*)(lds + (regionbase) + (rowbase) * 128 + w * 1024), 16, 0, 0); \
} while (0)
#define LOADA(buf, qm) do { \
    _Pragma("unroll") for (int ai_ = 0; ai_ < 4; ++ai_) \
    _Pragma("unroll") for (int ks_ = 0; ks_ < 2; ++ks_) \
        a[ai_][ks_] = *(const bf16x8*)(lds + ((((buf) * 65536) + \
            (wm * 128 + (qm) * 64 + ai_ * 16 + l15) * 128 + ks_ * 64 + l4 * 16) ^ rswz)); \
} while (0)
#define LOADB2(buf, half) do { \
    _Pragma("unroll") for (int j_ = 0; j_ < 2; ++j_) \
    _Pragma("unroll") for (int ks_ = 0; ks_ < 2; ++ks_) \
        b2[j_][ks_] = *(const bf16x8*)(lds + ((((buf) * 65536 + 32768) + \
            (wn * 64 + ((half) * 2 + j_) * 16 + l15) * 128 + ks_ * 64 + l4 * 16) ^ rswz)); \
} while (0)
#define MFMA_PH(qm, half) do { \
    __builtin_amdgcn_s_setprio(1); \
    _Pragma("unroll") for (int ai_ = 0; ai_ < 4; ++ai_) \
    _Pragma("unroll") for (int j_ = 0; j_ < 2; ++j_) { \
        f32x4 c_ = acc[(qm) * 4 + ai_][(half) * 2 + j_]; \
        c_ = __builtin_amdgcn_mfma_f32_16x16x32_bf16(a[ai_][0], b2[j_][0], c_, 0, 0, 0); \
        c_ = __builtin_amdgcn_mfma_f32_16x16x32_bf16(a[ai_][1], b2[j_][1], c_, 0, 0, 0); \
        acc[(qm) * 4 + ai_][(half) * 2 + j_] = c_; \
    } \
    __builtin_amdgcn_s_setprio(0); \
} while (0)

__global__ __launch_bounds__(512, 2) void gemm256_bf16(
    const __bf16* __restrict__ A, const __bf16* __restrict__ Bt,
    int M, int N, int K, __bf16* __restrict__ outb) {
    __shared__ char lds[131072];
    const int t = threadIdx.x, w = t >> 6, l = t & 63;
    const int wm = w >> 2, wn = w & 3;
    const int l15 = l & 15, l4 = l >> 4;
    // T1 XCD-aware block swizzle (1D grid, nwg % 8 == 0)
    const int nwg = gridDim.x, cpx = nwg >> 3;
    const int bid = blockIdx.x;
    const int sid = (bid & 7) * cpx + (bid >> 3);
    const int mtiles = M >> 8;
    const int m0 = (sid % mtiles) * 256, n0 = (sid / mtiles) * 256;
    const int NT = K >> 6;
    const int rswz = (l15 & 7) << 4;

    f32x4 acc[8][4];
    #pragma unroll
    for (int i = 0; i < 8; ++i)
        #pragma unroll
        for (int j = 0; j < 4; ++j) acc[i][j] = (f32x4){0.f, 0.f, 0.f, 0.f};
    bf16x8 a[4][2], b2[2][2];

    const __bf16* Ab = A + (size_t)m0 * K;
    const __bf16* Bb = Bt + (size_t)n0 * K;

    // prologue: tile 0 -> buf0 (Ae,Ao,B0,B1), then Ae(1) -> buf1 (kept in flight)
    STG(Ab, 0, 0, 0);        STG(Ab, 0, 128, 0);
    STG(Ab, 0, 64, 0);       STG(Ab, 0, 192, 0);
    STG(Bb, 32768, 0, 0);    STG(Bb, 32768, 64, 0);
    STG(Bb, 32768, 128, 0);  STG(Bb, 32768, 192, 0);
    STG(Ab, 65536, 0, 64);   STG(Ab, 65536, 128, 64);
    VMC(2); BAR();

    int it = 0;
    for (; it + 3 < NT; it += 2) {
        const int kt1 = (it + 1) << 6, kt2 = (it + 2) << 6, kt3 = (it + 3) << 6;
        // P1
        LOADA(0, 0); LOADB2(0, 0);
        STG(Ab, 65536, 64, kt1); STG(Ab, 65536, 192, kt1);
        BAR(); LGK0(); MFMA_PH(0, 0); BAR();
        // P2
        LOADB2(0, 1);
        STG(Bb, 98304, 0, kt1); STG(Bb, 98304, 64, kt1);
        BAR(); LGK0(); MFMA_PH(0, 1); BAR();
        // P3
        LOADA(0, 1); LOADB2(0, 0);
        STG(Bb, 98304, 128, kt1); STG(Bb, 98304, 192, kt1);
        BAR(); LGK0(); MFMA_PH(1, 0); BAR();
        // P4
        LOADB2(0, 1);
        STG(Ab, 0, 0, kt2); STG(Ab, 0, 128, kt2);
        BAR(); LGK0(); MFMA_PH(1, 1); VMC(2); BAR();
        // P5
        LOADA(1, 0); LOADB2(1, 0);
        STG(Ab, 0, 64, kt2); STG(Ab, 0, 192, kt2);
        BAR(); LGK0(); MFMA_PH(0, 0); BAR();
        // P6
        LOADB2(1, 1);
        STG(Bb, 32768, 0, kt2); STG(Bb, 32768, 64, kt2);
        BAR(); LGK0(); MFMA_PH(0, 1); BAR();
        // P7
        LOADA(1, 1); LOADB2(1, 0);
        STG(Bb, 32768, 128, kt2); STG(Bb, 32768, 192, kt2);
        BAR(); LGK0(); MFMA_PH(1, 0); BAR();
        // P8
        LOADB2(1, 1);
        STG(Ab, 65536, 0, kt3); STG(Ab, 65536, 128, kt3);
        BAR(); LGK0(); MFMA_PH(1, 1); VMC(2); BAR();
    }
    // final iteration (t = NT-2, t+1 = NT-1): stage only t+1 (P1-P3), drain at P4
    {
        const int kt1 = (it + 1) << 6;
        LOADA(0, 0); LOADB2(0, 0);
        STG(Ab, 65536, 64, kt1); STG(Ab, 65536, 192, kt1);
        BAR(); LGK0(); MFMA_PH(0, 0); BAR();
        LOADB2(0, 1);
        STG(Bb, 98304, 0, kt1); STG(Bb, 98304, 64, kt1);
        BAR(); LGK0(); MFMA_PH(0, 1); BAR();
        LOADA(0, 1); LOADB2(0, 0);
        STG(Bb, 98304, 128, kt1); STG(Bb, 98304, 192, kt1);
        BAR(); LGK0(); MFMA_PH(1, 0); BAR();
        LOADB2(0, 1);
        BAR(); LGK0(); MFMA_PH(1, 1); VMC(0); BAR();
        LOADA(1, 0); LOADB2(1, 0);
        BAR(); LGK0(); MFMA_PH(0, 0); BAR();
        LOADB2(1, 1);
        BAR(); LGK0(); MFMA_PH(0, 1); BAR();
        LOADA(1, 1); LOADB2(1, 0);
        BAR(); LGK0(); MFMA_PH(1, 0); BAR();
        LOADB2(1, 1);
        LGK0(); MFMA_PH(1, 1);
    }

    // epilogue (same verified C/D mapping as gemm_bf16)
    int cr = l4 * 4, cc = l15;
    #pragma unroll
    for (int mi = 0; mi < 8; ++mi) {
        #pragma unroll
        for (int ni = 0; ni < 4; ++ni) {
            int col = n0 + wn * 64 + ni * 16 + cc;
            #pragma unroll
            for (int r = 0; r < 4; ++r) {
                int row = m0 + wm * 128 + mi * 16 + cr + r;
                outb[(size_t)row * N + col] = (__bf16)acc[mi][ni][r];
            }
        }
    }
}
#undef BAR
#undef LGK0
#undef VMC
#undef STG
#undef LOADA
#undef LOADB2
#undef MFMA_PH

// ---------------- local sliding-window attention, MFMA (verified r5/r6) ----------------
__global__ __launch_bounds__(256, 2) void local_attn_mfma(
    const __bf16* __restrict__ QKVG, const __bf16* __restrict__ Vt,
    const float* __restrict__ glw, const float* __restrict__ grw,
    __bf16* __restrict__ outl, float* __restrict__ grbuf) {
    int blk = blockIdx.x, h = blockIdx.y, b = blockIdx.z;
    int t = threadIdx.x, w = t >> 6, l = t & 63;
    int l15 = l & 15, l4 = l >> 4;

    __shared__ alignas(16) char sKb[512 * 128];
    __shared__ alignas(16) char sPb[4 * 64 * 64];

    bf16x8 qf[4][2];
    long qbase = (long)b * SEQ + blk * 256 + 64 * w;
    #pragma unroll
    for (int qq = 0; qq < 4; ++qq)
        #pragma unroll
        for (int ks = 0; ks < 2; ++ks)
            qf[qq][ks] = *(const bf16x8*)(QKVG + (size_t)(qbase + qq * 16 + l15) * QKVN
                                          + h * 64 + ks * 32 + l4 * 8);

    long g0 = (long)b * SEQ + (long)(blk - 1) * WIN;
    #pragma unroll
    for (int rep = 0; rep < 16; ++rep) {
        int ci = rep * 256 + t;
        int row = ci >> 3, c8 = (ci & 7) * 8;
        u32x4 kv = {0u, 0u, 0u, 0u};
        if (!(blk == 0 && row < 256))
            kv = *(const u32x4*)(QKVG + (size_t)(g0 + row) * QKVN + KOFF + h * 64 + c8);
        *(u32x4*)(sKb + row * 128 + ((c8 * 2) ^ ((row & 7) << 4))) = kv;
    }

    float dlp[4], drp[4];
    #pragma unroll
    for (int qq = 0; qq < 4; ++qq) {
        float dl = 0.f, dr = 0.f;
        #pragma unroll
        for (int ks = 0; ks < 2; ++ks) {
            const float* gp = glw + h * 64 + ks * 32 + l4 * 8;
            const float* rp = grw + h * 64 + ks * 32 + l4 * 8;
            #pragma unroll
            for (int j = 0; j < 8; ++j) {
                float qv = (float)qf[qq][ks][j];
                dl += qv * gp[j];
                dr += qv * rp[j];
            }
        }
        dlp[qq] = dl; drp[qq] = dr;
    }
    float glv[4], grv[4];
    #pragma unroll
    for (int qq = 0; qq < 4; ++qq) {
        float dl = dlp[qq] + __shfl_xor(dlp[qq], 16);
        dl += __shfl_xor(dl, 32);
        float dr = drp[qq] + __shfl_xor(drp[qq], 16);
        dr += __shfl_xor(dr, 32);
        glv[qq] = 1.f / (1.f + __expf(-dl));
        grv[qq] = 1.f / (1.f + __expf(-dr));
    }
    if (l4 == 0) {
        #pragma unroll
        for (int qq = 0; qq < 4; ++qq)
            grbuf[(size_t)(qbase + qq * 16 + l15) * 16 + h] = grv[qq];
    }
    __syncthreads();

    f32x4 zero = {0.f, 0.f, 0.f, 0.f};
    f32x4 acc[4][4];
    #pragma unroll
    for (int a = 0; a < 4; ++a)
        #pragma unroll
        for (int d = 0; d < 4; ++d) acc[a][d] = zero;
    float psum[4] = {0.f, 0.f, 0.f, 0.f};

    char* sPw = sPb + w * 4096;
    int nsteps = (w == 3) ? 10 : 11;
    int kk0 = 64 * w;
    const __bf16* vtb = Vt + (size_t)b * DMODEL * SEQ + (size_t)(h * 64) * SEQ;

    for (int stp = 0; stp < nsteps; ++stp) {
        int kk = kk0 + 32 * stp;
        f32x4 sacc[2][4];
        #pragma unroll
        for (int kt2 = 0; kt2 < 2; ++kt2) {
            int krow = kk + kt2 * 16 + l15;
            int swz = (krow & 7) << 4;
            bf16x8 af0 = *(const bf16x8*)(sKb + krow * 128 + ((l4 * 16) ^ swz));
            bf16x8 af1 = *(const bf16x8*)(sKb + krow * 128 + ((64 + l4 * 16) ^ swz));
            #pragma unroll
            for (int qq = 0; qq < 4; ++qq) {
                f32x4 s = __builtin_amdgcn_mfma_f32_16x16x32_bf16(af0, qf[qq][0], zero, 0, 0, 0);
                sacc[kt2][qq] = __builtin_amdgcn_mfma_f32_16x16x32_bf16(af1, qf[qq][1], s, 0, 0, 0);
            }
        }
        #pragma unroll
        for (int qq = 0; qq < 4; ++qq) {
            int qloc = 64 * w + qq * 16 + l15;
            int prow = qq * 16 + l15;
            #pragma unroll
            for (int kt2 = 0; kt2 < 2; ++kt2) {
                int jb = kk + kt2 * 16 + l4 * 4;
                bf16x4 pb;
                #pragma unroll
                for (int r = 0; r < 4; ++r) {
                    int jw = jb + r;
                    bool act = (jw > qloc) && (jw <= qloc + 256) && (blk > 0 || jw >= 256);
                    float pv = act ? __expf(sacc[kt2][qq][r] * 0.125f) : 0.f;
                    psum[qq] += pv;
                    pb[r] = (__bf16)pv;
                }
                *(bf16x4*)(sPw + prow * 64 + ((kt2 * 32 + l4 * 8) ^ ((prow & 3) << 4))) = pb;
            }
        }
        int kglob = (blk - 1) * WIN + kk + l4 * 8;
        if (kglob < 0) kglob = 0;
        bf16x8 pa[4], bv[4];
        #pragma unroll
        for (int qq = 0; qq < 4; ++qq) {
            int prow = qq * 16 + l15;
            pa[qq] = *(const bf16x8*)(sPw + prow * 64 + ((l4 * 16) ^ ((prow & 3) << 4)));
        }
        #pragma unroll
        for (int dt = 0; dt < 4; ++dt)
            bv[dt] = *(const bf16x8*)(vtb + (size_t)(dt * 16 + l15) * SEQ + kglob);
        #pragma unroll
        for (int qq = 0; qq < 4; ++qq)
            #pragma unroll
            for (int dt = 0; dt < 4; ++dt)
                acc[qq][dt] = __builtin_amdgcn_mfma_f32_16x16x32_bf16(pa[qq], bv[dt], acc[qq][dt], 0, 0, 0);
    }

    float cmb[4];
    #pragma unroll
    for (int qq = 0; qq < 4; ++qq) {
        float s = psum[qq] + __shfl_xor(psum[qq], 16);
        s += __shfl_xor(s, 32);
        cmb[qq] = glv[qq] / s;
    }
    #pragma unroll
    for (int qq = 0; qq < 4; ++qq) {
        #pragma unroll
        for (int r = 0; r < 4; ++r) {
            float sc = __shfl(cmb[qq], l4 * 4 + r, 64);
            size_t row = (size_t)(qbase + qq * 16 + l4 * 4 + r);
            __bf16* op = outl + row * DMODEL + h * 64 + l15;
            #pragma unroll
            for (int dt = 0; dt < 4; ++dt)
                op[dt * 16] = (__bf16)(acc[qq][dt][r] * sc);
        }
    }
}

// ---------------- latent (remote) attention, MFMA (verified r4-r6) ----------------
__global__ __launch_bounds__(256, 1) void latent_attn_mfma(
    const __bf16* __restrict__ QKVG, const __bf16* __restrict__ GK,
    const __bf16* __restrict__ GV, __bf16* __restrict__ rem) {
    int sb = blockIdx.x, lh = blockIdx.y, b = blockIdx.z;
    int t = threadIdx.x, w = t >> 6, l = t & 63;
    int l15 = l & 15, l4 = l >> 4;

    __shared__ alignas(16) char sK[64 * 128];
    __shared__ alignas(16) char sVt[64 * 128];
    __shared__ alignas(16) char sPb[4 * 64 * 64];

    bf16x8 qf[4][2];
    long qbase = (long)b * SEQ + sb * 256 + 64 * w;
    #pragma unroll
    for (int qq = 0; qq < 4; ++qq)
        #pragma unroll
        for (int ks = 0; ks < 2; ++ks)
            qf[qq][ks] = *(const bf16x8*)(QKVG + (size_t)(qbase + qq * 16 + l15) * QKVN
                                          + GQOFF + lh * 64 + ks * 32 + l4 * 8);

    #pragma unroll
    for (int rep = 0; rep < 2; ++rep) {
        int ci = rep * 256 + t;
        int row = ci >> 3, c8 = (ci & 7) * 8;
        u32x4 kv = *(const u32x4*)(GK + (size_t)(b * 64 + row) * LDIM + lh * 64 + c8);
        *(u32x4*)(sK + row * 128 + ((c8 * 2) ^ ((row & 7) << 4))) = kv;
    }
    #pragma unroll
    for (int rep = 0; rep < 16; ++rep) {
        int idx = rep * 256 + t;
        int d = idx & 63, n = idx >> 6;
        __bf16 v = GV[(size_t)(b * 64 + n) * LDIM + lh * 64 + d];
        *(__bf16*)(sVt + d * 128 + ((n * 2) ^ ((d & 7) << 4))) = v;
    }
    __syncthreads();

    f32x4 zero = {0.f, 0.f, 0.f, 0.f};
    f32x4 acc[4][4];
    #pragma unroll
    for (int a = 0; a < 4; ++a)
        #pragma unroll
        for (int d = 0; d < 4; ++d) acc[a][d] = zero;
    float psum[4] = {0.f, 0.f, 0.f, 0.f};

    char* sPw = sPb + w * 4096;
    int qloc0 = sb * 256 + 64 * w;

    #pragma unroll
    for (int stp = 0; stp < 2; ++stp) {
        int kk = 32 * stp;
        f32x4 sacc[2][4];
        #pragma unroll
        for (int kt2 = 0; kt2 < 2; ++kt2) {
            int krow = kk + kt2 * 16 + l15;
            int swz = (krow & 7) << 4;
            bf16x8 af0 = *(const bf16x8*)(sK + krow * 128 + ((l4 * 16) ^ swz));
            bf16x8 af1 = *(const bf16x8*)(sK + krow * 128 + ((64 + l4 * 16) ^ swz));
            #pragma unroll
            for (int qq = 0; qq < 4; ++qq) {
                f32x4 s = __builtin_amdgcn_mfma_f32_16x16x32_bf16(af0, qf[qq][0], zero, 0, 0, 0);
                sacc[kt2][qq] = __builtin_amdgcn_mfma_f32_16x16x32_bf16(af1, qf[qq][1], s, 0, 0, 0);
            }
        }
        #pragma unroll
        for (int qq = 0; qq < 4; ++qq) {
            int qdv = (qloc0 + qq * 16 + l15) >> 6;
            int prow = qq * 16 + l15;
            #pragma unroll
            for (int kt2 = 0; kt2 < 2; ++kt2) {
                int nb = kk + kt2 * 16 + l4 * 4;
                bf16x4 pb;
                #pragma unroll
                for (int r = 0; r < 4; ++r) {
                    int n = nb + r;
                    float pv = (n <= qdv) ? __expf(sacc[kt2][qq][r] * 0.125f) : 0.f;
                    psum[qq] += pv;
                    pb[r] = (__bf16)pv;
                }
                *(bf16x4*)(sPw + prow * 64 + ((kt2 * 32 + l4 * 8) ^ ((prow & 3) << 4))) = pb;
            }
        }
        bf16x8 pa[4], bv[4];
        #pragma unroll
        for (int qq = 0; qq < 4; ++qq) {
            int prow = qq * 16 + l15;
            pa[qq] = *(const bf16x8*)(sPw + prow * 64 + ((l4 * 16) ^ ((prow & 3) << 4)));
        }
        #pragma unroll
        for (int dt = 0; dt < 4; ++dt) {
            int d = dt * 16 + l15;
            bv[dt] = *(const bf16x8*)(sVt + d * 128 + ((kk * 2 + l4 * 16) ^ ((d & 7) << 4)));
        }
        #pragma unroll
        for (int qq = 0; qq < 4; ++qq)
            #pragma unroll
            for (int dt = 0; dt < 4; ++dt)
                acc[qq][dt] = __builtin_amdgcn_mfma_f32_16x16x32_bf16(pa[qq], bv[dt], acc[qq][dt], 0, 0, 0);
    }

    float cmb[4];
    #pragma unroll
    for (int qq = 0; qq < 4; ++qq) {
        float s = psum[qq] + __shfl_xor(psum[qq], 16);
        s += __shfl_xor(s, 32);
        cmb[qq] = 1.f / s;
    }
    #pragma unroll
    for (int qq = 0; qq < 4; ++qq) {
        #pragma unroll
        for (int r = 0; r < 4; ++r) {
            float sc = __shfl(cmb[qq], l4 * 4 + r, 64);
            size_t row = (size_t)(qbase + qq * 16 + l4 * 4 + r);
            __bf16* op = rem + row * LDIM + lh * 64 + l15;
            #pragma unroll
            for (int dt = 0; dt < 4; ++dt)
                op[dt * 16] = (__bf16)(acc[qq][dt][r] * sc);
        }
    }
}

// ---------------- host launcher ----------------
extern "C" void kernel_launch(void* const* d_in, const int* in_sizes, int n_in,
                              void* d_out, int out_size, void* d_ws, size_t ws_size,
                              hipStream_t stream) {
    (void)in_sizes; (void)n_in; (void)out_size; (void)ws_size;
    const float* x    = (const float*)d_in[0];
    const float* wq   = (const float*)d_in[1];
    const float* wk   = (const float*)d_in[2];
    const float* wv   = (const float*)d_in[3];
    const float* wgq  = (const float*)d_in[4];
    const float* wgk  = (const float*)d_in[5];
    const float* wgv  = (const float*)d_in[6];
    const float* rout = (const float*)d_in[7];
    const float* glw  = (const float*)d_in[8];
    const float* grw  = (const float*)d_in[9];
    const float* wout = (const float*)d_in[10];

    char* p = (char*)d_ws;
    auto alloc = [&](size_t bytes) {
        char* r = p;
        p += (bytes + 255) & ~(size_t)255;
        return r;
    };
    __bf16* xb    = (__bf16*)alloc((size_t)BSROWS * DMODEL * 2);
    __bf16* QKVG  = (__bf16*)alloc((size_t)BSROWS * QKVN * 2);
    __bf16* VtG   = (__bf16*)alloc((size_t)BSROWS * DMODEL * 2);
    __bf16* wcatT = (__bf16*)alloc((size_t)QKVN * DMODEL * 2);
    __bf16* woutT = (__bf16*)alloc((size_t)DMODEL * DMODEL * 2);
    __bf16* wgkT  = (__bf16*)alloc((size_t)LDIM * DMODEL * 2);
    __bf16* wgvT  = (__bf16*)alloc((size_t)LDIM * DMODEL * 2);
    __bf16* routT = (__bf16*)alloc((size_t)DMODEL * LDIM * 2);
    __bf16* xpool = (__bf16*)alloc((size_t)128 * DMODEL * 2);
    __bf16* GKb   = (__bf16*)alloc((size_t)128 * LDIM * 2);
    __bf16* GVb   = (__bf16*)alloc((size_t)128 * LDIM * 2);
    __bf16* localg= (__bf16*)alloc((size_t)BSROWS * DMODEL * 2);
    float*  grbuf = (float*) alloc((size_t)BSROWS * 16 * 4);
    __bf16* remb  = (__bf16*)alloc((size_t)BSROWS * LDIM * 2);
    __bf16* outpre = xb; // alias: xb dead after fused projection

    cvt_f32_to_bf16<<<dim3((BSROWS * DMODEL / 4 + 255) / 256), 256, 0, stream>>>(
        x, xb, BSROWS * DMODEL / 4);

    TJ8 jobs;
    jobs.j[0] = {wq,   wcatT,                 DMODEL, DMODEL};
    jobs.j[1] = {wk,   wcatT + 1024 * DMODEL, DMODEL, DMODEL};
    jobs.j[2] = {wv,   wcatT + 2048 * DMODEL, DMODEL, DMODEL};
    jobs.j[3] = {wgq,  wcatT + 3072 * DMODEL, DMODEL, LDIM};
    jobs.j[4] = {wout, woutT,                 DMODEL, DMODEL};
    jobs.j[5] = {wgk,  wgkT,                  DMODEL, LDIM};
    jobs.j[6] = {wgv,  wgvT,                  DMODEL, LDIM};
    jobs.j[7] = {rout, routT,                 LDIM,   DMODEL};
    transpose_cvt_all<<<dim3(32, 32, 8), dim3(32, 8), 0, stream>>>(jobs);

    pool_x_kernel<<<dim3(4, 128), 256, 0, stream>>>(xb, xpool);

    // fused [Q|K|V|GQ] projection via the 8-phase 256^2 GEMM (1D grid, T1 swizzle inside)
    gemm256_bf16<<<dim3(32 * 14), 512, 0, stream>>>(xb, wcatT, BSROWS, QKVN, DMODEL, QKVG);
    gemm_bf16<false, true><<<dim3(1, 4), 256, 0, stream>>>(xpool, wgkT, 128, LDIM, DMODEL, GKb, nullptr, nullptr, nullptr);
    gemm_bf16<false, true><<<dim3(1, 4), 256, 0, stream>>>(xpool, wgvT, 128, LDIM, DMODEL, GVb, nullptr, nullptr, nullptr);

    transpose_v_bf16<<<dim3(64, 16, 2), 256, 0, stream>>>(QKVG, VtG);

    local_attn_mfma<<<dim3(16, 16, 2), 256, 0, stream>>>(QKVG, VtG, glw, grw, localg, grbuf);
    latent_attn_mfma<<<dim3(16, 8, 2), 256, 0, stream>>>(QKVG, GKb, GVb, remb);

    gemm_bf16<true, true><<<dim3(64, 8), 256, 0, stream>>>(remb, routT, BSROWS, DMODEL, LDIM, outpre, nullptr, localg, grbuf);
    gemm_bf16<false, false><<<dim3(64, 8), 256, 0, stream>>>(outpre, woutT, BSROWS, DMODEL, DMODEL, nullptr, (float*)d_out, nullptr, nullptr);
}

// Round 8
// 232.928 us; speedup vs baseline: 3.9178x; 1.0581x over previous
//
#include <hip/hip_runtime.h>

#define AS1 __attribute__((address_space(1)))
#define AS3 __attribute__((address_space(3)))

typedef float    f32x4  __attribute__((ext_vector_type(4)));
typedef __bf16   bf16x8 __attribute__((ext_vector_type(8)));
typedef __bf16   bf16x4 __attribute__((ext_vector_type(4)));
typedef unsigned int u32x4 __attribute__((ext_vector_type(4)));

static constexpr int SEQ = 4096, NBATCH = 2, DMODEL = 1024, NHEADS = 16, HDIM = 64;
static constexpr int LHEADS = 8, LDIM = 512, NLAT = 64, WIN = 256;
static constexpr int BSROWS = NBATCH * SEQ; // 8192
static constexpr int QKVN = 3584;           // fused [Q|K|V|GQ] column count
static constexpr int KOFF = 1024, VOFF = 2048, GQOFF = 3072;

// ---------------- f32 -> bf16 convert (vectorized) ----------------
__global__ __launch_bounds__(256) void cvt_f32_to_bf16(const float* __restrict__ in,
                                                       __bf16* __restrict__ out, int n4) {
    int i = blockIdx.x * 256 + threadIdx.x;
    if (i >= n4) return;
    f32x4 v = ((const f32x4*)in)[i];
    bf16x4 r;
    r[0] = (__bf16)v[0]; r[1] = (__bf16)v[1]; r[2] = (__bf16)v[2]; r[3] = (__bf16)v[3];
    ((bf16x4*)out)[i] = r;
}

// ---------------- all 8 weight transposes in ONE launch ----------------
struct TJ { const float* in; __bf16* out; int K; int N; };
struct TJ8 { TJ j[8]; };
__global__ void transpose_cvt_all(TJ8 jobs) {
    TJ jb = jobs.j[blockIdx.z];
    int k0 = blockIdx.x * 32, n0 = blockIdx.y * 32;
    if (k0 >= jb.K || n0 >= jb.N) return;
    __shared__ float tbuf[32][33];
    int tx = threadIdx.x, ty = threadIdx.y; // (32, 8)
    #pragma unroll
    for (int i = ty; i < 32; i += 8) tbuf[i][tx] = jb.in[(size_t)(k0 + i) * jb.N + n0 + tx];
    __syncthreads();
    #pragma unroll
    for (int i = ty; i < 32; i += 8) jb.out[(size_t)(n0 + i) * jb.K + k0 + tx] = (__bf16)tbuf[tx][i];
}

// ---------------- pool xb (bf16) over chunks of 64 rows -> bf16 [128][1024] ----------------
__global__ __launch_bounds__(256) void pool_x_kernel(const __bf16* __restrict__ xb,
                                                     __bf16* __restrict__ xpool) {
    int c  = blockIdx.x * 256 + threadIdx.x;
    int bn = blockIdx.y;
    const __bf16* p = xb + (size_t)bn * 64 * 1024 + c;
    float s = 0.f;
    #pragma unroll 8
    for (int j = 0; j < 64; ++j) s += (float)p[(size_t)j * 1024];
    xpool[(size_t)bn * 1024 + c] = (__bf16)(s * 0.015625f);
}

// ---------------- m97-style 128x128 GEMM (kept for small/N=1024 GEMMs) ----------------
template <bool EPI, bool OUTBF>
__global__ __launch_bounds__(256) void gemm_bf16(const __bf16* __restrict__ A,
                                                 const __bf16* __restrict__ Bt,
                                                 int M, int N, int K,
                                                 __bf16* __restrict__ outb,
                                                 float* __restrict__ outf,
                                                 const __bf16* __restrict__ lcl,
                                                 const float* __restrict__ grb) {
    __shared__ alignas(16) __bf16 sA[128 * 64];
    __shared__ alignas(16) __bf16 sB[128 * 64];
    int t = threadIdx.x, w = t >> 6, l = t & 63;
    int m0 = blockIdx.x * 128, n0 = blockIdx.y * 128;
    int wr = w >> 1, wc = w & 1;
    int lr = l & 15, lk = (l >> 4) * 8;

    f32x4 zero = {0.f, 0.f, 0.f, 0.f};
    f32x4 acc[4][4];
    #pragma unroll
    for (int a = 0; a < 4; ++a)
        #pragma unroll
        for (int b2 = 0; b2 < 4; ++b2) acc[a][b2] = zero;

    for (int kt = 0; kt < K; kt += 64) {
        #pragma unroll
        for (int c = 0; c < 4; ++c) {
            int lin  = w * 64 + c * 256;
            int linl = lin + l;
            int row = linl >> 3, c8 = (linl & 7) * 8;
            __builtin_amdgcn_global_load_lds(
                (const AS1 void*)(A + (size_t)(m0 + row) * K + kt + c8),
                (AS3 void*)((char*)sA + (size_t)lin * 16), 16, 0, 0);
            __builtin_amdgcn_global_load_lds(
                (const AS1 void*)(Bt + (size_t)(n0 + row) * K + kt + c8),
                (AS3 void*)((char*)sB + (size_t)lin * 16), 16, 0, 0);
        }
        __syncthreads();
        #pragma unroll
        for (int ks = 0; ks < 2; ++ks) {
            bf16x8 av[4], bv[4];
            #pragma unroll
            for (int mi = 0; mi < 4; ++mi)
                av[mi] = *(const bf16x8*)(sA + (wr * 64 + mi * 16 + lr) * 64 + ks * 32 + lk);
            #pragma unroll
            for (int ni = 0; ni < 4; ++ni)
                bv[ni] = *(const bf16x8*)(sB + (wc * 64 + ni * 16 + lr) * 64 + ks * 32 + lk);
            #pragma unroll
            for (int mi = 0; mi < 4; ++mi)
                #pragma unroll
                for (int ni = 0; ni < 4; ++ni)
                    acc[mi][ni] = __builtin_amdgcn_mfma_f32_16x16x32_bf16(
                        av[mi], bv[ni], acc[mi][ni], 0, 0, 0);
        }
        __syncthreads();
    }

    int cr = (l >> 4) * 4, cc = l & 15;
    #pragma unroll
    for (int mi = 0; mi < 4; ++mi) {
        #pragma unroll
        for (int ni = 0; ni < 4; ++ni) {
            int col = n0 + wc * 64 + ni * 16 + cc;
            #pragma unroll
            for (int r = 0; r < 4; ++r) {
                int row = m0 + wr * 64 + mi * 16 + cr + r;
                float v = acc[mi][ni][r];
                if constexpr (EPI) {
                    v = (float)lcl[(size_t)row * 1024 + col] +
                        grb[(size_t)row * 16 + (col >> 6)] * v;
                }
                if constexpr (OUTBF) outb[(size_t)row * N + col] = (__bf16)v;
                else                 outf[(size_t)row * N + col] = v;
            }
        }
    }
}

// ---------------- 256x256 8-phase GEMM (T2+T3+T4+T5), NT even, dims % 256 == 0 ----------------
// 512 threads = 8 waves (wm=w>>2, wn=w&3); per-wave out 128x64; BK=64; LDS 128KB (2 bufs).
// LDS swizzle: byte ^= (row&7)<<4 (full 8-slot spread; conflict-free, r7 PMC = 0).
// 2D grid (x = m-tile fastest) — r7's XCD swizzle REVERTED (FETCH 55.8 -> 132.6 MB regression).
// Fused V-transpose epilogue: n-tiles covering QKVG cols [VOFF, GQOFF) write the tile
// TRANSPOSED straight into Vt[b][c][s] (scattered 2B stores, L2 merges; QKVG V region
// is never written or read — transpose_v kernel eliminated).
#define BAR() do { __builtin_amdgcn_sched_barrier(0); __builtin_amdgcn_s_barrier(); \
                   __builtin_amdgcn_sched_barrier(0); } while (0)
#define LGK0() do { asm volatile("s_waitcnt lgkmcnt(0)" ::: "memory"); \
                    __builtin_amdgcn_sched_barrier(0); } while (0)
#define VMC(n) do { asm volatile("s_waitcnt vmcnt(" #n ")" ::: "memory"); \
                    __builtin_amdgcn_sched_barrier(0); } while (0)
#define STG(gp, regionbase, rowbase, ktc) do { \
    int row_ = (rowbase) + (t >> 3); \
    int tc_ = (t & 7) ^ ((t >> 3) & 7); \
    __builtin_amdgcn_global_load_lds( \
        (const AS1 void*)((gp) + (size_t)row_ * K + (ktc) + tc_ * 8), \
        (AS3 void*)(lds + (regionbase) + (rowbase) * 128 + w * 1024), 16, 0, 0); \
} while (0)
#define LOADA(buf, qm) do { \
    _Pragma("unroll") for (int ai_ = 0; ai_ < 4; ++ai_) \
    _Pragma("unroll") for (int ks_ = 0; ks_ < 2; ++ks_) \
        a[ai_][ks_] = *(const bf16x8*)(lds + ((((buf) * 65536) + \
            (wm * 128 + (qm) * 64 + ai_ * 16 + l15) * 128 + ks_ * 64 + l4 * 16) ^ rswz)); \
} while (0)
#define LOADB2(buf, half) do { \
    _Pragma("unroll") for (int j_ = 0; j_ < 2; ++j_) \
    _Pragma("unroll") for (int ks_ = 0; ks_ < 2; ++ks_) \
        b2[j_][ks_] = *(const bf16x8*)(lds + ((((buf) * 65536 + 32768) + \
            (wn * 64 + ((half) * 2 + j_) * 16 + l15) * 128 + ks_ * 64 + l4 * 16) ^ rswz)); \
} while (0)
#define MFMA_PH(qm, half) do { \
    __builtin_amdgcn_s_setprio(1); \
    _Pragma("unroll") for (int ai_ = 0; ai_ < 4; ++ai_) \
    _Pragma("unroll") for (int j_ = 0; j_ < 2; ++j_) { \
        f32x4 c_ = acc[(qm) * 4 + ai_][(half) * 2 + j_]; \
        c_ = __builtin_amdgcn_mfma_f32_16x16x32_bf16(a[ai_][0], b2[j_][0], c_, 0, 0, 0); \
        c_ = __builtin_amdgcn_mfma_f32_16x16x32_bf16(a[ai_][1], b2[j_][1], c_, 0, 0, 0); \
        acc[(qm) * 4 + ai_][(half) * 2 + j_] = c_; \
    } \
    __builtin_amdgcn_s_setprio(0); \
} while (0)

__global__ __launch_bounds__(512, 2) void gemm256_bf16(
    const __bf16* __restrict__ A, const __bf16* __restrict__ Bt,
    int M, int N, int K, __bf16* __restrict__ outb, __bf16* __restrict__ Vt) {
    __shared__ char lds[131072];
    const int t = threadIdx.x, w = t >> 6, l = t & 63;
    const int wm = w >> 2, wn = w & 3;
    const int l15 = l & 15, l4 = l >> 4;
    const int m0 = blockIdx.x * 256, n0 = blockIdx.y * 256;
    const int NT = K >> 6;
    const int rswz = (l15 & 7) << 4;

    f32x4 acc[8][4];
    #pragma unroll
    for (int i = 0; i < 8; ++i)
        #pragma unroll
        for (int j = 0; j < 4; ++j) acc[i][j] = (f32x4){0.f, 0.f, 0.f, 0.f};
    bf16x8 a[4][2], b2[2][2];

    const __bf16* Ab = A + (size_t)m0 * K;
    const __bf16* Bb = Bt + (size_t)n0 * K;

    // prologue: tile 0 -> buf0 (Ae,Ao,B0,B1), then Ae(1) -> buf1 (kept in flight)
    STG(Ab, 0, 0, 0);        STG(Ab, 0, 128, 0);
    STG(Ab, 0, 64, 0);       STG(Ab, 0, 192, 0);
    STG(Bb, 32768, 0, 0);    STG(Bb, 32768, 64, 0);
    STG(Bb, 32768, 128, 0);  STG(Bb, 32768, 192, 0);
    STG(Ab, 65536, 0, 64);   STG(Ab, 65536, 128, 64);
    VMC(2); BAR();

    int it = 0;
    for (; it + 3 < NT; it += 2) {
        const int kt1 = (it + 1) << 6, kt2 = (it + 2) << 6, kt3 = (it + 3) << 6;
        // P1
        LOADA(0, 0); LOADB2(0, 0);
        STG(Ab, 65536, 64, kt1); STG(Ab, 65536, 192, kt1);
        BAR(); LGK0(); MFMA_PH(0, 0); BAR();
        // P2
        LOADB2(0, 1);
        STG(Bb, 98304, 0, kt1); STG(Bb, 98304, 64, kt1);
        BAR(); LGK0(); MFMA_PH(0, 1); BAR();
        // P3
        LOADA(0, 1); LOADB2(0, 0);
        STG(Bb, 98304, 128, kt1); STG(Bb, 98304, 192, kt1);
        BAR(); LGK0(); MFMA_PH(1, 0); BAR();
        // P4
        LOADB2(0, 1);
        STG(Ab, 0, 0, kt2); STG(Ab, 0, 128, kt2);
        BAR(); LGK0(); MFMA_PH(1, 1); VMC(2); BAR();
        // P5
        LOADA(1, 0); LOADB2(1, 0);
        STG(Ab, 0, 64, kt2); STG(Ab, 0, 192, kt2);
        BAR(); LGK0(); MFMA_PH(0, 0); BAR();
        // P6
        LOADB2(1, 1);
        STG(Bb, 32768, 0, kt2); STG(Bb, 32768, 64, kt2);
        BAR(); LGK0(); MFMA_PH(0, 1); BAR();
        // P7
        LOADA(1, 1); LOADB2(1, 0);
        STG(Bb, 32768, 128, kt2); STG(Bb, 32768, 192, kt2);
        BAR(); LGK0(); MFMA_PH(1, 0); BAR();
        // P8
        LOADB2(1, 1);
        STG(Ab, 65536, 0, kt3); STG(Ab, 65536, 128, kt3);
        BAR(); LGK0(); MFMA_PH(1, 1); VMC(2); BAR();
    }
    // final iteration (t = NT-2, t+1 = NT-1): stage only t+1 (P1-P3), drain at P4
    {
        const int kt1 = (it + 1) << 6;
        LOADA(0, 0); LOADB2(0, 0);
        STG(Ab, 65536, 64, kt1); STG(Ab, 65536, 192, kt1);
        BAR(); LGK0(); MFMA_PH(0, 0); BAR();
        LOADB2(0, 1);
        STG(Bb, 98304, 0, kt1); STG(Bb, 98304, 64, kt1);
        BAR(); LGK0(); MFMA_PH(0, 1); BAR();
        LOADA(0, 1); LOADB2(0, 0);
        STG(Bb, 98304, 128, kt1); STG(Bb, 98304, 192, kt1);
        BAR(); LGK0(); MFMA_PH(1, 0); BAR();
        LOADB2(0, 1);
        BAR(); LGK0(); MFMA_PH(1, 1); VMC(0); BAR();
        LOADA(1, 0); LOADB2(1, 0);
        BAR(); LGK0(); MFMA_PH(0, 0); BAR();
        LOADB2(1, 1);
        BAR(); LGK0(); MFMA_PH(0, 1); BAR();
        LOADA(1, 1); LOADB2(1, 0);
        BAR(); LGK0(); MFMA_PH(1, 0); BAR();
        LOADB2(1, 1);
        LGK0(); MFMA_PH(1, 1);
    }

    // epilogue (verified C/D mapping): V-tiles write transposed to Vt, others to outb
    int cr = l4 * 4, cc = l15;
    if (Vt != nullptr && n0 >= VOFF && n0 < GQOFF) {
        #pragma unroll
        for (int mi = 0; mi < 8; ++mi) {
            #pragma unroll
            for (int ni = 0; ni < 4; ++ni) {
                int vcol = (n0 - VOFF) + wn * 64 + ni * 16 + cc;
                #pragma unroll
                for (int r = 0; r < 4; ++r) {
                    int row = m0 + wm * 128 + mi * 16 + cr + r;
                    int bb = row >> 12, ss = row & 4095;
                    Vt[((size_t)bb * DMODEL + vcol) * SEQ + ss] = (__bf16)acc[mi][ni][r];
                }
            }
        }
    } else {
        #pragma unroll
        for (int mi = 0; mi < 8; ++mi) {
            #pragma unroll
            for (int ni = 0; ni < 4; ++ni) {
                int col = n0 + wn * 64 + ni * 16 + cc;
                #pragma unroll
                for (int r = 0; r < 4; ++r) {
                    int row = m0 + wm * 128 + mi * 16 + cr + r;
                    outb[(size_t)row * N + col] = (__bf16)acc[mi][ni][r];
                }
            }
        }
    }
}
#undef BAR
#undef LGK0
#undef VMC
#undef STG
#undef LOADA
#undef LOADB2
#undef MFMA_PH

// ---------------- local sliding-window attention, MFMA (verified r5-r7) ----------------
__global__ __launch_bounds__(256, 2) void local_attn_mfma(
    const __bf16* __restrict__ QKVG, const __bf16* __restrict__ Vt,
    const float* __restrict__ glw, const float* __restrict__ grw,
    __bf16* __restrict__ outl, float* __restrict__ grbuf) {
    int blk = blockIdx.x, h = blockIdx.y, b = blockIdx.z;
    int t = threadIdx.x, w = t >> 6, l = t & 63;
    int l15 = l & 15, l4 = l >> 4;

    __shared__ alignas(16) char sKb[512 * 128];
    __shared__ alignas(16) char sPb[4 * 64 * 64];

    bf16x8 qf[4][2];
    long qbase = (long)b * SEQ + blk * 256 + 64 * w;
    #pragma unroll
    for (int qq = 0; qq < 4; ++qq)
        #pragma unroll
        for (int ks = 0; ks < 2; ++ks)
            qf[qq][ks] = *(const bf16x8*)(QKVG + (size_t)(qbase + qq * 16 + l15) * QKVN
                                          + h * 64 + ks * 32 + l4 * 8);

    long g0 = (long)b * SEQ + (long)(blk - 1) * WIN;
    #pragma unroll
    for (int rep = 0; rep < 16; ++rep) {
        int ci = rep * 256 + t;
        int row = ci >> 3, c8 = (ci & 7) * 8;
        u32x4 kv = {0u, 0u, 0u, 0u};
        if (!(blk == 0 && row < 256))
            kv = *(const u32x4*)(QKVG + (size_t)(g0 + row) * QKVN + KOFF + h * 64 + c8);
        *(u32x4*)(sKb + row * 128 + ((c8 * 2) ^ ((row & 7) << 4))) = kv;
    }

    float dlp[4], drp[4];
    #pragma unroll
    for (int qq = 0; qq < 4; ++qq) {
        float dl = 0.f, dr = 0.f;
        #pragma unroll
        for (int ks = 0; ks < 2; ++ks) {
            const float* gp = glw + h * 64 + ks * 32 + l4 * 8;
            const float* rp = grw + h * 64 + ks * 32 + l4 * 8;
            #pragma unroll
            for (int j = 0; j < 8; ++j) {
                float qv = (float)qf[qq][ks][j];
                dl += qv * gp[j];
                dr += qv * rp[j];
            }
        }
        dlp[qq] = dl; drp[qq] = dr;
    }
    float glv[4], grv[4];
    #pragma unroll
    for (int qq = 0; qq < 4; ++qq) {
        float dl = dlp[qq] + __shfl_xor(dlp[qq], 16);
        dl += __shfl_xor(dl, 32);
        float dr = drp[qq] + __shfl_xor(drp[qq], 16);
        dr += __shfl_xor(dr, 32);
        glv[qq] = 1.f / (1.f + __expf(-dl));
        grv[qq] = 1.f / (1.f + __expf(-dr));
    }
    if (l4 == 0) {
        #pragma unroll
        for (int qq = 0; qq < 4; ++qq)
            grbuf[(size_t)(qbase + qq * 16 + l15) * 16 + h] = grv[qq];
    }
    __syncthreads();

    f32x4 zero = {0.f, 0.f, 0.f, 0.f};
    f32x4 acc[4][4];
    #pragma unroll
    for (int a = 0; a < 4; ++a)
        #pragma unroll
        for (int d = 0; d < 4; ++d) acc[a][d] = zero;
    float psum[4] = {0.f, 0.f, 0.f, 0.f};

    char* sPw = sPb + w * 4096;
    int nsteps = (w == 3) ? 10 : 11;
    int kk0 = 64 * w;
    const __bf16* vtb = Vt + (size_t)b * DMODEL * SEQ + (size_t)(h * 64) * SEQ;

    for (int stp = 0; stp < nsteps; ++stp) {
        int kk = kk0 + 32 * stp;
        f32x4 sacc[2][4];
        #pragma unroll
        for (int kt2 = 0; kt2 < 2; ++kt2) {
            int krow = kk + kt2 * 16 + l15;
            int swz = (krow & 7) << 4;
            bf16x8 af0 = *(const bf16x8*)(sKb + krow * 128 + ((l4 * 16) ^ swz));
            bf16x8 af1 = *(const bf16x8*)(sKb + krow * 128 + ((64 + l4 * 16) ^ swz));
            #pragma unroll
            for (int qq = 0; qq < 4; ++qq) {
                f32x4 s = __builtin_amdgcn_mfma_f32_16x16x32_bf16(af0, qf[qq][0], zero, 0, 0, 0);
                sacc[kt2][qq] = __builtin_amdgcn_mfma_f32_16x16x32_bf16(af1, qf[qq][1], s, 0, 0, 0);
            }
        }
        #pragma unroll
        for (int qq = 0; qq < 4; ++qq) {
            int qloc = 64 * w + qq * 16 + l15;
            int prow = qq * 16 + l15;
            #pragma unroll
            for (int kt2 = 0; kt2 < 2; ++kt2) {
                int jb = kk + kt2 * 16 + l4 * 4;
                bf16x4 pb;
                #pragma unroll
                for (int r = 0; r < 4; ++r) {
                    int jw = jb + r;
                    bool act = (jw > qloc) && (jw <= qloc + 256) && (blk > 0 || jw >= 256);
                    float pv = act ? __expf(sacc[kt2][qq][r] * 0.125f) : 0.f;
                    psum[qq] += pv;
                    pb[r] = (__bf16)pv;
                }
                *(bf16x4*)(sPw + prow * 64 + ((kt2 * 32 + l4 * 8) ^ ((prow & 3) << 4))) = pb;
            }
        }
        int kglob = (blk - 1) * WIN + kk + l4 * 8;
        if (kglob < 0) kglob = 0;
        bf16x8 pa[4], bv[4];
        #pragma unroll
        for (int qq = 0; qq < 4; ++qq) {
            int prow = qq * 16 + l15;
            pa[qq] = *(const bf16x8*)(sPw + prow * 64 + ((l4 * 16) ^ ((prow & 3) << 4)));
        }
        #pragma unroll
        for (int dt = 0; dt < 4; ++dt)
            bv[dt] = *(const bf16x8*)(vtb + (size_t)(dt * 16 + l15) * SEQ + kglob);
        #pragma unroll
        for (int qq = 0; qq < 4; ++qq)
            #pragma unroll
            for (int dt = 0; dt < 4; ++dt)
                acc[qq][dt] = __builtin_amdgcn_mfma_f32_16x16x32_bf16(pa[qq], bv[dt], acc[qq][dt], 0, 0, 0);
    }

    float cmb[4];
    #pragma unroll
    for (int qq = 0; qq < 4; ++qq) {
        float s = psum[qq] + __shfl_xor(psum[qq], 16);
        s += __shfl_xor(s, 32);
        cmb[qq] = glv[qq] / s;
    }
    #pragma unroll
    for (int qq = 0; qq < 4; ++qq) {
        #pragma unroll
        for (int r = 0; r < 4; ++r) {
            float sc = __shfl(cmb[qq], l4 * 4 + r, 64);
            size_t row = (size_t)(qbase + qq * 16 + l4 * 4 + r);
            __bf16* op = outl + row * DMODEL + h * 64 + l15;
            #pragma unroll
            for (int dt = 0; dt < 4; ++dt)
                op[dt * 16] = (__bf16)(acc[qq][dt][r] * sc);
        }
    }
}

// ---------------- latent (remote) attention, MFMA (verified r4-r7) ----------------
__global__ __launch_bounds__(256, 1) void latent_attn_mfma(
    const __bf16* __restrict__ QKVG, const __bf16* __restrict__ GK,
    const __bf16* __restrict__ GV, __bf16* __restrict__ rem) {
    int sb = blockIdx.x, lh = blockIdx.y, b = blockIdx.z;
    int t = threadIdx.x, w = t >> 6, l = t & 63;
    int l15 = l & 15, l4 = l >> 4;

    __shared__ alignas(16) char sK[64 * 128];
    __shared__ alignas(16) char sVt[64 * 128];
    __shared__ alignas(16) char sPb[4 * 64 * 64];

    bf16x8 qf[4][2];
    long qbase = (long)b * SEQ + sb * 256 + 64 * w;
    #pragma unroll
    for (int qq = 0; qq < 4; ++qq)
        #pragma unroll
        for (int ks = 0; ks < 2; ++ks)
            qf[qq][ks] = *(const bf16x8*)(QKVG + (size_t)(qbase + qq * 16 + l15) * QKVN
                                          + GQOFF + lh * 64 + ks * 32 + l4 * 8);

    #pragma unroll
    for (int rep = 0; rep < 2; ++rep) {
        int ci = rep * 256 + t;
        int row = ci >> 3, c8 = (ci & 7) * 8;
        u32x4 kv = *(const u32x4*)(GK + (size_t)(b * 64 + row) * LDIM + lh * 64 + c8);
        *(u32x4*)(sK + row * 128 + ((c8 * 2) ^ ((row & 7) << 4))) = kv;
    }
    #pragma unroll
    for (int rep = 0; rep < 16; ++rep) {
        int idx = rep * 256 + t;
        int d = idx & 63, n = idx >> 6;
        __bf16 v = GV[(size_t)(b * 64 + n) * LDIM + lh * 64 + d];
        *(__bf16*)(sVt + d * 128 + ((n * 2) ^ ((d & 7) << 4))) = v;
    }
    __syncthreads();

    f32x4 zero = {0.f, 0.f, 0.f, 0.f};
    f32x4 acc[4][4];
    #pragma unroll
    for (int a = 0; a < 4; ++a)
        #pragma unroll
        for (int d = 0; d < 4; ++d) acc[a][d] = zero;
    float psum[4] = {0.f, 0.f, 0.f, 0.f};

    char* sPw = sPb + w * 4096;
    int qloc0 = sb * 256 + 64 * w;

    #pragma unroll
    for (int stp = 0; stp < 2; ++stp) {
        int kk = 32 * stp;
        f32x4 sacc[2][4];
        #pragma unroll
        for (int kt2 = 0; kt2 < 2; ++kt2) {
            int krow = kk + kt2 * 16 + l15;
            int swz = (krow & 7) << 4;
            bf16x8 af0 = *(const bf16x8*)(sK + krow * 128 + ((l4 * 16) ^ swz));
            bf16x8 af1 = *(const bf16x8*)(sK + krow * 128 + ((64 + l4 * 16) ^ swz));
            #pragma unroll
            for (int qq = 0; qq < 4; ++qq) {
                f32x4 s = __builtin_amdgcn_mfma_f32_16x16x32_bf16(af0, qf[qq][0], zero, 0, 0, 0);
                sacc[kt2][qq] = __builtin_amdgcn_mfma_f32_16x16x32_bf16(af1, qf[qq][1], s, 0, 0, 0);
            }
        }
        #pragma unroll
        for (int qq = 0; qq < 4; ++qq) {
            int qdv = (qloc0 + qq * 16 + l15) >> 6;
            int prow = qq * 16 + l15;
            #pragma unroll
            for (int kt2 = 0; kt2 < 2; ++kt2) {
                int nb = kk + kt2 * 16 + l4 * 4;
                bf16x4 pb;
                #pragma unroll
                for (int r = 0; r < 4; ++r) {
                    int n = nb + r;
                    float pv = (n <= qdv) ? __expf(sacc[kt2][qq][r] * 0.125f) : 0.f;
                    psum[qq] += pv;
                    pb[r] = (__bf16)pv;
                }
                *(bf16x4*)(sPw + prow * 64 + ((kt2 * 32 + l4 * 8) ^ ((prow & 3) << 4))) = pb;
            }
        }
        bf16x8 pa[4], bv[4];
        #pragma unroll
        for (int qq = 0; qq < 4; ++qq) {
            int prow = qq * 16 + l15;
            pa[qq] = *(const bf16x8*)(sPw + prow * 64 + ((l4 * 16) ^ ((prow & 3) << 4)));
        }
        #pragma unroll
        for (int dt = 0; dt < 4; ++dt) {
            int d = dt * 16 + l15;
            bv[dt] = *(const bf16x8*)(sVt + d * 128 + ((kk * 2 + l4 * 16) ^ ((d & 7) << 4)));
        }
        #pragma unroll
        for (int qq = 0; qq < 4; ++qq)
            #pragma unroll
            for (int dt = 0; dt < 4; ++dt)
                acc[qq][dt] = __builtin_amdgcn_mfma_f32_16x16x32_bf16(pa[qq], bv[dt], acc[qq][dt], 0, 0, 0);
    }

    float cmb[4];
    #pragma unroll
    for (int qq = 0; qq < 4; ++qq) {
        float s = psum[qq] + __shfl_xor(psum[qq], 16);
        s += __shfl_xor(s, 32);
        cmb[qq] = 1.f / s;
    }
    #pragma unroll
    for (int qq = 0; qq < 4; ++qq) {
        #pragma unroll
        for (int r = 0; r < 4; ++r) {
            float sc = __shfl(cmb[qq], l4 * 4 + r, 64);
            size_t row = (size_t)(qbase + qq * 16 + l4 * 4 + r);
            __bf16* op = rem + row * LDIM + lh * 64 + l15;
            #pragma unroll
            for (int dt = 0; dt < 4; ++dt)
                op[dt * 16] = (__bf16)(acc[qq][dt][r] * sc);
        }
    }
}

// ---------------- host launcher ----------------
extern "C" void kernel_launch(void* const* d_in, const int* in_sizes, int n_in,
                              void* d_out, int out_size, void* d_ws, size_t ws_size,
                              hipStream_t stream) {
    (void)in_sizes; (void)n_in; (void)out_size; (void)ws_size;
    const float* x    = (const float*)d_in[0];
    const float* wq   = (const float*)d_in[1];
    const float* wk   = (const float*)d_in[2];
    const float* wv   = (const float*)d_in[3];
    const float* wgq  = (const float*)d_in[4];
    const float* wgk  = (const float*)d_in[5];
    const float* wgv  = (const float*)d_in[6];
    const float* rout = (const float*)d_in[7];
    const float* glw  = (const float*)d_in[8];
    const float* grw  = (const float*)d_in[9];
    const float* wout = (const float*)d_in[10];

    char* p = (char*)d_ws;
    auto alloc = [&](size_t bytes) {
        char* r = p;
        p += (bytes + 255) & ~(size_t)255;
        return r;
    };
    __bf16* xb    = (__bf16*)alloc((size_t)BSROWS * DMODEL * 2);
    __bf16* QKVG  = (__bf16*)alloc((size_t)BSROWS * QKVN * 2);
    __bf16* VtG   = (__bf16*)alloc((size_t)BSROWS * DMODEL * 2);
    __bf16* wcatT = (__bf16*)alloc((size_t)QKVN * DMODEL * 2);
    __bf16* woutT = (__bf16*)alloc((size_t)DMODEL * DMODEL * 2);
    __bf16* wgkT  = (__bf16*)alloc((size_t)LDIM * DMODEL * 2);
    __bf16* wgvT  = (__bf16*)alloc((size_t)LDIM * DMODEL * 2);
    __bf16* routT = (__bf16*)alloc((size_t)DMODEL * LDIM * 2);
    __bf16* xpool = (__bf16*)alloc((size_t)128 * DMODEL * 2);
    __bf16* GKb   = (__bf16*)alloc((size_t)128 * LDIM * 2);
    __bf16* GVb   = (__bf16*)alloc((size_t)128 * LDIM * 2);
    __bf16* localg= (__bf16*)alloc((size_t)BSROWS * DMODEL * 2);
    float*  grbuf = (float*) alloc((size_t)BSROWS * 16 * 4);
    __bf16* remb  = (__bf16*)alloc((size_t)BSROWS * LDIM * 2);
    __bf16* outpre = xb; // alias: xb dead after fused projection

    cvt_f32_to_bf16<<<dim3((BSROWS * DMODEL / 4 + 255) / 256), 256, 0, stream>>>(
        x, xb, BSROWS * DMODEL / 4);

    TJ8 jobs;
    jobs.j[0] = {wq,   wcatT,                 DMODEL, DMODEL};
    jobs.j[1] = {wk,   wcatT + 1024 * DMODEL, DMODEL, DMODEL};
    jobs.j[2] = {wv,   wcatT + 2048 * DMODEL, DMODEL, DMODEL};
    jobs.j[3] = {wgq,  wcatT + 3072 * DMODEL, DMODEL, LDIM};
    jobs.j[4] = {wout, woutT,                 DMODEL, DMODEL};
    jobs.j[5] = {wgk,  wgkT,                  DMODEL, LDIM};
    jobs.j[6] = {wgv,  wgvT,                  DMODEL, LDIM};
    jobs.j[7] = {rout, routT,                 LDIM,   DMODEL};
    transpose_cvt_all<<<dim3(32, 32, 8), dim3(32, 8), 0, stream>>>(jobs);

    pool_x_kernel<<<dim3(4, 128), 256, 0, stream>>>(xb, xpool);

    // fused [Q|K|V|GQ] projection via the 8-phase 256^2 GEMM; V n-tiles land
    // transposed in VtG (no separate transpose kernel, V region of QKVG unused)
    gemm256_bf16<<<dim3(32, 14), 512, 0, stream>>>(xb, wcatT, BSROWS, QKVN, DMODEL, QKVG, VtG);
    gemm_bf16<false, true><<<dim3(1, 4), 256, 0, stream>>>(xpool, wgkT, 128, LDIM, DMODEL, GKb, nullptr, nullptr, nullptr);
    gemm_bf16<false, true><<<dim3(1, 4), 256, 0, stream>>>(xpool, wgvT, 128, LDIM, DMODEL, GVb, nullptr, nullptr, nullptr);

    local_attn_mfma<<<dim3(16, 16, 2), 256, 0, stream>>>(QKVG, VtG, glw, grw, localg, grbuf);
    latent_attn_mfma<<<dim3(16, 8, 2), 256, 0, stream>>>(QKVG, GKb, GVb, remb);

    gemm_bf16<true, true><<<dim3(64, 8), 256, 0, stream>>>(remb, routT, BSROWS, DMODEL, LDIM, outpre, nullptr, localg, grbuf);
    gemm_bf16<false, false><<<dim3(64, 8), 256, 0, stream>>>(outpre, woutT, BSROWS, DMODEL, DMODEL, nullptr, (float*)d_out, nullptr, nullptr);
}

// Round 9
// 228.394 us; speedup vs baseline: 3.9956x; 1.0199x over previous
//
#include <hip/hip_runtime.h>

#define AS1 __attribute__((address_space(1)))
#define AS3 __attribute__((address_space(3)))

typedef float    f32x4  __attribute__((ext_vector_type(4)));
typedef __bf16   bf16x8 __attribute__((ext_vector_type(8)));
typedef __bf16   bf16x4 __attribute__((ext_vector_type(4)));
typedef unsigned int u32x4 __attribute__((ext_vector_type(4)));

static constexpr int SEQ = 4096, NBATCH = 2, DMODEL = 1024, NHEADS = 16, HDIM = 64;
static constexpr int LHEADS = 8, LDIM = 512, NLAT = 64, WIN = 256;
static constexpr int BSROWS = NBATCH * SEQ; // 8192
static constexpr int QKVN = 3584;           // fused [Q|K|V|GQ] column count
static constexpr int KOFF = 1024, VOFF = 2048, GQOFF = 3072;

// ---------------- fused f32->bf16 convert + 64-row mean-pool ----------------
// grid (128 bn-groups, 4 col-blocks) x 256 threads; thread owns one column.
__global__ __launch_bounds__(256) void cvt_pool_kernel(const float* __restrict__ x,
                                                       __bf16* __restrict__ xb,
                                                       __bf16* __restrict__ xpool) {
    int bn = blockIdx.x;                       // 0..127
    int c  = blockIdx.y * 256 + threadIdx.x;   // 0..1023
    const float* p = x + (size_t)bn * 64 * 1024 + c;
    __bf16* q = xb + (size_t)bn * 64 * 1024 + c;
    float s = 0.f;
    #pragma unroll 8
    for (int j = 0; j < 64; ++j) {
        float v = p[(size_t)j * 1024];
        q[(size_t)j * 1024] = (__bf16)v;
        s += v;
    }
    xpool[(size_t)bn * 1024 + c] = (__bf16)(s * 0.015625f);
}

// ---------------- all 8 weight transposes in ONE launch ----------------
struct TJ { const float* in; __bf16* out; int K; int N; };
struct TJ8 { TJ j[8]; };
__global__ void transpose_cvt_all(TJ8 jobs) {
    TJ jb = jobs.j[blockIdx.z];
    int k0 = blockIdx.x * 32, n0 = blockIdx.y * 32;
    if (k0 >= jb.K || n0 >= jb.N) return;
    __shared__ float tbuf[32][33];
    int tx = threadIdx.x, ty = threadIdx.y; // (32, 8)
    #pragma unroll
    for (int i = ty; i < 32; i += 8) tbuf[i][tx] = jb.in[(size_t)(k0 + i) * jb.N + n0 + tx];
    __syncthreads();
    #pragma unroll
    for (int i = ty; i < 32; i += 8) jb.out[(size_t)(n0 + i) * jb.K + k0 + tx] = (__bf16)tbuf[tx][i];
}

// ---------------- m97-style 128x128 GEMM (kept for small/N=1024 GEMMs) ----------------
template <bool EPI, bool OUTBF>
__global__ __launch_bounds__(256) void gemm_bf16(const __bf16* __restrict__ A,
                                                 const __bf16* __restrict__ Bt,
                                                 int M, int N, int K,
                                                 __bf16* __restrict__ outb,
                                                 float* __restrict__ outf,
                                                 const __bf16* __restrict__ lcl,
                                                 const float* __restrict__ grb) {
    __shared__ alignas(16) __bf16 sA[128 * 64];
    __shared__ alignas(16) __bf16 sB[128 * 64];
    int t = threadIdx.x, w = t >> 6, l = t & 63;
    int m0 = blockIdx.x * 128, n0 = blockIdx.y * 128;
    int wr = w >> 1, wc = w & 1;
    int lr = l & 15, lk = (l >> 4) * 8;

    f32x4 zero = {0.f, 0.f, 0.f, 0.f};
    f32x4 acc[4][4];
    #pragma unroll
    for (int a = 0; a < 4; ++a)
        #pragma unroll
        for (int b2 = 0; b2 < 4; ++b2) acc[a][b2] = zero;

    for (int kt = 0; kt < K; kt += 64) {
        #pragma unroll
        for (int c = 0; c < 4; ++c) {
            int lin  = w * 64 + c * 256;
            int linl = lin + l;
            int row = linl >> 3, c8 = (linl & 7) * 8;
            __builtin_amdgcn_global_load_lds(
                (const AS1 void*)(A + (size_t)(m0 + row) * K + kt + c8),
                (AS3 void*)((char*)sA + (size_t)lin * 16), 16, 0, 0);
            __builtin_amdgcn_global_load_lds(
                (const AS1 void*)(Bt + (size_t)(n0 + row) * K + kt + c8),
                (AS3 void*)((char*)sB + (size_t)lin * 16), 16, 0, 0);
        }
        __syncthreads();
        #pragma unroll
        for (int ks = 0; ks < 2; ++ks) {
            bf16x8 av[4], bv[4];
            #pragma unroll
            for (int mi = 0; mi < 4; ++mi)
                av[mi] = *(const bf16x8*)(sA + (wr * 64 + mi * 16 + lr) * 64 + ks * 32 + lk);
            #pragma unroll
            for (int ni = 0; ni < 4; ++ni)
                bv[ni] = *(const bf16x8*)(sB + (wc * 64 + ni * 16 + lr) * 64 + ks * 32 + lk);
            #pragma unroll
            for (int mi = 0; mi < 4; ++mi)
                #pragma unroll
                for (int ni = 0; ni < 4; ++ni)
                    acc[mi][ni] = __builtin_amdgcn_mfma_f32_16x16x32_bf16(
                        av[mi], bv[ni], acc[mi][ni], 0, 0, 0);
        }
        __syncthreads();
    }

    int cr = (l >> 4) * 4, cc = l & 15;
    #pragma unroll
    for (int mi = 0; mi < 4; ++mi) {
        #pragma unroll
        for (int ni = 0; ni < 4; ++ni) {
            int col = n0 + wc * 64 + ni * 16 + cc;
            #pragma unroll
            for (int r = 0; r < 4; ++r) {
                int row = m0 + wr * 64 + mi * 16 + cr + r;
                float v = acc[mi][ni][r];
                if constexpr (EPI) {
                    v = (float)lcl[(size_t)row * 1024 + col] +
                        grb[(size_t)row * 16 + (col >> 6)] * v;
                }
                if constexpr (OUTBF) outb[(size_t)row * N + col] = (__bf16)v;
                else                 outf[(size_t)row * N + col] = v;
            }
        }
    }
}

// ---------------- 256x256 8-phase GEMM (T2+T3+T4+T5), NT even, dims % 256 == 0 ----------------
// 512 threads = 8 waves; BK=64; LDS 128KB (2 bufs); swizzle byte ^= (row&7)<<4 (conflict-free,
// r7 PMC = 0). 2D grid. Fused V-transpose epilogue: n-tiles in [VOFF,GQOFF) write TRANSPOSED
// into Vt[b][c][s] as packed bf16x4 (4 consecutive ss = one 8B store; r8 WRITE inflation fix).
#define BAR() do { __builtin_amdgcn_sched_barrier(0); __builtin_amdgcn_s_barrier(); \
                   __builtin_amdgcn_sched_barrier(0); } while (0)
#define LGK0() do { asm volatile("s_waitcnt lgkmcnt(0)" ::: "memory"); \
                    __builtin_amdgcn_sched_barrier(0); } while (0)
#define VMC(n) do { asm volatile("s_waitcnt vmcnt(" #n ")" ::: "memory"); \
                    __builtin_amdgcn_sched_barrier(0); } while (0)
#define STG(gp, regionbase, rowbase, ktc) do { \
    int row_ = (rowbase) + (t >> 3); \
    int tc_ = (t & 7) ^ ((t >> 3) & 7); \
    __builtin_amdgcn_global_load_lds( \
        (const AS1 void*)((gp) + (size_t)row_ * K + (ktc) + tc_ * 8), \
        (AS3 void*)(lds + (regionbase) + (rowbase) * 128 + w * 1024), 16, 0, 0); \
} while (0)
#define LOADA(buf, qm) do { \
    _Pragma("unroll") for (int ai_ = 0; ai_ < 4; ++ai_) \
    _Pragma("unroll") for (int ks_ = 0; ks_ < 2; ++ks_) \
        a[ai_][ks_] = *(const bf16x8*)(lds + ((((buf) * 65536) + \
            (wm * 128 + (qm) * 64 + ai_ * 16 + l15) * 128 + ks_ * 64 + l4 * 16) ^ rswz)); \
} while (0)
#define LOADB2(buf, half) do { \
    _Pragma("unroll") for (int j_ = 0; j_ < 2; ++j_) \
    _Pragma("unroll") for (int ks_ = 0; ks_ < 2; ++ks_) \
        b2[j_][ks_] = *(const bf16x8*)(lds + ((((buf) * 65536 + 32768) + \
            (wn * 64 + ((half) * 2 + j_) * 16 + l15) * 128 + ks_ * 64 + l4 * 16) ^ rswz)); \
} while (0)
#define MFMA_PH(qm, half) do { \
    __builtin_amdgcn_s_setprio(1); \
    _Pragma("unroll") for (int ai_ = 0; ai_ < 4; ++ai_) \
    _Pragma("unroll") for (int j_ = 0; j_ < 2; ++j_) { \
        f32x4 c_ = acc[(qm) * 4 + ai_][(half) * 2 + j_]; \
        c_ = __builtin_amdgcn_mfma_f32_16x16x32_bf16(a[ai_][0], b2[j_][0], c_, 0, 0, 0); \
        c_ = __builtin_amdgcn_mfma_f32_16x16x32_bf16(a[ai_][1], b2[j_][1], c_, 0, 0, 0); \
        acc[(qm) * 4 + ai_][(half) * 2 + j_] = c_; \
    } \
    __builtin_amdgcn_s_setprio(0); \
} while (0)

__global__ __launch_bounds__(512, 2) void gemm256_bf16(
    const __bf16* __restrict__ A, const __bf16* __restrict__ Bt,
    int M, int N, int K, __bf16* __restrict__ outb, __bf16* __restrict__ Vt) {
    __shared__ char lds[131072];
    const int t = threadIdx.x, w = t >> 6, l = t & 63;
    const int wm = w >> 2, wn = w & 3;
    const int l15 = l & 15, l4 = l >> 4;
    const int m0 = blockIdx.x * 256, n0 = blockIdx.y * 256;
    const int NT = K >> 6;
    const int rswz = (l15 & 7) << 4;

    f32x4 acc[8][4];
    #pragma unroll
    for (int i = 0; i < 8; ++i)
        #pragma unroll
        for (int j = 0; j < 4; ++j) acc[i][j] = (f32x4){0.f, 0.f, 0.f, 0.f};
    bf16x8 a[4][2], b2[2][2];

    const __bf16* Ab = A + (size_t)m0 * K;
    const __bf16* Bb = Bt + (size_t)n0 * K;

    // prologue: tile 0 -> buf0 (Ae,Ao,B0,B1), then Ae(1) -> buf1 (kept in flight)
    STG(Ab, 0, 0, 0);        STG(Ab, 0, 128, 0);
    STG(Ab, 0, 64, 0);       STG(Ab, 0, 192, 0);
    STG(Bb, 32768, 0, 0);    STG(Bb, 32768, 64, 0);
    STG(Bb, 32768, 128, 0);  STG(Bb, 32768, 192, 0);
    STG(Ab, 65536, 0, 64);   STG(Ab, 65536, 128, 64);
    VMC(2); BAR();

    int it = 0;
    for (; it + 3 < NT; it += 2) {
        const int kt1 = (it + 1) << 6, kt2 = (it + 2) << 6, kt3 = (it + 3) << 6;
        // P1
        LOADA(0, 0); LOADB2(0, 0);
        STG(Ab, 65536, 64, kt1); STG(Ab, 65536, 192, kt1);
        BAR(); LGK0(); MFMA_PH(0, 0); BAR();
        // P2
        LOADB2(0, 1);
        STG(Bb, 98304, 0, kt1); STG(Bb, 98304, 64, kt1);
        BAR(); LGK0(); MFMA_PH(0, 1); BAR();
        // P3
        LOADA(0, 1); LOADB2(0, 0);
        STG(Bb, 98304, 128, kt1); STG(Bb, 98304, 192, kt1);
        BAR(); LGK0(); MFMA_PH(1, 0); BAR();
        // P4
        LOADB2(0, 1);
        STG(Ab, 0, 0, kt2); STG(Ab, 0, 128, kt2);
        BAR(); LGK0(); MFMA_PH(1, 1); VMC(2); BAR();
        // P5
        LOADA(1, 0); LOADB2(1, 0);
        STG(Ab, 0, 64, kt2); STG(Ab, 0, 192, kt2);
        BAR(); LGK0(); MFMA_PH(0, 0); BAR();
        // P6
        LOADB2(1, 1);
        STG(Bb, 32768, 0, kt2); STG(Bb, 32768, 64, kt2);
        BAR(); LGK0(); MFMA_PH(0, 1); BAR();
        // P7
        LOADA(1, 1); LOADB2(1, 0);
        STG(Bb, 32768, 128, kt2); STG(Bb, 32768, 192, kt2);
        BAR(); LGK0(); MFMA_PH(1, 0); BAR();
        // P8
        LOADB2(1, 1);
        STG(Ab, 65536, 0, kt3); STG(Ab, 65536, 128, kt3);
        BAR(); LGK0(); MFMA_PH(1, 1); VMC(2); BAR();
    }
    // final iteration (t = NT-2, t+1 = NT-1): stage only t+1 (P1-P3), drain at P4
    {
        const int kt1 = (it + 1) << 6;
        LOADA(0, 0); LOADB2(0, 0);
        STG(Ab, 65536, 64, kt1); STG(Ab, 65536, 192, kt1);
        BAR(); LGK0(); MFMA_PH(0, 0); BAR();
        LOADB2(0, 1);
        STG(Bb, 98304, 0, kt1); STG(Bb, 98304, 64, kt1);
        BAR(); LGK0(); MFMA_PH(0, 1); BAR();
        LOADA(0, 1); LOADB2(0, 0);
        STG(Bb, 98304, 128, kt1); STG(Bb, 98304, 192, kt1);
        BAR(); LGK0(); MFMA_PH(1, 0); BAR();
        LOADB2(0, 1);
        BAR(); LGK0(); MFMA_PH(1, 1); VMC(0); BAR();
        LOADA(1, 0); LOADB2(1, 0);
        BAR(); LGK0(); MFMA_PH(0, 0); BAR();
        LOADB2(1, 1);
        BAR(); LGK0(); MFMA_PH(0, 1); BAR();
        LOADA(1, 1); LOADB2(1, 0);
        BAR(); LGK0(); MFMA_PH(1, 0); BAR();
        LOADB2(1, 1);
        LGK0(); MFMA_PH(1, 1);
    }

    // epilogue (verified C/D mapping): V-tiles write transposed to Vt (packed 8B), else outb
    int cr = l4 * 4, cc = l15;
    if (Vt != nullptr && n0 >= VOFF && n0 < GQOFF) {
        #pragma unroll
        for (int mi = 0; mi < 8; ++mi) {
            #pragma unroll
            for (int ni = 0; ni < 4; ++ni) {
                int vcol = (n0 - VOFF) + wn * 64 + ni * 16 + cc;
                int row0 = m0 + wm * 128 + mi * 16 + cr;   // rows row0..row0+3, same batch
                int bb = row0 >> 12, ss = row0 & 4095;
                bf16x4 pk;
                #pragma unroll
                for (int r = 0; r < 4; ++r) pk[r] = (__bf16)acc[mi][ni][r];
                *(bf16x4*)(Vt + ((size_t)bb * DMODEL + vcol) * SEQ + ss) = pk;
            }
        }
    } else {
        #pragma unroll
        for (int mi = 0; mi < 8; ++mi) {
            #pragma unroll
            for (int ni = 0; ni < 4; ++ni) {
                int col = n0 + wn * 64 + ni * 16 + cc;
                #pragma unroll
                for (int r = 0; r < 4; ++r) {
                    int row = m0 + wm * 128 + mi * 16 + cr + r;
                    outb[(size_t)row * N + col] = (__bf16)acc[mi][ni][r];
                }
            }
        }
    }
}
#undef BAR
#undef LGK0
#undef VMC
#undef STG
#undef LOADA
#undef LOADB2
#undef MFMA_PH

// ---------------- fused attention: ONE dispatch for local + latent ----------------
// grid (16, 24, 2): blockIdx.y in [0,16) = local sliding-window head; [16,24) = latent
// head (lh = y-16). Bodies are the verified r5-r7 kernels verbatim; shared mem carved
// from one 80KB block (local: sKb 64K + sPb 16K; latent: sK 8K + sVt 8K + sPb 16K).
__global__ __launch_bounds__(256, 2) void attn_fused(
    const __bf16* __restrict__ QKVG, const __bf16* __restrict__ Vt,
    const __bf16* __restrict__ GK, const __bf16* __restrict__ GV,
    const float* __restrict__ glw, const float* __restrict__ grw,
    __bf16* __restrict__ outl, float* __restrict__ grbuf,
    __bf16* __restrict__ rem) {
    __shared__ alignas(16) char smem[81920];
    int t = threadIdx.x, w = t >> 6, l = t & 63;
    int l15 = l & 15, l4 = l >> 4;
    int b = blockIdx.z;
    f32x4 zero = {0.f, 0.f, 0.f, 0.f};

    if (blockIdx.y < 16) {
        // ======== local sliding-window attention ========
        int blk = blockIdx.x, h = blockIdx.y;
        char* sKb = smem;              // 512*128
        char* sPb = smem + 65536;      // 4*64*64

        bf16x8 qf[4][2];
        long qbase = (long)b * SEQ + blk * 256 + 64 * w;
        #pragma unroll
        for (int qq = 0; qq < 4; ++qq)
            #pragma unroll
            for (int ks = 0; ks < 2; ++ks)
                qf[qq][ks] = *(const bf16x8*)(QKVG + (size_t)(qbase + qq * 16 + l15) * QKVN
                                              + h * 64 + ks * 32 + l4 * 8);

        long g0 = (long)b * SEQ + (long)(blk - 1) * WIN;
        #pragma unroll
        for (int rep = 0; rep < 16; ++rep) {
            int ci = rep * 256 + t;
            int row = ci >> 3, c8 = (ci & 7) * 8;
            u32x4 kv = {0u, 0u, 0u, 0u};
            if (!(blk == 0 && row < 256))
                kv = *(const u32x4*)(QKVG + (size_t)(g0 + row) * QKVN + KOFF + h * 64 + c8);
            *(u32x4*)(sKb + row * 128 + ((c8 * 2) ^ ((row & 7) << 4))) = kv;
        }

        float dlp[4], drp[4];
        #pragma unroll
        for (int qq = 0; qq < 4; ++qq) {
            float dl = 0.f, dr = 0.f;
            #pragma unroll
            for (int ks = 0; ks < 2; ++ks) {
                const float* gp = glw + h * 64 + ks * 32 + l4 * 8;
                const float* rp = grw + h * 64 + ks * 32 + l4 * 8;
                #pragma unroll
                for (int j = 0; j < 8; ++j) {
                    float qv = (float)qf[qq][ks][j];
                    dl += qv * gp[j];
                    dr += qv * rp[j];
                }
            }
            dlp[qq] = dl; drp[qq] = dr;
        }
        float glv[4], grv[4];
        #pragma unroll
        for (int qq = 0; qq < 4; ++qq) {
            float dl = dlp[qq] + __shfl_xor(dlp[qq], 16);
            dl += __shfl_xor(dl, 32);
            float dr = drp[qq] + __shfl_xor(drp[qq], 16);
            dr += __shfl_xor(dr, 32);
            glv[qq] = 1.f / (1.f + __expf(-dl));
            grv[qq] = 1.f / (1.f + __expf(-dr));
        }
        if (l4 == 0) {
            #pragma unroll
            for (int qq = 0; qq < 4; ++qq)
                grbuf[(size_t)(qbase + qq * 16 + l15) * 16 + h] = grv[qq];
        }
        __syncthreads();

        f32x4 acc[4][4];
        #pragma unroll
        for (int a2 = 0; a2 < 4; ++a2)
            #pragma unroll
            for (int d = 0; d < 4; ++d) acc[a2][d] = zero;
        float psum[4] = {0.f, 0.f, 0.f, 0.f};

        char* sPw = sPb + w * 4096;
        int nsteps = (w == 3) ? 10 : 11;
        int kk0 = 64 * w;
        const __bf16* vtb = Vt + (size_t)b * DMODEL * SEQ + (size_t)(h * 64) * SEQ;

        for (int stp = 0; stp < nsteps; ++stp) {
            int kk = kk0 + 32 * stp;
            f32x4 sacc[2][4];
            #pragma unroll
            for (int kt2 = 0; kt2 < 2; ++kt2) {
                int krow = kk + kt2 * 16 + l15;
                int swz = (krow & 7) << 4;
                bf16x8 af0 = *(const bf16x8*)(sKb + krow * 128 + ((l4 * 16) ^ swz));
                bf16x8 af1 = *(const bf16x8*)(sKb + krow * 128 + ((64 + l4 * 16) ^ swz));
                #pragma unroll
                for (int qq = 0; qq < 4; ++qq) {
                    f32x4 s = __builtin_amdgcn_mfma_f32_16x16x32_bf16(af0, qf[qq][0], zero, 0, 0, 0);
                    sacc[kt2][qq] = __builtin_amdgcn_mfma_f32_16x16x32_bf16(af1, qf[qq][1], s, 0, 0, 0);
                }
            }
            #pragma unroll
            for (int qq = 0; qq < 4; ++qq) {
                int qloc = 64 * w + qq * 16 + l15;
                int prow = qq * 16 + l15;
                #pragma unroll
                for (int kt2 = 0; kt2 < 2; ++kt2) {
                    int jb = kk + kt2 * 16 + l4 * 4;
                    bf16x4 pb;
                    #pragma unroll
                    for (int r = 0; r < 4; ++r) {
                        int jw = jb + r;
                        bool act = (jw > qloc) && (jw <= qloc + 256) && (blk > 0 || jw >= 256);
                        float pv = act ? __expf(sacc[kt2][qq][r] * 0.125f) : 0.f;
                        psum[qq] += pv;
                        pb[r] = (__bf16)pv;
                    }
                    *(bf16x4*)(sPw + prow * 64 + ((kt2 * 32 + l4 * 8) ^ ((prow & 3) << 4))) = pb;
                }
            }
            int kglob = (blk - 1) * WIN + kk + l4 * 8;
            if (kglob < 0) kglob = 0;
            bf16x8 pa[4], bv[4];
            #pragma unroll
            for (int qq = 0; qq < 4; ++qq) {
                int prow = qq * 16 + l15;
                pa[qq] = *(const bf16x8*)(sPw + prow * 64 + ((l4 * 16) ^ ((prow & 3) << 4)));
            }
            #pragma unroll
            for (int dt = 0; dt < 4; ++dt)
                bv[dt] = *(const bf16x8*)(vtb + (size_t)(dt * 16 + l15) * SEQ + kglob);
            #pragma unroll
            for (int qq = 0; qq < 4; ++qq)
                #pragma unroll
                for (int dt = 0; dt < 4; ++dt)
                    acc[qq][dt] = __builtin_amdgcn_mfma_f32_16x16x32_bf16(pa[qq], bv[dt], acc[qq][dt], 0, 0, 0);
        }

        float cmb[4];
        #pragma unroll
        for (int qq = 0; qq < 4; ++qq) {
            float s = psum[qq] + __shfl_xor(psum[qq], 16);
            s += __shfl_xor(s, 32);
            cmb[qq] = glv[qq] / s;
        }
        #pragma unroll
        for (int qq = 0; qq < 4; ++qq) {
            #pragma unroll
            for (int r = 0; r < 4; ++r) {
                float sc = __shfl(cmb[qq], l4 * 4 + r, 64);
                size_t row = (size_t)(qbase + qq * 16 + l4 * 4 + r);
                __bf16* op = outl + row * DMODEL + h * 64 + l15;
                #pragma unroll
                for (int dt = 0; dt < 4; ++dt)
                    op[dt * 16] = (__bf16)(acc[qq][dt][r] * sc);
            }
        }
    } else {
        // ======== latent (remote) attention ========
        int sb = blockIdx.x, lh = blockIdx.y - 16;
        char* sK  = smem;              // 64*128
        char* sVt = smem + 8192;       // 64*128
        char* sPb = smem + 16384;      // 4*64*64

        bf16x8 qf[4][2];
        long qbase = (long)b * SEQ + sb * 256 + 64 * w;
        #pragma unroll
        for (int qq = 0; qq < 4; ++qq)
            #pragma unroll
            for (int ks = 0; ks < 2; ++ks)
                qf[qq][ks] = *(const bf16x8*)(QKVG + (size_t)(qbase + qq * 16 + l15) * QKVN
                                              + GQOFF + lh * 64 + ks * 32 + l4 * 8);

        #pragma unroll
        for (int rep = 0; rep < 2; ++rep) {
            int ci = rep * 256 + t;
            int row = ci >> 3, c8 = (ci & 7) * 8;
            u32x4 kv = *(const u32x4*)(GK + (size_t)(b * 64 + row) * LDIM + lh * 64 + c8);
            *(u32x4*)(sK + row * 128 + ((c8 * 2) ^ ((row & 7) << 4))) = kv;
        }
        #pragma unroll
        for (int rep = 0; rep < 16; ++rep) {
            int idx = rep * 256 + t;
            int d = idx & 63, n = idx >> 6;
            __bf16 v = GV[(size_t)(b * 64 + n) * LDIM + lh * 64 + d];
            *(__bf16*)(sVt + d * 128 + ((n * 2) ^ ((d & 7) << 4))) = v;
        }
        __syncthreads();

        f32x4 acc[4][4];
        #pragma unroll
        for (int a2 = 0; a2 < 4; ++a2)
            #pragma unroll
            for (int d = 0; d < 4; ++d) acc[a2][d] = zero;
        float psum[4] = {0.f, 0.f, 0.f, 0.f};

        char* sPw = sPb + w * 4096;
        int qloc0 = sb * 256 + 64 * w;

        #pragma unroll
        for (int stp = 0; stp < 2; ++stp) {
            int kk = 32 * stp;
            f32x4 sacc[2][4];
            #pragma unroll
            for (int kt2 = 0; kt2 < 2; ++kt2) {
                int krow = kk + kt2 * 16 + l15;
                int swz = (krow & 7) << 4;
                bf16x8 af0 = *(const bf16x8*)(sK + krow * 128 + ((l4 * 16) ^ swz));
                bf16x8 af1 = *(const bf16x8*)(sK + krow * 128 + ((64 + l4 * 16) ^ swz));
                #pragma unroll
                for (int qq = 0; qq < 4; ++qq) {
                    f32x4 s = __builtin_amdgcn_mfma_f32_16x16x32_bf16(af0, qf[qq][0], zero, 0, 0, 0);
                    sacc[kt2][qq] = __builtin_amdgcn_mfma_f32_16x16x32_bf16(af1, qf[qq][1], s, 0, 0, 0);
                }
            }
            #pragma unroll
            for (int qq = 0; qq < 4; ++qq) {
                int qdv = (qloc0 + qq * 16 + l15) >> 6;
                int prow = qq * 16 + l15;
                #pragma unroll
                for (int kt2 = 0; kt2 < 2; ++kt2) {
                    int nb = kk + kt2 * 16 + l4 * 4;
                    bf16x4 pb;
                    #pragma unroll
                    for (int r = 0; r < 4; ++r) {
                        int n = nb + r;
                        float pv = (n <= qdv) ? __expf(sacc[kt2][qq][r] * 0.125f) : 0.f;
                        psum[qq] += pv;
                        pb[r] = (__bf16)pv;
                    }
                    *(bf16x4*)(sPw + prow * 64 + ((kt2 * 32 + l4 * 8) ^ ((prow & 3) << 4))) = pb;
                }
            }
            bf16x8 pa[4], bv[4];
            #pragma unroll
            for (int qq = 0; qq < 4; ++qq) {
                int prow = qq * 16 + l15;
                pa[qq] = *(const bf16x8*)(sPw + prow * 64 + ((l4 * 16) ^ ((prow & 3) << 4)));
            }
            #pragma unroll
            for (int dt = 0; dt < 4; ++dt) {
                int d = dt * 16 + l15;
                bv[dt] = *(const bf16x8*)(sVt + d * 128 + ((kk * 2 + l4 * 16) ^ ((d & 7) << 4)));
            }
            #pragma unroll
            for (int qq = 0; qq < 4; ++qq)
                #pragma unroll
                for (int dt = 0; dt < 4; ++dt)
                    acc[qq][dt] = __builtin_amdgcn_mfma_f32_16x16x32_bf16(pa[qq], bv[dt], acc[qq][dt], 0, 0, 0);
        }

        float cmb[4];
        #pragma unroll
        for (int qq = 0; qq < 4; ++qq) {
            float s = psum[qq] + __shfl_xor(psum[qq], 16);
            s += __shfl_xor(s, 32);
            cmb[qq] = 1.f / s;
        }
        #pragma unroll
        for (int qq = 0; qq < 4; ++qq) {
            #pragma unroll
            for (int r = 0; r < 4; ++r) {
                float sc = __shfl(cmb[qq], l4 * 4 + r, 64);
                size_t row = (size_t)(qbase + qq * 16 + l4 * 4 + r);
                __bf16* op = rem + row * LDIM + lh * 64 + l15;
                #pragma unroll
                for (int dt = 0; dt < 4; ++dt)
                    op[dt * 16] = (__bf16)(acc[qq][dt][r] * sc);
            }
        }
    }
}

// ---------------- host launcher ----------------
extern "C" void kernel_launch(void* const* d_in, const int* in_sizes, int n_in,
                              void* d_out, int out_size, void* d_ws, size_t ws_size,
                              hipStream_t stream) {
    (void)in_sizes; (void)n_in; (void)out_size; (void)ws_size;
    const float* x    = (const float*)d_in[0];
    const float* wq   = (const float*)d_in[1];
    const float* wk   = (const float*)d_in[2];
    const float* wv   = (const float*)d_in[3];
    const float* wgq  = (const float*)d_in[4];
    const float* wgk  = (const float*)d_in[5];
    const float* wgv  = (const float*)d_in[6];
    const float* rout = (const float*)d_in[7];
    const float* glw  = (const float*)d_in[8];
    const float* grw  = (const float*)d_in[9];
    const float* wout = (const float*)d_in[10];

    char* p = (char*)d_ws;
    auto alloc = [&](size_t bytes) {
        char* r = p;
        p += (bytes + 255) & ~(size_t)255;
        return r;
    };
    __bf16* xb    = (__bf16*)alloc((size_t)BSROWS * DMODEL * 2);
    __bf16* QKVG  = (__bf16*)alloc((size_t)BSROWS * QKVN * 2);
    __bf16* VtG   = (__bf16*)alloc((size_t)BSROWS * DMODEL * 2);
    __bf16* wcatT = (__bf16*)alloc((size_t)QKVN * DMODEL * 2);
    __bf16* woutT = (__bf16*)alloc((size_t)DMODEL * DMODEL * 2);
    __bf16* wgkT  = (__bf16*)alloc((size_t)LDIM * DMODEL * 2);
    __bf16* wgvT  = (__bf16*)alloc((size_t)LDIM * DMODEL * 2);
    __bf16* routT = (__bf16*)alloc((size_t)DMODEL * LDIM * 2);
    __bf16* xpool = (__bf16*)alloc((size_t)128 * DMODEL * 2);
    __bf16* GKb   = (__bf16*)alloc((size_t)128 * LDIM * 2);
    __bf16* GVb   = (__bf16*)alloc((size_t)128 * LDIM * 2);
    __bf16* localg= (__bf16*)alloc((size_t)BSROWS * DMODEL * 2);
    float*  grbuf = (float*) alloc((size_t)BSROWS * 16 * 4);
    __bf16* remb  = (__bf16*)alloc((size_t)BSROWS * LDIM * 2);
    __bf16* outpre = xb; // alias: xb dead after fused projection

    cvt_pool_kernel<<<dim3(128, 4), 256, 0, stream>>>(x, xb, xpool);

    TJ8 jobs;
    jobs.j[0] = {wq,   wcatT,                 DMODEL, DMODEL};
    jobs.j[1] = {wk,   wcatT + 1024 * DMODEL, DMODEL, DMODEL};
    jobs.j[2] = {wv,   wcatT + 2048 * DMODEL, DMODEL, DMODEL};
    jobs.j[3] = {wgq,  wcatT + 3072 * DMODEL, DMODEL, LDIM};
    jobs.j[4] = {wout, woutT,                 DMODEL, DMODEL};
    jobs.j[5] = {wgk,  wgkT,                  DMODEL, LDIM};
    jobs.j[6] = {wgv,  wgvT,                  DMODEL, LDIM};
    jobs.j[7] = {rout, routT,                 LDIM,   DMODEL};
    transpose_cvt_all<<<dim3(32, 32, 8), dim3(32, 8), 0, stream>>>(jobs);

    // fused [Q|K|V|GQ] projection via the 8-phase 256^2 GEMM; V n-tiles land
    // transposed in VtG (packed 8B stores)
    gemm256_bf16<<<dim3(32, 14), 512, 0, stream>>>(xb, wcatT, BSROWS, QKVN, DMODEL, QKVG, VtG);
    gemm_bf16<false, true><<<dim3(1, 4), 256, 0, stream>>>(xpool, wgkT, 128, LDIM, DMODEL, GKb, nullptr, nullptr, nullptr);
    gemm_bf16<false, true><<<dim3(1, 4), 256, 0, stream>>>(xpool, wgvT, 128, LDIM, DMODEL, GVb, nullptr, nullptr, nullptr);

    // single fused attention dispatch (local y=0..15, latent y=16..23)
    attn_fused<<<dim3(16, 24, 2), 256, 0, stream>>>(QKVG, VtG, GKb, GVb, glw, grw,
                                                    localg, grbuf, remb);

    gemm_bf16<true, true><<<dim3(64, 8), 256, 0, stream>>>(remb, routT, BSROWS, DMODEL, LDIM, outpre, nullptr, localg, grbuf);
    gemm_bf16<false, false><<<dim3(64, 8), 256, 0, stream>>>(outpre, woutT, BSROWS, DMODEL, DMODEL, nullptr, (float*)d_out, nullptr, nullptr);
}

// Round 10
// 203.643 us; speedup vs baseline: 4.4812x; 1.1215x over previous
//
#include <hip/hip_runtime.h>

#define AS1 __attribute__((address_space(1)))
#define AS3 __attribute__((address_space(3)))

typedef float    f32x4  __attribute__((ext_vector_type(4)));
typedef __bf16   bf16x8 __attribute__((ext_vector_type(8)));
typedef __bf16   bf16x4 __attribute__((ext_vector_type(4)));
typedef unsigned int u32x4 __attribute__((ext_vector_type(4)));

static constexpr int SEQ = 4096, NBATCH = 2, DMODEL = 1024, NHEADS = 16, HDIM = 64;
static constexpr int LHEADS = 8, LDIM = 512, NLAT = 64, WIN = 256;
static constexpr int BSROWS = NBATCH * SEQ; // 8192
static constexpr int QKVN = 3584;           // fused [Q|K|V|GQ] column count
static constexpr int KOFF = 1024, VOFF = 2048, GQOFF = 3072;

// ---------------- ONE prep dispatch: cvt+pool (blocks 0..511) + 8 weight transposes ----------------
struct TJ { const float* in; __bf16* out; int K; int N; };
struct TJ8 { TJ j[8]; };
__global__ __launch_bounds__(256) void prep_all(const float* __restrict__ x,
                                                __bf16* __restrict__ xb,
                                                __bf16* __restrict__ xpool, TJ8 jobs) {
    __shared__ float tbuf[32][33];
    int bid = blockIdx.x, t = threadIdx.x;
    if (bid < 512) {
        // fused f32->bf16 convert + 64-row mean-pool (verified r8 body)
        int bn = bid >> 2;
        int c  = (bid & 3) * 256 + t;
        const float* p = x + (size_t)bn * 64 * 1024 + c;
        __bf16* q = xb + (size_t)bn * 64 * 1024 + c;
        float s = 0.f;
        #pragma unroll 8
        for (int j = 0; j < 64; ++j) {
            float v = p[(size_t)j * 1024];
            q[(size_t)j * 1024] = (__bf16)v;
            s += v;
        }
        xpool[(size_t)bn * 1024 + c] = (__bf16)(s * 0.015625f);
    } else {
        // weight transpose+convert (verified r6 body, flattened indexing)
        int ti = bid - 512;
        TJ jb = jobs.j[ti >> 10];
        int rem = ti & 1023;
        int k0 = (rem >> 5) * 32, n0 = (rem & 31) * 32;
        if (k0 >= jb.K || n0 >= jb.N) return;
        int tx = t & 31, ty = t >> 5; // (32, 8)
        #pragma unroll
        for (int i = ty; i < 32; i += 8) tbuf[i][tx] = jb.in[(size_t)(k0 + i) * jb.N + n0 + tx];
        __syncthreads();
        #pragma unroll
        for (int i = ty; i < 32; i += 8) jb.out[(size_t)(n0 + i) * jb.K + k0 + tx] = (__bf16)tbuf[tx][i];
    }
}

// ---------------- m97-style 128x128 GEMM (kept for small/N=1024 GEMMs) ----------------
template <bool EPI, bool OUTBF>
__global__ __launch_bounds__(256) void gemm_bf16(const __bf16* __restrict__ A,
                                                 const __bf16* __restrict__ Bt,
                                                 int M, int N, int K,
                                                 __bf16* __restrict__ outb,
                                                 float* __restrict__ outf,
                                                 const __bf16* __restrict__ lcl,
                                                 const float* __restrict__ grb) {
    __shared__ alignas(16) __bf16 sA[128 * 64];
    __shared__ alignas(16) __bf16 sB[128 * 64];
    int t = threadIdx.x, w = t >> 6, l = t & 63;
    int m0 = blockIdx.x * 128, n0 = blockIdx.y * 128;
    int wr = w >> 1, wc = w & 1;
    int lr = l & 15, lk = (l >> 4) * 8;

    f32x4 zero = {0.f, 0.f, 0.f, 0.f};
    f32x4 acc[4][4];
    #pragma unroll
    for (int a = 0; a < 4; ++a)
        #pragma unroll
        for (int b2 = 0; b2 < 4; ++b2) acc[a][b2] = zero;

    for (int kt = 0; kt < K; kt += 64) {
        #pragma unroll
        for (int c = 0; c < 4; ++c) {
            int lin  = w * 64 + c * 256;
            int linl = lin + l;
            int row = linl >> 3, c8 = (linl & 7) * 8;
            __builtin_amdgcn_global_load_lds(
                (const AS1 void*)(A + (size_t)(m0 + row) * K + kt + c8),
                (AS3 void*)((char*)sA + (size_t)lin * 16), 16, 0, 0);
            __builtin_amdgcn_global_load_lds(
                (const AS1 void*)(Bt + (size_t)(n0 + row) * K + kt + c8),
                (AS3 void*)((char*)sB + (size_t)lin * 16), 16, 0, 0);
        }
        __syncthreads();
        #pragma unroll
        for (int ks = 0; ks < 2; ++ks) {
            bf16x8 av[4], bv[4];
            #pragma unroll
            for (int mi = 0; mi < 4; ++mi)
                av[mi] = *(const bf16x8*)(sA + (wr * 64 + mi * 16 + lr) * 64 + ks * 32 + lk);
            #pragma unroll
            for (int ni = 0; ni < 4; ++ni)
                bv[ni] = *(const bf16x8*)(sB + (wc * 64 + ni * 16 + lr) * 64 + ks * 32 + lk);
            #pragma unroll
            for (int mi = 0; mi < 4; ++mi)
                #pragma unroll
                for (int ni = 0; ni < 4; ++ni)
                    acc[mi][ni] = __builtin_amdgcn_mfma_f32_16x16x32_bf16(
                        av[mi], bv[ni], acc[mi][ni], 0, 0, 0);
        }
        __syncthreads();
    }

    int cr = (l >> 4) * 4, cc = l & 15;
    #pragma unroll
    for (int mi = 0; mi < 4; ++mi) {
        #pragma unroll
        for (int ni = 0; ni < 4; ++ni) {
            int col = n0 + wc * 64 + ni * 16 + cc;
            #pragma unroll
            for (int r = 0; r < 4; ++r) {
                int row = m0 + wr * 64 + mi * 16 + cr + r;
                float v = acc[mi][ni][r];
                if constexpr (EPI) {
                    v = (float)lcl[(size_t)row * 1024 + col] +
                        grb[(size_t)row * 16 + (col >> 6)] * v;
                }
                if constexpr (OUTBF) outb[(size_t)row * N + col] = (__bf16)v;
                else                 outf[(size_t)row * N + col] = v;
            }
        }
    }
}

// ---------------- 256x256 8-phase GEMM (T2+T3+T4+T5), NT even, dims % 256 == 0 ----------------
// (verified r7-r9; conflict-free swizzle byte^=(row&7)<<4; fused V-transpose epilogue)
#define BAR() do { __builtin_amdgcn_sched_barrier(0); __builtin_amdgcn_s_barrier(); \
                   __builtin_amdgcn_sched_barrier(0); } while (0)
#define LGK0() do { asm volatile("s_waitcnt lgkmcnt(0)" ::: "memory"); \
                    __builtin_amdgcn_sched_barrier(0); } while (0)
#define VMC(n) do { asm volatile("s_waitcnt vmcnt(" #n ")" ::: "memory"); \
                    __builtin_amdgcn_sched_barrier(0); } while (0)
#define STG(gp, regionbase, rowbase, ktc) do { \
    int row_ = (rowbase) + (t >> 3); \
    int tc_ = (t & 7) ^ ((t >> 3) & 7); \
    __builtin_amdgcn_global_load_lds( \
        (const AS1 void*)((gp) + (size_t)row_ * K + (ktc) + tc_ * 8), \
        (AS3 void*)(lds + (regionbase) + (rowbase) * 128 + w * 1024), 16, 0, 0); \
} while (0)
#define LOADA(buf, qm) do { \
    _Pragma("unroll") for (int ai_ = 0; ai_ < 4; ++ai_) \
    _Pragma("unroll") for (int ks_ = 0; ks_ < 2; ++ks_) \
        a[ai_][ks_] = *(const bf16x8*)(lds + ((((buf) * 65536) + \
            (wm * 128 + (qm) * 64 + ai_ * 16 + l15) * 128 + ks_ * 64 + l4 * 16) ^ rswz)); \
} while (0)
#define LOADB2(buf, half) do { \
    _Pragma("unroll") for (int j_ = 0; j_ < 2; ++j_) \
    _Pragma("unroll") for (int ks_ = 0; ks_ < 2; ++ks_) \
        b2[j_][ks_] = *(const bf16x8*)(lds + ((((buf) * 65536 + 32768) + \
            (wn * 64 + ((half) * 2 + j_) * 16 + l15) * 128 + ks_ * 64 + l4 * 16) ^ rswz)); \
} while (0)
#define MFMA_PH(qm, half) do { \
    __builtin_amdgcn_s_setprio(1); \
    _Pragma("unroll") for (int ai_ = 0; ai_ < 4; ++ai_) \
    _Pragma("unroll") for (int j_ = 0; j_ < 2; ++j_) { \
        f32x4 c_ = acc[(qm) * 4 + ai_][(half) * 2 + j_]; \
        c_ = __builtin_amdgcn_mfma_f32_16x16x32_bf16(a[ai_][0], b2[j_][0], c_, 0, 0, 0); \
        c_ = __builtin_amdgcn_mfma_f32_16x16x32_bf16(a[ai_][1], b2[j_][1], c_, 0, 0, 0); \
        acc[(qm) * 4 + ai_][(half) * 2 + j_] = c_; \
    } \
    __builtin_amdgcn_s_setprio(0); \
} while (0)

__global__ __launch_bounds__(512, 2) void gemm256_bf16(
    const __bf16* __restrict__ A, const __bf16* __restrict__ Bt,
    int M, int N, int K, __bf16* __restrict__ outb, __bf16* __restrict__ Vt) {
    __shared__ char lds[131072];
    const int t = threadIdx.x, w = t >> 6, l = t & 63;
    const int wm = w >> 2, wn = w & 3;
    const int l15 = l & 15, l4 = l >> 4;
    const int m0 = blockIdx.x * 256, n0 = blockIdx.y * 256;
    const int NT = K >> 6;
    const int rswz = (l15 & 7) << 4;

    f32x4 acc[8][4];
    #pragma unroll
    for (int i = 0; i < 8; ++i)
        #pragma unroll
        for (int j = 0; j < 4; ++j) acc[i][j] = (f32x4){0.f, 0.f, 0.f, 0.f};
    bf16x8 a[4][2], b2[2][2];

    const __bf16* Ab = A + (size_t)m0 * K;
    const __bf16* Bb = Bt + (size_t)n0 * K;

    // prologue: tile 0 -> buf0 (Ae,Ao,B0,B1), then Ae(1) -> buf1 (kept in flight)
    STG(Ab, 0, 0, 0);        STG(Ab, 0, 128, 0);
    STG(Ab, 0, 64, 0);       STG(Ab, 0, 192, 0);
    STG(Bb, 32768, 0, 0);    STG(Bb, 32768, 64, 0);
    STG(Bb, 32768, 128, 0);  STG(Bb, 32768, 192, 0);
    STG(Ab, 65536, 0, 64);   STG(Ab, 65536, 128, 64);
    VMC(2); BAR();

    int it = 0;
    for (; it + 3 < NT; it += 2) {
        const int kt1 = (it + 1) << 6, kt2 = (it + 2) << 6, kt3 = (it + 3) << 6;
        // P1
        LOADA(0, 0); LOADB2(0, 0);
        STG(Ab, 65536, 64, kt1); STG(Ab, 65536, 192, kt1);
        BAR(); LGK0(); MFMA_PH(0, 0); BAR();
        // P2
        LOADB2(0, 1);
        STG(Bb, 98304, 0, kt1); STG(Bb, 98304, 64, kt1);
        BAR(); LGK0(); MFMA_PH(0, 1); BAR();
        // P3
        LOADA(0, 1); LOADB2(0, 0);
        STG(Bb, 98304, 128, kt1); STG(Bb, 98304, 192, kt1);
        BAR(); LGK0(); MFMA_PH(1, 0); BAR();
        // P4
        LOADB2(0, 1);
        STG(Ab, 0, 0, kt2); STG(Ab, 0, 128, kt2);
        BAR(); LGK0(); MFMA_PH(1, 1); VMC(2); BAR();
        // P5
        LOADA(1, 0); LOADB2(1, 0);
        STG(Ab, 0, 64, kt2); STG(Ab, 0, 192, kt2);
        BAR(); LGK0(); MFMA_PH(0, 0); BAR();
        // P6
        LOADB2(1, 1);
        STG(Bb, 32768, 0, kt2); STG(Bb, 32768, 64, kt2);
        BAR(); LGK0(); MFMA_PH(0, 1); BAR();
        // P7
        LOADA(1, 1); LOADB2(1, 0);
        STG(Bb, 32768, 128, kt2); STG(Bb, 32768, 192, kt2);
        BAR(); LGK0(); MFMA_PH(1, 0); BAR();
        // P8
        LOADB2(1, 1);
        STG(Ab, 65536, 0, kt3); STG(Ab, 65536, 128, kt3);
        BAR(); LGK0(); MFMA_PH(1, 1); VMC(2); BAR();
    }
    // final iteration (t = NT-2, t+1 = NT-1): stage only t+1 (P1-P3), drain at P4
    {
        const int kt1 = (it + 1) << 6;
        LOADA(0, 0); LOADB2(0, 0);
        STG(Ab, 65536, 64, kt1); STG(Ab, 65536, 192, kt1);
        BAR(); LGK0(); MFMA_PH(0, 0); BAR();
        LOADB2(0, 1);
        STG(Bb, 98304, 0, kt1); STG(Bb, 98304, 64, kt1);
        BAR(); LGK0(); MFMA_PH(0, 1); BAR();
        LOADA(0, 1); LOADB2(0, 0);
        STG(Bb, 98304, 128, kt1); STG(Bb, 98304, 192, kt1);
        BAR(); LGK0(); MFMA_PH(1, 0); BAR();
        LOADB2(0, 1);
        BAR(); LGK0(); MFMA_PH(1, 1); VMC(0); BAR();
        LOADA(1, 0); LOADB2(1, 0);
        BAR(); LGK0(); MFMA_PH(0, 0); BAR();
        LOADB2(1, 1);
        BAR(); LGK0(); MFMA_PH(0, 1); BAR();
        LOADA(1, 1); LOADB2(1, 0);
        BAR(); LGK0(); MFMA_PH(1, 0); BAR();
        LOADB2(1, 1);
        LGK0(); MFMA_PH(1, 1);
    }

    // epilogue (verified C/D mapping): V-tiles write transposed to Vt (packed 8B), else outb
    int cr = l4 * 4, cc = l15;
    if (Vt != nullptr && n0 >= VOFF && n0 < GQOFF) {
        #pragma unroll
        for (int mi = 0; mi < 8; ++mi) {
            #pragma unroll
            for (int ni = 0; ni < 4; ++ni) {
                int vcol = (n0 - VOFF) + wn * 64 + ni * 16 + cc;
                int row0 = m0 + wm * 128 + mi * 16 + cr;
                int bb = row0 >> 12, ss = row0 & 4095;
                bf16x4 pk;
                #pragma unroll
                for (int r = 0; r < 4; ++r) pk[r] = (__bf16)acc[mi][ni][r];
                *(bf16x4*)(Vt + ((size_t)bb * DMODEL + vcol) * SEQ + ss) = pk;
            }
        }
    } else {
        #pragma unroll
        for (int mi = 0; mi < 8; ++mi) {
            #pragma unroll
            for (int ni = 0; ni < 4; ++ni) {
                int col = n0 + wn * 64 + ni * 16 + cc;
                #pragma unroll
                for (int r = 0; r < 4; ++r) {
                    int row = m0 + wm * 128 + mi * 16 + cr + r;
                    outb[(size_t)row * N + col] = (__bf16)acc[mi][ni][r];
                }
            }
        }
    }
}
#undef BAR
#undef LGK0
#undef VMC
#undef STG
#undef LOADA
#undef LOADB2
#undef MFMA_PH

// ---------------- fused attention: ONE dispatch for local + latent ----------------
// grid (16, 24, 2): y<16 local head; y>=16 latent head (lh=y-16). GKV is the merged
// [128][1024] buffer: cols 0-511 = GK, 512-1023 = GV (row stride 1024).
__global__ __launch_bounds__(256, 2) void attn_fused(
    const __bf16* __restrict__ QKVG, const __bf16* __restrict__ Vt,
    const __bf16* __restrict__ GKV,
    const float* __restrict__ glw, const float* __restrict__ grw,
    __bf16* __restrict__ outl, float* __restrict__ grbuf,
    __bf16* __restrict__ rem) {
    __shared__ alignas(16) char smem[81920];
    int t = threadIdx.x, w = t >> 6, l = t & 63;
    int l15 = l & 15, l4 = l >> 4;
    int b = blockIdx.z;
    f32x4 zero = {0.f, 0.f, 0.f, 0.f};

    if (blockIdx.y < 16) {
        // ======== local sliding-window attention (verified r5-r9) ========
        int blk = blockIdx.x, h = blockIdx.y;
        char* sKb = smem;              // 512*128
        char* sPb = smem + 65536;      // 4*64*64

        bf16x8 qf[4][2];
        long qbase = (long)b * SEQ + blk * 256 + 64 * w;
        #pragma unroll
        for (int qq = 0; qq < 4; ++qq)
            #pragma unroll
            for (int ks = 0; ks < 2; ++ks)
                qf[qq][ks] = *(const bf16x8*)(QKVG + (size_t)(qbase + qq * 16 + l15) * QKVN
                                              + h * 64 + ks * 32 + l4 * 8);

        long g0 = (long)b * SEQ + (long)(blk - 1) * WIN;
        #pragma unroll
        for (int rep = 0; rep < 16; ++rep) {
            int ci = rep * 256 + t;
            int row = ci >> 3, c8 = (ci & 7) * 8;
            u32x4 kv = {0u, 0u, 0u, 0u};
            if (!(blk == 0 && row < 256))
                kv = *(const u32x4*)(QKVG + (size_t)(g0 + row) * QKVN + KOFF + h * 64 + c8);
            *(u32x4*)(sKb + row * 128 + ((c8 * 2) ^ ((row & 7) << 4))) = kv;
        }

        float dlp[4], drp[4];
        #pragma unroll
        for (int qq = 0; qq < 4; ++qq) {
            float dl = 0.f, dr = 0.f;
            #pragma unroll
            for (int ks = 0; ks < 2; ++ks) {
                const float* gp = glw + h * 64 + ks * 32 + l4 * 8;
                const float* rp = grw + h * 64 + ks * 32 + l4 * 8;
                #pragma unroll
                for (int j = 0; j < 8; ++j) {
                    float qv = (float)qf[qq][ks][j];
                    dl += qv * gp[j];
                    dr += qv * rp[j];
                }
            }
            dlp[qq] = dl; drp[qq] = dr;
        }
        float glv[4], grv[4];
        #pragma unroll
        for (int qq = 0; qq < 4; ++qq) {
            float dl = dlp[qq] + __shfl_xor(dlp[qq], 16);
            dl += __shfl_xor(dl, 32);
            float dr = drp[qq] + __shfl_xor(drp[qq], 16);
            dr += __shfl_xor(dr, 32);
            glv[qq] = 1.f / (1.f + __expf(-dl));
            grv[qq] = 1.f / (1.f + __expf(-dr));
        }
        if (l4 == 0) {
            #pragma unroll
            for (int qq = 0; qq < 4; ++qq)
                grbuf[(size_t)(qbase + qq * 16 + l15) * 16 + h] = grv[qq];
        }
        __syncthreads();

        f32x4 acc[4][4];
        #pragma unroll
        for (int a2 = 0; a2 < 4; ++a2)
            #pragma unroll
            for (int d = 0; d < 4; ++d) acc[a2][d] = zero;
        float psum[4] = {0.f, 0.f, 0.f, 0.f};

        char* sPw = sPb + w * 4096;
        int nsteps = (w == 3) ? 10 : 11;
        int kk0 = 64 * w;
        const __bf16* vtb = Vt + (size_t)b * DMODEL * SEQ + (size_t)(h * 64) * SEQ;

        for (int stp = 0; stp < nsteps; ++stp) {
            int kk = kk0 + 32 * stp;
            f32x4 sacc[2][4];
            #pragma unroll
            for (int kt2 = 0; kt2 < 2; ++kt2) {
                int krow = kk + kt2 * 16 + l15;
                int swz = (krow & 7) << 4;
                bf16x8 af0 = *(const bf16x8*)(sKb + krow * 128 + ((l4 * 16) ^ swz));
                bf16x8 af1 = *(const bf16x8*)(sKb + krow * 128 + ((64 + l4 * 16) ^ swz));
                #pragma unroll
                for (int qq = 0; qq < 4; ++qq) {
                    f32x4 s = __builtin_amdgcn_mfma_f32_16x16x32_bf16(af0, qf[qq][0], zero, 0, 0, 0);
                    sacc[kt2][qq] = __builtin_amdgcn_mfma_f32_16x16x32_bf16(af1, qf[qq][1], s, 0, 0, 0);
                }
            }
            #pragma unroll
            for (int qq = 0; qq < 4; ++qq) {
                int qloc = 64 * w + qq * 16 + l15;
                int prow = qq * 16 + l15;
                #pragma unroll
                for (int kt2 = 0; kt2 < 2; ++kt2) {
                    int jb = kk + kt2 * 16 + l4 * 4;
                    bf16x4 pb;
                    #pragma unroll
                    for (int r = 0; r < 4; ++r) {
                        int jw = jb + r;
                        bool act = (jw > qloc) && (jw <= qloc + 256) && (blk > 0 || jw >= 256);
                        float pv = act ? __expf(sacc[kt2][qq][r] * 0.125f) : 0.f;
                        psum[qq] += pv;
                        pb[r] = (__bf16)pv;
                    }
                    *(bf16x4*)(sPw + prow * 64 + ((kt2 * 32 + l4 * 8) ^ ((prow & 3) << 4))) = pb;
                }
            }
            int kglob = (blk - 1) * WIN + kk + l4 * 8;
            if (kglob < 0) kglob = 0;
            bf16x8 pa[4], bv[4];
            #pragma unroll
            for (int qq = 0; qq < 4; ++qq) {
                int prow = qq * 16 + l15;
                pa[qq] = *(const bf16x8*)(sPw + prow * 64 + ((l4 * 16) ^ ((prow & 3) << 4)));
            }
            #pragma unroll
            for (int dt = 0; dt < 4; ++dt)
                bv[dt] = *(const bf16x8*)(vtb + (size_t)(dt * 16 + l15) * SEQ + kglob);
            #pragma unroll
            for (int qq = 0; qq < 4; ++qq)
                #pragma unroll
                for (int dt = 0; dt < 4; ++dt)
                    acc[qq][dt] = __builtin_amdgcn_mfma_f32_16x16x32_bf16(pa[qq], bv[dt], acc[qq][dt], 0, 0, 0);
        }

        float cmb[4];
        #pragma unroll
        for (int qq = 0; qq < 4; ++qq) {
            float s = psum[qq] + __shfl_xor(psum[qq], 16);
            s += __shfl_xor(s, 32);
            cmb[qq] = glv[qq] / s;
        }
        #pragma unroll
        for (int qq = 0; qq < 4; ++qq) {
            #pragma unroll
            for (int r = 0; r < 4; ++r) {
                float sc = __shfl(cmb[qq], l4 * 4 + r, 64);
                size_t row = (size_t)(qbase + qq * 16 + l4 * 4 + r);
                __bf16* op = outl + row * DMODEL + h * 64 + l15;
                #pragma unroll
                for (int dt = 0; dt < 4; ++dt)
                    op[dt * 16] = (__bf16)(acc[qq][dt][r] * sc);
            }
        }
    } else {
        // ======== latent (remote) attention (verified r4-r9; GKV merged stride 1024) ========
        int sb = blockIdx.x, lh = blockIdx.y - 16;
        char* sK  = smem;              // 64*128
        char* sVt = smem + 8192;       // 64*128
        char* sPb = smem + 16384;      // 4*64*64

        bf16x8 qf[4][2];
        long qbase = (long)b * SEQ + sb * 256 + 64 * w;
        #pragma unroll
        for (int qq = 0; qq < 4; ++qq)
            #pragma unroll
            for (int ks = 0; ks < 2; ++ks)
                qf[qq][ks] = *(const bf16x8*)(QKVG + (size_t)(qbase + qq * 16 + l15) * QKVN
                                              + GQOFF + lh * 64 + ks * 32 + l4 * 8);

        #pragma unroll
        for (int rep = 0; rep < 2; ++rep) {
            int ci = rep * 256 + t;
            int row = ci >> 3, c8 = (ci & 7) * 8;
            u32x4 kv = *(const u32x4*)(GKV + (size_t)(b * 64 + row) * 1024 + lh * 64 + c8);
            *(u32x4*)(sK + row * 128 + ((c8 * 2) ^ ((row & 7) << 4))) = kv;
        }
        #pragma unroll
        for (int rep = 0; rep < 16; ++rep) {
            int idx = rep * 256 + t;
            int d = idx & 63, n = idx >> 6;
            __bf16 v = GKV[(size_t)(b * 64 + n) * 1024 + 512 + lh * 64 + d];
            *(__bf16*)(sVt + d * 128 + ((n * 2) ^ ((d & 7) << 4))) = v;
        }
        __syncthreads();

        f32x4 acc[4][4];
        #pragma unroll
        for (int a2 = 0; a2 < 4; ++a2)
            #pragma unroll
            for (int d = 0; d < 4; ++d) acc[a2][d] = zero;
        float psum[4] = {0.f, 0.f, 0.f, 0.f};

        char* sPw = sPb + w * 4096;
        int qloc0 = sb * 256 + 64 * w;

        #pragma unroll
        for (int stp = 0; stp < 2; ++stp) {
            int kk = 32 * stp;
            f32x4 sacc[2][4];
            #pragma unroll
            for (int kt2 = 0; kt2 < 2; ++kt2) {
                int krow = kk + kt2 * 16 + l15;
                int swz = (krow & 7) << 4;
                bf16x8 af0 = *(const bf16x8*)(sK + krow * 128 + ((l4 * 16) ^ swz));
                bf16x8 af1 = *(const bf16x8*)(sK + krow * 128 + ((64 + l4 * 16) ^ swz));
                #pragma unroll
                for (int qq = 0; qq < 4; ++qq) {
                    f32x4 s = __builtin_amdgcn_mfma_f32_16x16x32_bf16(af0, qf[qq][0], zero, 0, 0, 0);
                    sacc[kt2][qq] = __builtin_amdgcn_mfma_f32_16x16x32_bf16(af1, qf[qq][1], s, 0, 0, 0);
                }
            }
            #pragma unroll
            for (int qq = 0; qq < 4; ++qq) {
                int qdv = (qloc0 + qq * 16 + l15) >> 6;
                int prow = qq * 16 + l15;
                #pragma unroll
                for (int kt2 = 0; kt2 < 2; ++kt2) {
                    int nb = kk + kt2 * 16 + l4 * 4;
                    bf16x4 pb;
                    #pragma unroll
                    for (int r = 0; r < 4; ++r) {
                        int n = nb + r;
                        float pv = (n <= qdv) ? __expf(sacc[kt2][qq][r] * 0.125f) : 0.f;
                        psum[qq] += pv;
                        pb[r] = (__bf16)pv;
                    }
                    *(bf16x4*)(sPw + prow * 64 + ((kt2 * 32 + l4 * 8) ^ ((prow & 3) << 4))) = pb;
                }
            }
            bf16x8 pa[4], bv[4];
            #pragma unroll
            for (int qq = 0; qq < 4; ++qq) {
                int prow = qq * 16 + l15;
                pa[qq] = *(const bf16x8*)(sPw + prow * 64 + ((l4 * 16) ^ ((prow & 3) << 4)));
            }
            #pragma unroll
            for (int dt = 0; dt < 4; ++dt) {
                int d = dt * 16 + l15;
                bv[dt] = *(const bf16x8*)(sVt + d * 128 + ((kk * 2 + l4 * 16) ^ ((d & 7) << 4)));
            }
            #pragma unroll
            for (int qq = 0; qq < 4; ++qq)
                #pragma unroll
                for (int dt = 0; dt < 4; ++dt)
                    acc[qq][dt] = __builtin_amdgcn_mfma_f32_16x16x32_bf16(pa[qq], bv[dt], acc[qq][dt], 0, 0, 0);
        }

        float cmb[4];
        #pragma unroll
        for (int qq = 0; qq < 4; ++qq) {
            float s = psum[qq] + __shfl_xor(psum[qq], 16);
            s += __shfl_xor(s, 32);
            cmb[qq] = 1.f / s;
        }
        #pragma unroll
        for (int qq = 0; qq < 4; ++qq) {
            #pragma unroll
            for (int r = 0; r < 4; ++r) {
                float sc = __shfl(cmb[qq], l4 * 4 + r, 64);
                size_t row = (size_t)(qbase + qq * 16 + l4 * 4 + r);
                __bf16* op = rem + row * LDIM + lh * 64 + l15;
                #pragma unroll
                for (int dt = 0; dt < 4; ++dt)
                    op[dt * 16] = (__bf16)(acc[qq][dt][r] * sc);
            }
        }
    }
}

// ---------------- host launcher ----------------
extern "C" void kernel_launch(void* const* d_in, const int* in_sizes, int n_in,
                              void* d_out, int out_size, void* d_ws, size_t ws_size,
                              hipStream_t stream) {
    (void)in_sizes; (void)n_in; (void)out_size; (void)ws_size;
    const float* x    = (const float*)d_in[0];
    const float* wq   = (const float*)d_in[1];
    const float* wk   = (const float*)d_in[2];
    const float* wv   = (const float*)d_in[3];
    const float* wgq  = (const float*)d_in[4];
    const float* wgk  = (const float*)d_in[5];
    const float* wgv  = (const float*)d_in[6];
    const float* rout = (const float*)d_in[7];
    const float* glw  = (const float*)d_in[8];
    const float* grw  = (const float*)d_in[9];
    const float* wout = (const float*)d_in[10];

    char* p = (char*)d_ws;
    auto alloc = [&](size_t bytes) {
        char* r = p;
        p += (bytes + 255) & ~(size_t)255;
        return r;
    };
    __bf16* xb    = (__bf16*)alloc((size_t)BSROWS * DMODEL * 2);
    __bf16* QKVG  = (__bf16*)alloc((size_t)BSROWS * QKVN * 2);
    __bf16* VtG   = (__bf16*)alloc((size_t)BSROWS * DMODEL * 2);
    __bf16* wcatT = (__bf16*)alloc((size_t)QKVN * DMODEL * 2);
    __bf16* woutT = (__bf16*)alloc((size_t)DMODEL * DMODEL * 2);
    __bf16* wgkvT = (__bf16*)alloc((size_t)1024 * DMODEL * 2);   // [wgkT | wgvT]
    __bf16* routT = (__bf16*)alloc((size_t)DMODEL * LDIM * 2);
    __bf16* xpool = (__bf16*)alloc((size_t)128 * DMODEL * 2);
    __bf16* GKVb  = (__bf16*)alloc((size_t)128 * 1024 * 2);      // [GK | GV]
    __bf16* localg= (__bf16*)alloc((size_t)BSROWS * DMODEL * 2);
    float*  grbuf = (float*) alloc((size_t)BSROWS * 16 * 4);
    __bf16* remb  = (__bf16*)alloc((size_t)BSROWS * LDIM * 2);
    __bf16* outpre = xb; // alias: xb dead after fused projection

    TJ8 jobs;
    jobs.j[0] = {wq,   wcatT,                 DMODEL, DMODEL};
    jobs.j[1] = {wk,   wcatT + 1024 * DMODEL, DMODEL, DMODEL};
    jobs.j[2] = {wv,   wcatT + 2048 * DMODEL, DMODEL, DMODEL};
    jobs.j[3] = {wgq,  wcatT + 3072 * DMODEL, DMODEL, LDIM};
    jobs.j[4] = {wout, woutT,                 DMODEL, DMODEL};
    jobs.j[5] = {wgk,  wgkvT,                 DMODEL, LDIM};
    jobs.j[6] = {wgv,  wgkvT + 512 * DMODEL,  DMODEL, LDIM};
    jobs.j[7] = {rout, routT,                 LDIM,   DMODEL};

    // ONE prep dispatch: cvt+pool (512 blocks) + all transposes (8192 blocks)
    prep_all<<<dim3(512 + 8192), 256, 0, stream>>>(x, xb, xpool, jobs);

    // fused [Q|K|V|GQ] projection via the 8-phase 256^2 GEMM; V n-tiles land
    // transposed in VtG (packed 8B stores)
    gemm256_bf16<<<dim3(32, 14), 512, 0, stream>>>(xb, wcatT, BSROWS, QKVN, DMODEL, QKVG, VtG);
    // merged GK|GV projection (one 8-block dispatch)
    gemm_bf16<false, true><<<dim3(1, 8), 256, 0, stream>>>(xpool, wgkvT, 128, 1024, DMODEL, GKVb, nullptr, nullptr, nullptr);

    // single fused attention dispatch (local y=0..15, latent y=16..23)
    attn_fused<<<dim3(16, 24, 2), 256, 0, stream>>>(QKVG, VtG, GKVb, glw, grw,
                                                    localg, grbuf, remb);

    gemm_bf16<true, true><<<dim3(64, 8), 256, 0, stream>>>(remb, routT, BSROWS, DMODEL, LDIM, outpre, nullptr, localg, grbuf);
    gemm_bf16<false, false><<<dim3(64, 8), 256, 0, stream>>>(outpre, woutT, BSROWS, DMODEL, DMODEL, nullptr, (float*)d_out, nullptr, nullptr);
}

// Round 11
// 176.324 us; speedup vs baseline: 5.1755x; 1.1549x over previous
//
#include <hip/hip_runtime.h>

#define AS1 __attribute__((address_space(1)))
#define AS3 __attribute__((address_space(3)))

typedef float    f32x4  __attribute__((ext_vector_type(4)));
typedef __bf16   bf16x8 __attribute__((ext_vector_type(8)));
typedef __bf16   bf16x4 __attribute__((ext_vector_type(4)));
typedef unsigned int u32x4 __attribute__((ext_vector_type(4)));

static constexpr int SEQ = 4096, NBATCH = 2, DMODEL = 1024, NHEADS = 16, HDIM = 64;
static constexpr int LHEADS = 8, LDIM = 512, NLAT = 64, WIN = 256;
static constexpr int BSROWS = NBATCH * SEQ; // 8192
static constexpr int QKVN = 3584;           // fused [Q|K|V|GQ] column count
static constexpr int KOFF = 1024, VOFF = 2048, GQOFF = 3072;

// ---------------- ONE prep dispatch: cvt+pool + 8 weight transposes + xpool pad-zero ----------------
struct TJ { const float* in; __bf16* out; int K; int N; };
struct TJ8 { TJ j[8]; };
__global__ __launch_bounds__(256) void prep_all(const float* __restrict__ x,
                                                __bf16* __restrict__ xb,
                                                __bf16* __restrict__ xpool, TJ8 jobs) {
    __shared__ float tbuf[32][33];
    int bid = blockIdx.x, t = threadIdx.x;
    if (bid < 512) {
        // fused f32->bf16 convert + 64-row mean-pool (verified r8-r10 body)
        int bn = bid >> 2;
        int c  = (bid & 3) * 256 + t;
        const float* p = x + (size_t)bn * 64 * 1024 + c;
        __bf16* q = xb + (size_t)bn * 64 * 1024 + c;
        float s = 0.f;
        #pragma unroll 8
        for (int j = 0; j < 64; ++j) {
            float v = p[(size_t)j * 1024];
            q[(size_t)j * 1024] = (__bf16)v;
            s += v;
        }
        xpool[(size_t)bn * 1024 + c] = (__bf16)(s * 0.015625f);
    } else if (bid < 8704) {
        // weight transpose+convert (verified r6-r10 body, flattened indexing)
        int ti = bid - 512;
        TJ jb = jobs.j[ti >> 10];
        int rem = ti & 1023;
        int k0 = (rem >> 5) * 32, n0 = (rem & 31) * 32;
        if (k0 >= jb.K || n0 >= jb.N) return;
        int tx = t & 31, ty = t >> 5; // (32, 8)
        #pragma unroll
        for (int i = ty; i < 32; i += 8) tbuf[i][tx] = jb.in[(size_t)(k0 + i) * jb.N + n0 + tx];
        __syncthreads();
        #pragma unroll
        for (int i = ty; i < 32; i += 8) jb.out[(size_t)(n0 + i) * jb.K + k0 + tx] = (__bf16)tbuf[tx][i];
    } else {
        // zero xpool pad rows 128..255 (for the 256-row GKV tile in gemm256)
        int zi = bid - 8704;                 // 0..31
        size_t idx = ((size_t)zi * 256 + t) * 16;
        u32x4 z = {0u, 0u, 0u, 0u};
        *(u32x4*)(xpool + 128 * 1024 + idx)     = z;
        *(u32x4*)(xpool + 128 * 1024 + idx + 8) = z;
    }
}

// ---------------- m97-style 128x128 GEMM (kept for the two N=1024 GEMMs) ----------------
template <bool EPI, bool OUTBF>
__global__ __launch_bounds__(256) void gemm_bf16(const __bf16* __restrict__ A,
                                                 const __bf16* __restrict__ Bt,
                                                 int M, int N, int K,
                                                 __bf16* __restrict__ outb,
                                                 float* __restrict__ outf,
                                                 const __bf16* __restrict__ lcl,
                                                 const float* __restrict__ grb) {
    __shared__ alignas(16) __bf16 sA[128 * 64];
    __shared__ alignas(16) __bf16 sB[128 * 64];
    int t = threadIdx.x, w = t >> 6, l = t & 63;
    int m0 = blockIdx.x * 128, n0 = blockIdx.y * 128;
    int wr = w >> 1, wc = w & 1;
    int lr = l & 15, lk = (l >> 4) * 8;

    f32x4 zero = {0.f, 0.f, 0.f, 0.f};
    f32x4 acc[4][4];
    #pragma unroll
    for (int a = 0; a < 4; ++a)
        #pragma unroll
        for (int b2 = 0; b2 < 4; ++b2) acc[a][b2] = zero;

    for (int kt = 0; kt < K; kt += 64) {
        #pragma unroll
        for (int c = 0; c < 4; ++c) {
            int lin  = w * 64 + c * 256;
            int linl = lin + l;
            int row = linl >> 3, c8 = (linl & 7) * 8;
            __builtin_amdgcn_global_load_lds(
                (const AS1 void*)(A + (size_t)(m0 + row) * K + kt + c8),
                (AS3 void*)((char*)sA + (size_t)lin * 16), 16, 0, 0);
            __builtin_amdgcn_global_load_lds(
                (const AS1 void*)(Bt + (size_t)(n0 + row) * K + kt + c8),
                (AS3 void*)((char*)sB + (size_t)lin * 16), 16, 0, 0);
        }
        __syncthreads();
        #pragma unroll
        for (int ks = 0; ks < 2; ++ks) {
            bf16x8 av[4], bv[4];
            #pragma unroll
            for (int mi = 0; mi < 4; ++mi)
                av[mi] = *(const bf16x8*)(sA + (wr * 64 + mi * 16 + lr) * 64 + ks * 32 + lk);
            #pragma unroll
            for (int ni = 0; ni < 4; ++ni)
                bv[ni] = *(const bf16x8*)(sB + (wc * 64 + ni * 16 + lr) * 64 + ks * 32 + lk);
            #pragma unroll
            for (int mi = 0; mi < 4; ++mi)
                #pragma unroll
                for (int ni = 0; ni < 4; ++ni)
                    acc[mi][ni] = __builtin_amdgcn_mfma_f32_16x16x32_bf16(
                        av[mi], bv[ni], acc[mi][ni], 0, 0, 0);
        }
        __syncthreads();
    }

    int cr = (l >> 4) * 4, cc = l & 15;
    #pragma unroll
    for (int mi = 0; mi < 4; ++mi) {
        #pragma unroll
        for (int ni = 0; ni < 4; ++ni) {
            int col = n0 + wc * 64 + ni * 16 + cc;
            #pragma unroll
            for (int r = 0; r < 4; ++r) {
                int row = m0 + wr * 64 + mi * 16 + cr + r;
                float v = acc[mi][ni][r];
                if constexpr (EPI) {
                    v = (float)lcl[(size_t)row * 1024 + col] +
                        grb[(size_t)row * 16 + (col >> 6)] * v;
                }
                if constexpr (OUTBF) outb[(size_t)row * N + col] = (__bf16)v;
                else                 outf[(size_t)row * N + col] = v;
            }
        }
    }
}

// ---------------- 256x256 8-phase GEMM (T2+T3+T4+T5) + GKV side-row ----------------
// (verified r7-r10; conflict-free swizzle byte^=(row&7)<<4; fused V-transpose epilogue)
// Extra grid row y==14 (4 active blocks): GKV projection xpool_pad[256][1024] @ wgkvT.
#define BAR() do { __builtin_amdgcn_sched_barrier(0); __builtin_amdgcn_s_barrier(); \
                   __builtin_amdgcn_sched_barrier(0); } while (0)
#define LGK0() do { asm volatile("s_waitcnt lgkmcnt(0)" ::: "memory"); \
                    __builtin_amdgcn_sched_barrier(0); } while (0)
#define VMC(n) do { asm volatile("s_waitcnt vmcnt(" #n ")" ::: "memory"); \
                    __builtin_amdgcn_sched_barrier(0); } while (0)
#define STG(gp, regionbase, rowbase, ktc) do { \
    int row_ = (rowbase) + (t >> 3); \
    int tc_ = (t & 7) ^ ((t >> 3) & 7); \
    __builtin_amdgcn_global_load_lds( \
        (const AS1 void*)((gp) + (size_t)row_ * K + (ktc) + tc_ * 8), \
        (AS3 void*)(lds + (regionbase) + (rowbase) * 128 + w * 1024), 16, 0, 0); \
} while (0)
#define LOADA(buf, qm) do { \
    _Pragma("unroll") for (int ai_ = 0; ai_ < 4; ++ai_) \
    _Pragma("unroll") for (int ks_ = 0; ks_ < 2; ++ks_) \
        a[ai_][ks_] = *(const bf16x8*)(lds + ((((buf) * 65536) + \
            (wm * 128 + (qm) * 64 + ai_ * 16 + l15) * 128 + ks_ * 64 + l4 * 16) ^ rswz)); \
} while (0)
#define LOADB2(buf, half) do { \
    _Pragma("unroll") for (int j_ = 0; j_ < 2; ++j_) \
    _Pragma("unroll") for (int ks_ = 0; ks_ < 2; ++ks_) \
        b2[j_][ks_] = *(const bf16x8*)(lds + ((((buf) * 65536 + 32768) + \
            (wn * 64 + ((half) * 2 + j_) * 16 + l15) * 128 + ks_ * 64 + l4 * 16) ^ rswz)); \
} while (0)
#define MFMA_PH(qm, half) do { \
    __builtin_amdgcn_s_setprio(1); \
    _Pragma("unroll") for (int ai_ = 0; ai_ < 4; ++ai_) \
    _Pragma("unroll") for (int j_ = 0; j_ < 2; ++j_) { \
        f32x4 c_ = acc[(qm) * 4 + ai_][(half) * 2 + j_]; \
        c_ = __builtin_amdgcn_mfma_f32_16x16x32_bf16(a[ai_][0], b2[j_][0], c_, 0, 0, 0); \
        c_ = __builtin_amdgcn_mfma_f32_16x16x32_bf16(a[ai_][1], b2[j_][1], c_, 0, 0, 0); \
        acc[(qm) * 4 + ai_][(half) * 2 + j_] = c_; \
    } \
    __builtin_amdgcn_s_setprio(0); \
} while (0)

__global__ __launch_bounds__(512, 2) void gemm256_bf16(
    const __bf16* __restrict__ A, const __bf16* __restrict__ Bt,
    int M, int N, int K, __bf16* __restrict__ outb, __bf16* __restrict__ Vt,
    const __bf16* __restrict__ A2, const __bf16* __restrict__ B2,
    __bf16* __restrict__ out2) {
    __shared__ char lds[131072];
    const int t = threadIdx.x, w = t >> 6, l = t & 63;
    const int wm = w >> 2, wn = w & 3;
    const int l15 = l & 15, l4 = l >> 4;
    const int NT = K >> 6;
    const int rswz = (l15 & 7) << 4;

    const __bf16* Ab; const __bf16* Bb; __bf16* outp; int Nout, m0, n0; bool doVt;
    if (blockIdx.y == 14) {
        if (blockIdx.x >= 4) return;      // whole block exits; no barrier hazard
        m0 = 0; n0 = blockIdx.x * 256;
        Ab = A2; Bb = B2 + (size_t)n0 * K;
        outp = out2; Nout = 1024; doVt = false;
    } else {
        m0 = blockIdx.x * 256; n0 = blockIdx.y * 256;
        Ab = A + (size_t)m0 * K; Bb = Bt + (size_t)n0 * K;
        outp = outb; Nout = N; doVt = (n0 >= VOFF && n0 < GQOFF);
    }

    f32x4 acc[8][4];
    #pragma unroll
    for (int i = 0; i < 8; ++i)
        #pragma unroll
        for (int j = 0; j < 4; ++j) acc[i][j] = (f32x4){0.f, 0.f, 0.f, 0.f};
    bf16x8 a[4][2], b2[2][2];

    // prologue: tile 0 -> buf0 (Ae,Ao,B0,B1), then Ae(1) -> buf1 (kept in flight)
    STG(Ab, 0, 0, 0);        STG(Ab, 0, 128, 0);
    STG(Ab, 0, 64, 0);       STG(Ab, 0, 192, 0);
    STG(Bb, 32768, 0, 0);    STG(Bb, 32768, 64, 0);
    STG(Bb, 32768, 128, 0);  STG(Bb, 32768, 192, 0);
    STG(Ab, 65536, 0, 64);   STG(Ab, 65536, 128, 64);
    VMC(2); BAR();

    int it = 0;
    for (; it + 3 < NT; it += 2) {
        const int kt1 = (it + 1) << 6, kt2 = (it + 2) << 6, kt3 = (it + 3) << 6;
        // P1
        LOADA(0, 0); LOADB2(0, 0);
        STG(Ab, 65536, 64, kt1); STG(Ab, 65536, 192, kt1);
        BAR(); LGK0(); MFMA_PH(0, 0); BAR();
        // P2
        LOADB2(0, 1);
        STG(Bb, 98304, 0, kt1); STG(Bb, 98304, 64, kt1);
        BAR(); LGK0(); MFMA_PH(0, 1); BAR();
        // P3
        LOADA(0, 1); LOADB2(0, 0);
        STG(Bb, 98304, 128, kt1); STG(Bb, 98304, 192, kt1);
        BAR(); LGK0(); MFMA_PH(1, 0); BAR();
        // P4
        LOADB2(0, 1);
        STG(Ab, 0, 0, kt2); STG(Ab, 0, 128, kt2);
        BAR(); LGK0(); MFMA_PH(1, 1); VMC(2); BAR();
        // P5
        LOADA(1, 0); LOADB2(1, 0);
        STG(Ab, 0, 64, kt2); STG(Ab, 0, 192, kt2);
        BAR(); LGK0(); MFMA_PH(0, 0); BAR();
        // P6
        LOADB2(1, 1);
        STG(Bb, 32768, 0, kt2); STG(Bb, 32768, 64, kt2);
        BAR(); LGK0(); MFMA_PH(0, 1); BAR();
        // P7
        LOADA(1, 1); LOADB2(1, 0);
        STG(Bb, 32768, 128, kt2); STG(Bb, 32768, 192, kt2);
        BAR(); LGK0(); MFMA_PH(1, 0); BAR();
        // P8
        LOADB2(1, 1);
        STG(Ab, 65536, 0, kt3); STG(Ab, 65536, 128, kt3);
        BAR(); LGK0(); MFMA_PH(1, 1); VMC(2); BAR();
    }
    // final iteration (t = NT-2, t+1 = NT-1): stage only t+1 (P1-P3), drain at P4
    {
        const int kt1 = (it + 1) << 6;
        LOADA(0, 0); LOADB2(0, 0);
        STG(Ab, 65536, 64, kt1); STG(Ab, 65536, 192, kt1);
        BAR(); LGK0(); MFMA_PH(0, 0); BAR();
        LOADB2(0, 1);
        STG(Bb, 98304, 0, kt1); STG(Bb, 98304, 64, kt1);
        BAR(); LGK0(); MFMA_PH(0, 1); BAR();
        LOADA(0, 1); LOADB2(0, 0);
        STG(Bb, 98304, 128, kt1); STG(Bb, 98304, 192, kt1);
        BAR(); LGK0(); MFMA_PH(1, 0); BAR();
        LOADB2(0, 1);
        BAR(); LGK0(); MFMA_PH(1, 1); VMC(0); BAR();
        LOADA(1, 0); LOADB2(1, 0);
        BAR(); LGK0(); MFMA_PH(0, 0); BAR();
        LOADB2(1, 1);
        BAR(); LGK0(); MFMA_PH(0, 1); BAR();
        LOADA(1, 1); LOADB2(1, 0);
        BAR(); LGK0(); MFMA_PH(1, 0); BAR();
        LOADB2(1, 1);
        LGK0(); MFMA_PH(1, 1);
    }

    // epilogue (verified C/D mapping): V-tiles write transposed to Vt (packed 8B), else outp
    int cr = l4 * 4, cc = l15;
    if (doVt) {
        #pragma unroll
        for (int mi = 0; mi < 8; ++mi) {
            #pragma unroll
            for (int ni = 0; ni < 4; ++ni) {
                int vcol = (n0 - VOFF) + wn * 64 + ni * 16 + cc;
                int row0 = m0 + wm * 128 + mi * 16 + cr;
                int bb = row0 >> 12, ss = row0 & 4095;
                bf16x4 pk;
                #pragma unroll
                for (int r = 0; r < 4; ++r) pk[r] = (__bf16)acc[mi][ni][r];
                *(bf16x4*)(Vt + ((size_t)bb * DMODEL + vcol) * SEQ + ss) = pk;
            }
        }
    } else {
        #pragma unroll
        for (int mi = 0; mi < 8; ++mi) {
            #pragma unroll
            for (int ni = 0; ni < 4; ++ni) {
                int col = n0 + wn * 64 + ni * 16 + cc;
                #pragma unroll
                for (int r = 0; r < 4; ++r) {
                    int row = m0 + wm * 128 + mi * 16 + cr + r;
                    outp[(size_t)row * Nout + col] = (__bf16)acc[mi][ni][r];
                }
            }
        }
    }
}
#undef BAR
#undef LGK0
#undef VMC
#undef STG
#undef LOADA
#undef LOADB2
#undef MFMA_PH

// ---------------- fused attention: ONE dispatch for local + latent ----------------
// grid (16, 24, 2): y<16 local head; y>=16 latent head (lh=y-16). Local branch now
// reads BOTH K and V fragments direct from global (r5 V-direct precedent) -> LDS
// 80KB -> 32KB (sP only), no barriers in local path, occupancy 2 -> 3 blocks/CU.
__global__ __launch_bounds__(256, 2) void attn_fused(
    const __bf16* __restrict__ QKVG, const __bf16* __restrict__ Vt,
    const __bf16* __restrict__ GKV,
    const float* __restrict__ glw, const float* __restrict__ grw,
    __bf16* __restrict__ outl, float* __restrict__ grbuf,
    __bf16* __restrict__ rem) {
    __shared__ alignas(16) char smem[32768];
    int t = threadIdx.x, w = t >> 6, l = t & 63;
    int l15 = l & 15, l4 = l >> 4;
    int b = blockIdx.z;
    f32x4 zero = {0.f, 0.f, 0.f, 0.f};

    if (blockIdx.y < 16) {
        // ======== local sliding-window attention (K-direct + V-direct) ========
        int blk = blockIdx.x, h = blockIdx.y;
        char* sPb = smem;              // 4*64*64 per-wave P (wave-private, no barriers)

        bf16x8 qf[4][2];
        long qbase = (long)b * SEQ + blk * 256 + 64 * w;
        #pragma unroll
        for (int qq = 0; qq < 4; ++qq)
            #pragma unroll
            for (int ks = 0; ks < 2; ++ks)
                qf[qq][ks] = *(const bf16x8*)(QKVG + (size_t)(qbase + qq * 16 + l15) * QKVN
                                              + h * 64 + ks * 32 + l4 * 8);

        float dlp[4], drp[4];
        #pragma unroll
        for (int qq = 0; qq < 4; ++qq) {
            float dl = 0.f, dr = 0.f;
            #pragma unroll
            for (int ks = 0; ks < 2; ++ks) {
                const float* gp = glw + h * 64 + ks * 32 + l4 * 8;
                const float* rp = grw + h * 64 + ks * 32 + l4 * 8;
                #pragma unroll
                for (int j = 0; j < 8; ++j) {
                    float qv = (float)qf[qq][ks][j];
                    dl += qv * gp[j];
                    dr += qv * rp[j];
                }
            }
            dlp[qq] = dl; drp[qq] = dr;
        }
        float glv[4], grv[4];
        #pragma unroll
        for (int qq = 0; qq < 4; ++qq) {
            float dl = dlp[qq] + __shfl_xor(dlp[qq], 16);
            dl += __shfl_xor(dl, 32);
            float dr = drp[qq] + __shfl_xor(drp[qq], 16);
            dr += __shfl_xor(dr, 32);
            glv[qq] = 1.f / (1.f + __expf(-dl));
            grv[qq] = 1.f / (1.f + __expf(-dr));
        }
        if (l4 == 0) {
            #pragma unroll
            for (int qq = 0; qq < 4; ++qq)
                grbuf[(size_t)(qbase + qq * 16 + l15) * 16 + h] = grv[qq];
        }

        f32x4 acc[4][4];
        #pragma unroll
        for (int a2 = 0; a2 < 4; ++a2)
            #pragma unroll
            for (int d = 0; d < 4; ++d) acc[a2][d] = zero;
        float psum[4] = {0.f, 0.f, 0.f, 0.f};

        char* sPw = sPb + w * 4096;
        int nsteps = (w == 3) ? 10 : 11;
        int kk0 = 64 * w;
        long g0 = (long)b * SEQ + (long)(blk - 1) * WIN;
        const __bf16* vtb = Vt + (size_t)b * DMODEL * SEQ + (size_t)(h * 64) * SEQ;

        for (int stp = 0; stp < nsteps; ++stp) {
            int kk = kk0 + 32 * stp;
            f32x4 sacc[2][4];
            #pragma unroll
            for (int kt2 = 0; kt2 < 2; ++kt2) {
                int krow = kk + kt2 * 16 + l15;
                long kgrow = g0 + krow;
                if (blk == 0 && krow < 256) kgrow = (long)b * SEQ;  // clamp; masked anyway
                const __bf16* kp = QKVG + (size_t)kgrow * QKVN + KOFF + h * 64;
                bf16x8 af0 = *(const bf16x8*)(kp + l4 * 8);
                bf16x8 af1 = *(const bf16x8*)(kp + 32 + l4 * 8);
                #pragma unroll
                for (int qq = 0; qq < 4; ++qq) {
                    f32x4 s = __builtin_amdgcn_mfma_f32_16x16x32_bf16(af0, qf[qq][0], zero, 0, 0, 0);
                    sacc[kt2][qq] = __builtin_amdgcn_mfma_f32_16x16x32_bf16(af1, qf[qq][1], s, 0, 0, 0);
                }
            }
            #pragma unroll
            for (int qq = 0; qq < 4; ++qq) {
                int qloc = 64 * w + qq * 16 + l15;
                int prow = qq * 16 + l15;
                #pragma unroll
                for (int kt2 = 0; kt2 < 2; ++kt2) {
                    int jb = kk + kt2 * 16 + l4 * 4;
                    bf16x4 pb;
                    #pragma unroll
                    for (int r = 0; r < 4; ++r) {
                        int jw = jb + r;
                        bool act = (jw > qloc) && (jw <= qloc + 256) && (blk > 0 || jw >= 256);
                        float pv = act ? __expf(sacc[kt2][qq][r] * 0.125f) : 0.f;
                        psum[qq] += pv;
                        pb[r] = (__bf16)pv;
                    }
                    *(bf16x4*)(sPw + prow * 64 + ((kt2 * 32 + l4 * 8) ^ ((prow & 3) << 4))) = pb;
                }
            }
            int kglob = (blk - 1) * WIN + kk + l4 * 8;
            if (kglob < 0) kglob = 0;
            bf16x8 pa[4], bv[4];
            #pragma unroll
            for (int qq = 0; qq < 4; ++qq) {
                int prow = qq * 16 + l15;
                pa[qq] = *(const bf16x8*)(sPw + prow * 64 + ((l4 * 16) ^ ((prow & 3) << 4)));
            }
            #pragma unroll
            for (int dt = 0; dt < 4; ++dt)
                bv[dt] = *(const bf16x8*)(vtb + (size_t)(dt * 16 + l15) * SEQ + kglob);
            #pragma unroll
            for (int qq = 0; qq < 4; ++qq)
                #pragma unroll
                for (int dt = 0; dt < 4; ++dt)
                    acc[qq][dt] = __builtin_amdgcn_mfma_f32_16x16x32_bf16(pa[qq], bv[dt], acc[qq][dt], 0, 0, 0);
        }

        float cmb[4];
        #pragma unroll
        for (int qq = 0; qq < 4; ++qq) {
            float s = psum[qq] + __shfl_xor(psum[qq], 16);
            s += __shfl_xor(s, 32);
            cmb[qq] = glv[qq] / s;
        }
        #pragma unroll
        for (int qq = 0; qq < 4; ++qq) {
            #pragma unroll
            for (int r = 0; r < 4; ++r) {
                float sc = __shfl(cmb[qq], l4 * 4 + r, 64);
                size_t row = (size_t)(qbase + qq * 16 + l4 * 4 + r);
                __bf16* op = outl + row * DMODEL + h * 64 + l15;
                #pragma unroll
                for (int dt = 0; dt < 4; ++dt)
                    op[dt * 16] = (__bf16)(acc[qq][dt][r] * sc);
            }
        }
    } else {
        // ======== latent (remote) attention (verified r4-r10; GKV merged stride 1024) ========
        int sb = blockIdx.x, lh = blockIdx.y - 16;
        char* sK  = smem;              // 64*128
        char* sVt = smem + 8192;       // 64*128
        char* sPb = smem + 16384;      // 4*64*64

        bf16x8 qf[4][2];
        long qbase = (long)b * SEQ + sb * 256 + 64 * w;
        #pragma unroll
        for (int qq = 0; qq < 4; ++qq)
            #pragma unroll
            for (int ks = 0; ks < 2; ++ks)
                qf[qq][ks] = *(const bf16x8*)(QKVG + (size_t)(qbase + qq * 16 + l15) * QKVN
                                              + GQOFF + lh * 64 + ks * 32 + l4 * 8);

        #pragma unroll
        for (int rep = 0; rep < 2; ++rep) {
            int ci = rep * 256 + t;
            int row = ci >> 3, c8 = (ci & 7) * 8;
            u32x4 kv = *(const u32x4*)(GKV + (size_t)(b * 64 + row) * 1024 + lh * 64 + c8);
            *(u32x4*)(sK + row * 128 + ((c8 * 2) ^ ((row & 7) << 4))) = kv;
        }
        #pragma unroll
        for (int rep = 0; rep < 16; ++rep) {
            int idx = rep * 256 + t;
            int d = idx & 63, n = idx >> 6;
            __bf16 v = GKV[(size_t)(b * 64 + n) * 1024 + 512 + lh * 64 + d];
            *(__bf16*)(sVt + d * 128 + ((n * 2) ^ ((d & 7) << 4))) = v;
        }
        __syncthreads();

        f32x4 acc[4][4];
        #pragma unroll
        for (int a2 = 0; a2 < 4; ++a2)
            #pragma unroll
            for (int d = 0; d < 4; ++d) acc[a2][d] = zero;
        float psum[4] = {0.f, 0.f, 0.f, 0.f};

        char* sPw = sPb + w * 4096;
        int qloc0 = sb * 256 + 64 * w;

        #pragma unroll
        for (int stp = 0; stp < 2; ++stp) {
            int kk = 32 * stp;
            f32x4 sacc[2][4];
            #pragma unroll
            for (int kt2 = 0; kt2 < 2; ++kt2) {
                int krow = kk + kt2 * 16 + l15;
                int swz = (krow & 7) << 4;
                bf16x8 af0 = *(const bf16x8*)(sK + krow * 128 + ((l4 * 16) ^ swz));
                bf16x8 af1 = *(const bf16x8*)(sK + krow * 128 + ((64 + l4 * 16) ^ swz));
                #pragma unroll
                for (int qq = 0; qq < 4; ++qq) {
                    f32x4 s = __builtin_amdgcn_mfma_f32_16x16x32_bf16(af0, qf[qq][0], zero, 0, 0, 0);
                    sacc[kt2][qq] = __builtin_amdgcn_mfma_f32_16x16x32_bf16(af1, qf[qq][1], s, 0, 0, 0);
                }
            }
            #pragma unroll
            for (int qq = 0; qq < 4; ++qq) {
                int qdv = (qloc0 + qq * 16 + l15) >> 6;
                int prow = qq * 16 + l15;
                #pragma unroll
                for (int kt2 = 0; kt2 < 2; ++kt2) {
                    int nb = kk + kt2 * 16 + l4 * 4;
                    bf16x4 pb;
                    #pragma unroll
                    for (int r = 0; r < 4; ++r) {
                        int n = nb + r;
                        float pv = (n <= qdv) ? __expf(sacc[kt2][qq][r] * 0.125f) : 0.f;
                        psum[qq] += pv;
                        pb[r] = (__bf16)pv;
                    }
                    *(bf16x4*)(sPw + prow * 64 + ((kt2 * 32 + l4 * 8) ^ ((prow & 3) << 4))) = pb;
                }
            }
            bf16x8 pa[4], bv[4];
            #pragma unroll
            for (int qq = 0; qq < 4; ++qq) {
                int prow = qq * 16 + l15;
                pa[qq] = *(const bf16x8*)(sPw + prow * 64 + ((l4 * 16) ^ ((prow & 3) << 4)));
            }
            #pragma unroll
            for (int dt = 0; dt < 4; ++dt) {
                int d = dt * 16 + l15;
                bv[dt] = *(const bf16x8*)(sVt + d * 128 + ((kk * 2 + l4 * 16) ^ ((d & 7) << 4)));
            }
            #pragma unroll
            for (int qq = 0; qq < 4; ++qq)
                #pragma unroll
                for (int dt = 0; dt < 4; ++dt)
                    acc[qq][dt] = __builtin_amdgcn_mfma_f32_16x16x32_bf16(pa[qq], bv[dt], acc[qq][dt], 0, 0, 0);
        }

        float cmb[4];
        #pragma unroll
        for (int qq = 0; qq < 4; ++qq) {
            float s = psum[qq] + __shfl_xor(psum[qq], 16);
            s += __shfl_xor(s, 32);
            cmb[qq] = 1.f / s;
        }
        #pragma unroll
        for (int qq = 0; qq < 4; ++qq) {
            #pragma unroll
            for (int r = 0; r < 4; ++r) {
                float sc = __shfl(cmb[qq], l4 * 4 + r, 64);
                size_t row = (size_t)(qbase + qq * 16 + l4 * 4 + r);
                __bf16* op = rem + row * LDIM + lh * 64 + l15;
                #pragma unroll
                for (int dt = 0; dt < 4; ++dt)
                    op[dt * 16] = (__bf16)(acc[qq][dt][r] * sc);
            }
        }
    }
}

// ---------------- host launcher ----------------
extern "C" void kernel_launch(void* const* d_in, const int* in_sizes, int n_in,
                              void* d_out, int out_size, void* d_ws, size_t ws_size,
                              hipStream_t stream) {
    (void)in_sizes; (void)n_in; (void)out_size; (void)ws_size;
    const float* x    = (const float*)d_in[0];
    const float* wq   = (const float*)d_in[1];
    const float* wk   = (const float*)d_in[2];
    const float* wv   = (const float*)d_in[3];
    const float* wgq  = (const float*)d_in[4];
    const float* wgk  = (const float*)d_in[5];
    const float* wgv  = (const float*)d_in[6];
    const float* rout = (const float*)d_in[7];
    const float* glw  = (const float*)d_in[8];
    const float* grw  = (const float*)d_in[9];
    const float* wout = (const float*)d_in[10];

    char* p = (char*)d_ws;
    auto alloc = [&](size_t bytes) {
        char* r = p;
        p += (bytes + 255) & ~(size_t)255;
        return r;
    };
    __bf16* xb    = (__bf16*)alloc((size_t)BSROWS * DMODEL * 2);
    __bf16* QKVG  = (__bf16*)alloc((size_t)BSROWS * QKVN * 2);
    __bf16* VtG   = (__bf16*)alloc((size_t)BSROWS * DMODEL * 2);
    __bf16* wcatT = (__bf16*)alloc((size_t)QKVN * DMODEL * 2);
    __bf16* woutT = (__bf16*)alloc((size_t)DMODEL * DMODEL * 2);
    __bf16* wgkvT = (__bf16*)alloc((size_t)1024 * DMODEL * 2);   // [wgkT | wgvT]
    __bf16* routT = (__bf16*)alloc((size_t)DMODEL * LDIM * 2);
    __bf16* xpool = (__bf16*)alloc((size_t)256 * DMODEL * 2);    // padded to 256 rows
    __bf16* GKVb  = (__bf16*)alloc((size_t)256 * 1024 * 2);      // [GK | GV], 256-row tile
    __bf16* localg= (__bf16*)alloc((size_t)BSROWS * DMODEL * 2);
    float*  grbuf = (float*) alloc((size_t)BSROWS * 16 * 4);
    __bf16* remb  = (__bf16*)alloc((size_t)BSROWS * LDIM * 2);
    __bf16* outpre = xb; // alias: xb dead after fused projection

    TJ8 jobs;
    jobs.j[0] = {wq,   wcatT,                 DMODEL, DMODEL};
    jobs.j[1] = {wk,   wcatT + 1024 * DMODEL, DMODEL, DMODEL};
    jobs.j[2] = {wv,   wcatT + 2048 * DMODEL, DMODEL, DMODEL};
    jobs.j[3] = {wgq,  wcatT + 3072 * DMODEL, DMODEL, LDIM};
    jobs.j[4] = {wout, woutT,                 DMODEL, DMODEL};
    jobs.j[5] = {wgk,  wgkvT,                 DMODEL, LDIM};
    jobs.j[6] = {wgv,  wgkvT + 512 * DMODEL,  DMODEL, LDIM};
    jobs.j[7] = {rout, routT,                 LDIM,   DMODEL};

    // ONE prep dispatch: cvt+pool (512) + transposes (8192) + xpool pad-zero (32)
    prep_all<<<dim3(512 + 8192 + 32), 256, 0, stream>>>(x, xb, xpool, jobs);

    // fused [Q|K|V|GQ] projection + GKV side-row (y==14) via the 8-phase 256^2 GEMM;
    // V n-tiles land transposed in VtG (packed 8B stores)
    gemm256_bf16<<<dim3(32, 15), 512, 0, stream>>>(xb, wcatT, BSROWS, QKVN, DMODEL,
                                                   QKVG, VtG, xpool, wgkvT, GKVb);

    // single fused attention dispatch (local y=0..15, latent y=16..23)
    attn_fused<<<dim3(16, 24, 2), 256, 0, stream>>>(QKVG, VtG, GKVb, glw, grw,
                                                    localg, grbuf, remb);

    gemm_bf16<true, true><<<dim3(64, 8), 256, 0, stream>>>(remb, routT, BSROWS, DMODEL, LDIM, outpre, nullptr, localg, grbuf);
    gemm_bf16<false, false><<<dim3(64, 8), 256, 0, stream>>>(outpre, woutT, BSROWS, DMODEL, DMODEL, nullptr, (float*)d_out, nullptr, nullptr);
}

// Round 12
// 169.968 us; speedup vs baseline: 5.3691x; 1.0374x over previous
//
#include <hip/hip_runtime.h>

#define AS1 __attribute__((address_space(1)))
#define AS3 __attribute__((address_space(3)))

typedef float    f32x4  __attribute__((ext_vector_type(4)));
typedef __bf16   bf16x8 __attribute__((ext_vector_type(8)));
typedef __bf16   bf16x4 __attribute__((ext_vector_type(4)));
typedef unsigned int u32x4 __attribute__((ext_vector_type(4)));

static constexpr int SEQ = 4096, NBATCH = 2, DMODEL = 1024, NHEADS = 16, HDIM = 64;
static constexpr int LHEADS = 8, LDIM = 512, NLAT = 64, WIN = 256;
static constexpr int BSROWS = NBATCH * SEQ; // 8192
static constexpr int QKVN = 3584;           // fused [Q|K|V|GQ] column count
static constexpr int KOFF = 1024, VOFF = 2048, GQOFF = 3072;

// ---------------- ONE prep dispatch: cvt+pool + 8 weight transposes + xpool pad-zero ----------------
struct TJ { const float* in; __bf16* out; int K; int N; };
struct TJ8 { TJ j[8]; };
__global__ __launch_bounds__(256) void prep_all(const float* __restrict__ x,
                                                __bf16* __restrict__ xb,
                                                __bf16* __restrict__ xpool, TJ8 jobs) {
    __shared__ float tbuf[32][33];
    int bid = blockIdx.x, t = threadIdx.x;
    if (bid < 512) {
        int bn = bid >> 2;
        int c  = (bid & 3) * 256 + t;
        const float* p = x + (size_t)bn * 64 * 1024 + c;
        __bf16* q = xb + (size_t)bn * 64 * 1024 + c;
        float s = 0.f;
        #pragma unroll 8
        for (int j = 0; j < 64; ++j) {
            float v = p[(size_t)j * 1024];
            q[(size_t)j * 1024] = (__bf16)v;
            s += v;
        }
        xpool[(size_t)bn * 1024 + c] = (__bf16)(s * 0.015625f);
    } else if (bid < 8704) {
        int ti = bid - 512;
        TJ jb = jobs.j[ti >> 10];
        int rem = ti & 1023;
        int k0 = (rem >> 5) * 32, n0 = (rem & 31) * 32;
        if (k0 >= jb.K || n0 >= jb.N) return;
        int tx = t & 31, ty = t >> 5; // (32, 8)
        #pragma unroll
        for (int i = ty; i < 32; i += 8) tbuf[i][tx] = jb.in[(size_t)(k0 + i) * jb.N + n0 + tx];
        __syncthreads();
        #pragma unroll
        for (int i = ty; i < 32; i += 8) jb.out[(size_t)(n0 + i) * jb.K + k0 + tx] = (__bf16)tbuf[tx][i];
    } else {
        int zi = bid - 8704;                 // 0..31
        size_t idx = ((size_t)zi * 256 + t) * 16;
        u32x4 z = {0u, 0u, 0u, 0u};
        *(u32x4*)(xpool + 128 * 1024 + idx)     = z;
        *(u32x4*)(xpool + 128 * 1024 + idx + 8) = z;
    }
}

// ---------------- 256x256 8-phase GEMM (T2+T3+T4+T5) + GKV side-row ----------------
// (verified r7-r11; conflict-free swizzle byte^=(row&7)<<4; fused V-transpose epilogue)
#define BAR() do { __builtin_amdgcn_sched_barrier(0); __builtin_amdgcn_s_barrier(); \
                   __builtin_amdgcn_sched_barrier(0); } while (0)
#define LGK0() do { asm volatile("s_waitcnt lgkmcnt(0)" ::: "memory"); \
                    __builtin_amdgcn_sched_barrier(0); } while (0)
#define VMC(n) do { asm volatile("s_waitcnt vmcnt(" #n ")" ::: "memory"); \
                    __builtin_amdgcn_sched_barrier(0); } while (0)
#define STG(gp, regionbase, rowbase, ktc) do { \
    int row_ = (rowbase) + (t >> 3); \
    int tc_ = (t & 7) ^ ((t >> 3) & 7); \
    __builtin_amdgcn_global_load_lds( \
        (const AS1 void*)((gp) + (size_t)row_ * K + (ktc) + tc_ * 8), \
        (AS3 void*)(lds + (regionbase) + (rowbase) * 128 + w * 1024), 16, 0, 0); \
} while (0)
#define LOADA(buf, qm) do { \
    _Pragma("unroll") for (int ai_ = 0; ai_ < 4; ++ai_) \
    _Pragma("unroll") for (int ks_ = 0; ks_ < 2; ++ks_) \
        a[ai_][ks_] = *(const bf16x8*)(lds + ((((buf) * 65536) + \
            (wm * 128 + (qm) * 64 + ai_ * 16 + l15) * 128 + ks_ * 64 + l4 * 16) ^ rswz)); \
} while (0)
#define LOADB2(buf, half) do { \
    _Pragma("unroll") for (int j_ = 0; j_ < 2; ++j_) \
    _Pragma("unroll") for (int ks_ = 0; ks_ < 2; ++ks_) \
        b2[j_][ks_] = *(const bf16x8*)(lds + ((((buf) * 65536 + 32768) + \
            (wn * 64 + ((half) * 2 + j_) * 16 + l15) * 128 + ks_ * 64 + l4 * 16) ^ rswz)); \
} while (0)
#define MFMA_PH(qm, half) do { \
    __builtin_amdgcn_s_setprio(1); \
    _Pragma("unroll") for (int ai_ = 0; ai_ < 4; ++ai_) \
    _Pragma("unroll") for (int j_ = 0; j_ < 2; ++j_) { \
        f32x4 c_ = acc[(qm) * 4 + ai_][(half) * 2 + j_]; \
        c_ = __builtin_amdgcn_mfma_f32_16x16x32_bf16(a[ai_][0], b2[j_][0], c_, 0, 0, 0); \
        c_ = __builtin_amdgcn_mfma_f32_16x16x32_bf16(a[ai_][1], b2[j_][1], c_, 0, 0, 0); \
        acc[(qm) * 4 + ai_][(half) * 2 + j_] = c_; \
    } \
    __builtin_amdgcn_s_setprio(0); \
} while (0)

__global__ __launch_bounds__(512, 2) void gemm256_bf16(
    const __bf16* __restrict__ A, const __bf16* __restrict__ Bt,
    int M, int N, int K, __bf16* __restrict__ outb, __bf16* __restrict__ Vt,
    const __bf16* __restrict__ A2, const __bf16* __restrict__ B2,
    __bf16* __restrict__ out2) {
    __shared__ char lds[131072];
    const int t = threadIdx.x, w = t >> 6, l = t & 63;
    const int wm = w >> 2, wn = w & 3;
    const int l15 = l & 15, l4 = l >> 4;
    const int NT = K >> 6;
    const int rswz = (l15 & 7) << 4;

    const __bf16* Ab; const __bf16* Bb; __bf16* outp; int Nout, m0, n0; bool doVt;
    if (blockIdx.y == 14) {
        if (blockIdx.x >= 4) return;      // whole block exits; no barrier hazard
        m0 = 0; n0 = blockIdx.x * 256;
        Ab = A2; Bb = B2 + (size_t)n0 * K;
        outp = out2; Nout = 1024; doVt = false;
    } else {
        m0 = blockIdx.x * 256; n0 = blockIdx.y * 256;
        Ab = A + (size_t)m0 * K; Bb = Bt + (size_t)n0 * K;
        outp = outb; Nout = N; doVt = (n0 >= VOFF && n0 < GQOFF);
    }

    f32x4 acc[8][4];
    #pragma unroll
    for (int i = 0; i < 8; ++i)
        #pragma unroll
        for (int j = 0; j < 4; ++j) acc[i][j] = (f32x4){0.f, 0.f, 0.f, 0.f};
    bf16x8 a[4][2], b2[2][2];

    STG(Ab, 0, 0, 0);        STG(Ab, 0, 128, 0);
    STG(Ab, 0, 64, 0);       STG(Ab, 0, 192, 0);
    STG(Bb, 32768, 0, 0);    STG(Bb, 32768, 64, 0);
    STG(Bb, 32768, 128, 0);  STG(Bb, 32768, 192, 0);
    STG(Ab, 65536, 0, 64);   STG(Ab, 65536, 128, 64);
    VMC(2); BAR();

    int it = 0;
    for (; it + 3 < NT; it += 2) {
        const int kt1 = (it + 1) << 6, kt2 = (it + 2) << 6, kt3 = (it + 3) << 6;
        LOADA(0, 0); LOADB2(0, 0);
        STG(Ab, 65536, 64, kt1); STG(Ab, 65536, 192, kt1);
        BAR(); LGK0(); MFMA_PH(0, 0); BAR();
        LOADB2(0, 1);
        STG(Bb, 98304, 0, kt1); STG(Bb, 98304, 64, kt1);
        BAR(); LGK0(); MFMA_PH(0, 1); BAR();
        LOADA(0, 1); LOADB2(0, 0);
        STG(Bb, 98304, 128, kt1); STG(Bb, 98304, 192, kt1);
        BAR(); LGK0(); MFMA_PH(1, 0); BAR();
        LOADB2(0, 1);
        STG(Ab, 0, 0, kt2); STG(Ab, 0, 128, kt2);
        BAR(); LGK0(); MFMA_PH(1, 1); VMC(2); BAR();
        LOADA(1, 0); LOADB2(1, 0);
        STG(Ab, 0, 64, kt2); STG(Ab, 0, 192, kt2);
        BAR(); LGK0(); MFMA_PH(0, 0); BAR();
        LOADB2(1, 1);
        STG(Bb, 32768, 0, kt2); STG(Bb, 32768, 64, kt2);
        BAR(); LGK0(); MFMA_PH(0, 1); BAR();
        LOADA(1, 1); LOADB2(1, 0);
        STG(Bb, 32768, 128, kt2); STG(Bb, 32768, 192, kt2);
        BAR(); LGK0(); MFMA_PH(1, 0); BAR();
        LOADB2(1, 1);
        STG(Ab, 65536, 0, kt3); STG(Ab, 65536, 128, kt3);
        BAR(); LGK0(); MFMA_PH(1, 1); VMC(2); BAR();
    }
    {
        const int kt1 = (it + 1) << 6;
        LOADA(0, 0); LOADB2(0, 0);
        STG(Ab, 65536, 64, kt1); STG(Ab, 65536, 192, kt1);
        BAR(); LGK0(); MFMA_PH(0, 0); BAR();
        LOADB2(0, 1);
        STG(Bb, 98304, 0, kt1); STG(Bb, 98304, 64, kt1);
        BAR(); LGK0(); MFMA_PH(0, 1); BAR();
        LOADA(0, 1); LOADB2(0, 0);
        STG(Bb, 98304, 128, kt1); STG(Bb, 98304, 192, kt1);
        BAR(); LGK0(); MFMA_PH(1, 0); BAR();
        LOADB2(0, 1);
        BAR(); LGK0(); MFMA_PH(1, 1); VMC(0); BAR();
        LOADA(1, 0); LOADB2(1, 0);
        BAR(); LGK0(); MFMA_PH(0, 0); BAR();
        LOADB2(1, 1);
        BAR(); LGK0(); MFMA_PH(0, 1); BAR();
        LOADA(1, 1); LOADB2(1, 0);
        BAR(); LGK0(); MFMA_PH(1, 0); BAR();
        LOADB2(1, 1);
        LGK0(); MFMA_PH(1, 1);
    }

    int cr = l4 * 4, cc = l15;
    if (doVt) {
        #pragma unroll
        for (int mi = 0; mi < 8; ++mi) {
            #pragma unroll
            for (int ni = 0; ni < 4; ++ni) {
                int vcol = (n0 - VOFF) + wn * 64 + ni * 16 + cc;
                int row0 = m0 + wm * 128 + mi * 16 + cr;
                int bb = row0 >> 12, ss = row0 & 4095;
                bf16x4 pk;
                #pragma unroll
                for (int r = 0; r < 4; ++r) pk[r] = (__bf16)acc[mi][ni][r];
                *(bf16x4*)(Vt + ((size_t)bb * DMODEL + vcol) * SEQ + ss) = pk;
            }
        }
    } else {
        #pragma unroll
        for (int mi = 0; mi < 8; ++mi) {
            #pragma unroll
            for (int ni = 0; ni < 4; ++ni) {
                int col = n0 + wn * 64 + ni * 16 + cc;
                #pragma unroll
                for (int r = 0; r < 4; ++r) {
                    int row = m0 + wm * 128 + mi * 16 + cr + r;
                    outp[(size_t)row * Nout + col] = (__bf16)acc[mi][ni][r];
                }
            }
        }
    }
}
#undef LOADA
#undef LOADB2
#undef MFMA_PH

// ---------------- 128x256-tile 4-phase/K-tile pipelined GEMM (tail-free for N=1024) ----------------
// 512 threads = 8 waves (wm2=w>>2 A-half, wn=w&3 B-quarter); per-wave out 64x64; BK=64.
// 3-buffer LDS rotation (48KB/buf: A 16KB + B 32KB; 144KB total, 1 block/CU): during tile t,
// stage tile t+2 into buf (t+2)%3 (== buf of tile t-1, freed at its last barrier). Counted
// vmcnt(6) at each P4 (T4: 6 loads stay in flight). Same verified swizzle/STG/fragments.
#define LOADA3(base, qm) do { \
    _Pragma("unroll") for (int ai_ = 0; ai_ < 2; ++ai_) \
    _Pragma("unroll") for (int ks_ = 0; ks_ < 2; ++ks_) \
        a[ai_][ks_] = *(const bf16x8*)(lds + (((base) + \
            (wm2 * 64 + (qm) * 32 + ai_ * 16 + l15) * 128 + ks_ * 64 + l4 * 16) ^ rswz)); \
} while (0)
#define LOADB3(base, nh) do { \
    _Pragma("unroll") for (int j_ = 0; j_ < 2; ++j_) \
    _Pragma("unroll") for (int ks_ = 0; ks_ < 2; ++ks_) \
        b2[j_][ks_] = *(const bf16x8*)(lds + (((base) + 16384 + \
            (wn * 64 + (nh) * 32 + j_ * 16 + l15) * 128 + ks_ * 64 + l4 * 16) ^ rswz)); \
} while (0)
#define MFMA_P3(qm, nh) do { \
    __builtin_amdgcn_s_setprio(1); \
    _Pragma("unroll") for (int ai_ = 0; ai_ < 2; ++ai_) \
    _Pragma("unroll") for (int j_ = 0; j_ < 2; ++j_) { \
        f32x4 c_ = acc[(qm) * 2 + ai_][(nh) * 2 + j_]; \
        c_ = __builtin_amdgcn_mfma_f32_16x16x32_bf16(a[ai_][0], b2[j_][0], c_, 0, 0, 0); \
        c_ = __builtin_amdgcn_mfma_f32_16x16x32_bf16(a[ai_][1], b2[j_][1], c_, 0, 0, 0); \
        acc[(qm) * 2 + ai_][(nh) * 2 + j_] = c_; \
    } \
    __builtin_amdgcn_s_setprio(0); \
} while (0)

template <bool EPI, bool OUTBF>
__global__ __launch_bounds__(512, 1) void gemm128n(
    const __bf16* __restrict__ A, const __bf16* __restrict__ Bt,
    int M, int N, int K,
    __bf16* __restrict__ outb, float* __restrict__ outf,
    const __bf16* __restrict__ lcl, const float* __restrict__ grb) {
    __shared__ char lds[147456];    // 3 x (16KB A + 32KB B)
    const int t = threadIdx.x, w = t >> 6, l = t & 63;
    const int wm2 = w >> 2, wn = w & 3;
    const int l15 = l & 15, l4 = l >> 4;
    const int m0 = blockIdx.x * 128, n0 = blockIdx.y * 256;
    const int NT = K >> 6;
    const int rswz = (l15 & 7) << 4;

    f32x4 acc[4][4];
    #pragma unroll
    for (int i = 0; i < 4; ++i)
        #pragma unroll
        for (int j = 0; j < 4; ++j) acc[i][j] = (f32x4){0.f, 0.f, 0.f, 0.f};
    bf16x8 a[2][2], b2[2][2];

    const __bf16* Ab = A + (size_t)m0 * K;
    const __bf16* Bb = Bt + (size_t)n0 * K;

    // prologue: stage tile0 -> buf0, tile1 -> buf1 (6 loads each); wait tile0 (vmcnt 6)
    STG(Ab, 0, 0, 0);      STG(Ab, 0, 64, 0);
    STG(Bb, 16384, 0, 0);  STG(Bb, 16384, 64, 0);
    STG(Bb, 16384, 128, 0); STG(Bb, 16384, 192, 0);
    STG(Ab, 49152, 0, 64);      STG(Ab, 49152, 64, 64);
    STG(Bb, 65536, 0, 64);  STG(Bb, 65536, 64, 64);
    STG(Bb, 65536, 128, 64); STG(Bb, 65536, 192, 64);
    VMC(6); BAR();

    int cb = 0, nb = 98304;   // current buf base; stage-target buf base ((it+2)%3)
    for (int it = 0; it + 2 < NT; ++it) {
        const int kt2 = (it + 2) << 6;
        // P1
        LOADA3(cb, 0); LOADB3(cb, 0);
        STG(Ab, nb, 0, kt2); STG(Ab, nb, 64, kt2);
        BAR(); LGK0(); MFMA_P3(0, 0); BAR();
        // P2
        LOADB3(cb, 1);
        STG(Bb, nb + 16384, 0, kt2); STG(Bb, nb + 16384, 64, kt2);
        BAR(); LGK0(); MFMA_P3(0, 1); BAR();
        // P3
        LOADA3(cb, 1); LOADB3(cb, 0);
        STG(Bb, nb + 16384, 128, kt2); STG(Bb, nb + 16384, 192, kt2);
        BAR(); LGK0(); MFMA_P3(1, 0); BAR();
        // P4
        LOADB3(cb, 1);
        BAR(); LGK0(); MFMA_P3(1, 1); VMC(6); BAR();
        cb = (cb == 98304) ? 0 : cb + 49152;
        nb = (nb == 98304) ? 0 : nb + 49152;
    }
    // tail tile NT-2: no stages; drain at P4
    {
        LOADA3(cb, 0); LOADB3(cb, 0);
        BAR(); LGK0(); MFMA_P3(0, 0); BAR();
        LOADB3(cb, 1);
        BAR(); LGK0(); MFMA_P3(0, 1); BAR();
        LOADA3(cb, 1); LOADB3(cb, 0);
        BAR(); LGK0(); MFMA_P3(1, 0); BAR();
        LOADB3(cb, 1);
        BAR(); LGK0(); MFMA_P3(1, 1); VMC(0); BAR();
        cb = (cb == 98304) ? 0 : cb + 49152;
    }
    // tail tile NT-1
    {
        LOADA3(cb, 0); LOADB3(cb, 0);
        BAR(); LGK0(); MFMA_P3(0, 0); BAR();
        LOADB3(cb, 1);
        BAR(); LGK0(); MFMA_P3(0, 1); BAR();
        LOADA3(cb, 1); LOADB3(cb, 0);
        BAR(); LGK0(); MFMA_P3(1, 0); BAR();
        LOADB3(cb, 1);
        LGK0(); MFMA_P3(1, 1);
    }

    // epilogue (verified C/D mapping + EPI combine)
    int cr = l4 * 4, cc = l15;
    #pragma unroll
    for (int mi = 0; mi < 4; ++mi) {
        #pragma unroll
        for (int ni = 0; ni < 4; ++ni) {
            int col = n0 + wn * 64 + ni * 16 + cc;
            #pragma unroll
            for (int r = 0; r < 4; ++r) {
                int row = m0 + wm2 * 64 + mi * 16 + cr + r;
                float v = acc[mi][ni][r];
                if constexpr (EPI) {
                    v = (float)lcl[(size_t)row * 1024 + col] +
                        grb[(size_t)row * 16 + (col >> 6)] * v;
                }
                if constexpr (OUTBF) outb[(size_t)row * N + col] = (__bf16)v;
                else                 outf[(size_t)row * N + col] = v;
            }
        }
    }
}
#undef BAR
#undef LGK0
#undef VMC
#undef STG
#undef LOADA3
#undef LOADB3
#undef MFMA_P3

// ---------------- fused attention: ONE dispatch for local + latent (verified r11) ----------------
__global__ __launch_bounds__(256, 2) void attn_fused(
    const __bf16* __restrict__ QKVG, const __bf16* __restrict__ Vt,
    const __bf16* __restrict__ GKV,
    const float* __restrict__ glw, const float* __restrict__ grw,
    __bf16* __restrict__ outl, float* __restrict__ grbuf,
    __bf16* __restrict__ rem) {
    __shared__ alignas(16) char smem[32768];
    int t = threadIdx.x, w = t >> 6, l = t & 63;
    int l15 = l & 15, l4 = l >> 4;
    int b = blockIdx.z;
    f32x4 zero = {0.f, 0.f, 0.f, 0.f};

    if (blockIdx.y < 16) {
        // ======== local sliding-window attention (K-direct + V-direct) ========
        int blk = blockIdx.x, h = blockIdx.y;
        char* sPb = smem;

        bf16x8 qf[4][2];
        long qbase = (long)b * SEQ + blk * 256 + 64 * w;
        #pragma unroll
        for (int qq = 0; qq < 4; ++qq)
            #pragma unroll
            for (int ks = 0; ks < 2; ++ks)
                qf[qq][ks] = *(const bf16x8*)(QKVG + (size_t)(qbase + qq * 16 + l15) * QKVN
                                              + h * 64 + ks * 32 + l4 * 8);

        float dlp[4], drp[4];
        #pragma unroll
        for (int qq = 0; qq < 4; ++qq) {
            float dl = 0.f, dr = 0.f;
            #pragma unroll
            for (int ks = 0; ks < 2; ++ks) {
                const float* gp = glw + h * 64 + ks * 32 + l4 * 8;
                const float* rp = grw + h * 64 + ks * 32 + l4 * 8;
                #pragma unroll
                for (int j = 0; j < 8; ++j) {
                    float qv = (float)qf[qq][ks][j];
                    dl += qv * gp[j];
                    dr += qv * rp[j];
                }
            }
            dlp[qq] = dl; drp[qq] = dr;
        }
        float glv[4], grv[4];
        #pragma unroll
        for (int qq = 0; qq < 4; ++qq) {
            float dl = dlp[qq] + __shfl_xor(dlp[qq], 16);
            dl += __shfl_xor(dl, 32);
            float dr = drp[qq] + __shfl_xor(drp[qq], 16);
            dr += __shfl_xor(dr, 32);
            glv[qq] = 1.f / (1.f + __expf(-dl));
            grv[qq] = 1.f / (1.f + __expf(-dr));
        }
        if (l4 == 0) {
            #pragma unroll
            for (int qq = 0; qq < 4; ++qq)
                grbuf[(size_t)(qbase + qq * 16 + l15) * 16 + h] = grv[qq];
        }

        f32x4 acc[4][4];
        #pragma unroll
        for (int a2 = 0; a2 < 4; ++a2)
            #pragma unroll
            for (int d = 0; d < 4; ++d) acc[a2][d] = zero;
        float psum[4] = {0.f, 0.f, 0.f, 0.f};

        char* sPw = sPb + w * 4096;
        int nsteps = (w == 3) ? 10 : 11;
        int kk0 = 64 * w;
        long g0 = (long)b * SEQ + (long)(blk - 1) * WIN;
        const __bf16* vtb = Vt + (size_t)b * DMODEL * SEQ + (size_t)(h * 64) * SEQ;

        for (int stp = 0; stp < nsteps; ++stp) {
            int kk = kk0 + 32 * stp;
            f32x4 sacc[2][4];
            #pragma unroll
            for (int kt2 = 0; kt2 < 2; ++kt2) {
                int krow = kk + kt2 * 16 + l15;
                long kgrow = g0 + krow;
                if (blk == 0 && krow < 256) kgrow = (long)b * SEQ;  // clamp; masked anyway
                const __bf16* kp = QKVG + (size_t)kgrow * QKVN + KOFF + h * 64;
                bf16x8 af0 = *(const bf16x8*)(kp + l4 * 8);
                bf16x8 af1 = *(const bf16x8*)(kp + 32 + l4 * 8);
                #pragma unroll
                for (int qq = 0; qq < 4; ++qq) {
                    f32x4 s = __builtin_amdgcn_mfma_f32_16x16x32_bf16(af0, qf[qq][0], zero, 0, 0, 0);
                    sacc[kt2][qq] = __builtin_amdgcn_mfma_f32_16x16x32_bf16(af1, qf[qq][1], s, 0, 0, 0);
                }
            }
            #pragma unroll
            for (int qq = 0; qq < 4; ++qq) {
                int qloc = 64 * w + qq * 16 + l15;
                int prow = qq * 16 + l15;
                #pragma unroll
                for (int kt2 = 0; kt2 < 2; ++kt2) {
                    int jb = kk + kt2 * 16 + l4 * 4;
                    bf16x4 pb;
                    #pragma unroll
                    for (int r = 0; r < 4; ++r) {
                        int jw = jb + r;
                        bool act = (jw > qloc) && (jw <= qloc + 256) && (blk > 0 || jw >= 256);
                        float pv = act ? __expf(sacc[kt2][qq][r] * 0.125f) : 0.f;
                        psum[qq] += pv;
                        pb[r] = (__bf16)pv;
                    }
                    *(bf16x4*)(sPw + prow * 64 + ((kt2 * 32 + l4 * 8) ^ ((prow & 3) << 4))) = pb;
                }
            }
            int kglob = (blk - 1) * WIN + kk + l4 * 8;
            if (kglob < 0) kglob = 0;
            bf16x8 pa[4], bv[4];
            #pragma unroll
            for (int qq = 0; qq < 4; ++qq) {
                int prow = qq * 16 + l15;
                pa[qq] = *(const bf16x8*)(sPw + prow * 64 + ((l4 * 16) ^ ((prow & 3) << 4)));
            }
            #pragma unroll
            for (int dt = 0; dt < 4; ++dt)
                bv[dt] = *(const bf16x8*)(vtb + (size_t)(dt * 16 + l15) * SEQ + kglob);
            #pragma unroll
            for (int qq = 0; qq < 4; ++qq)
                #pragma unroll
                for (int dt = 0; dt < 4; ++dt)
                    acc[qq][dt] = __builtin_amdgcn_mfma_f32_16x16x32_bf16(pa[qq], bv[dt], acc[qq][dt], 0, 0, 0);
        }

        float cmb[4];
        #pragma unroll
        for (int qq = 0; qq < 4; ++qq) {
            float s = psum[qq] + __shfl_xor(psum[qq], 16);
            s += __shfl_xor(s, 32);
            cmb[qq] = glv[qq] / s;
        }
        #pragma unroll
        for (int qq = 0; qq < 4; ++qq) {
            #pragma unroll
            for (int r = 0; r < 4; ++r) {
                float sc = __shfl(cmb[qq], l4 * 4 + r, 64);
                size_t row = (size_t)(qbase + qq * 16 + l4 * 4 + r);
                __bf16* op = outl + row * DMODEL + h * 64 + l15;
                #pragma unroll
                for (int dt = 0; dt < 4; ++dt)
                    op[dt * 16] = (__bf16)(acc[qq][dt][r] * sc);
            }
        }
    } else {
        // ======== latent (remote) attention (verified r4-r11; GKV merged stride 1024) ========
        int sb = blockIdx.x, lh = blockIdx.y - 16;
        char* sK  = smem;
        char* sVt = smem + 8192;
        char* sPb = smem + 16384;

        bf16x8 qf[4][2];
        long qbase = (long)b * SEQ + sb * 256 + 64 * w;
        #pragma unroll
        for (int qq = 0; qq < 4; ++qq)
            #pragma unroll
            for (int ks = 0; ks < 2; ++ks)
                qf[qq][ks] = *(const bf16x8*)(QKVG + (size_t)(qbase + qq * 16 + l15) * QKVN
                                              + GQOFF + lh * 64 + ks * 32 + l4 * 8);

        #pragma unroll
        for (int rep = 0; rep < 2; ++rep) {
            int ci = rep * 256 + t;
            int row = ci >> 3, c8 = (ci & 7) * 8;
            u32x4 kv = *(const u32x4*)(GKV + (size_t)(b * 64 + row) * 1024 + lh * 64 + c8);
            *(u32x4*)(sK + row * 128 + ((c8 * 2) ^ ((row & 7) << 4))) = kv;
        }
        #pragma unroll
        for (int rep = 0; rep < 16; ++rep) {
            int idx = rep * 256 + t;
            int d = idx & 63, n = idx >> 6;
            __bf16 v = GKV[(size_t)(b * 64 + n) * 1024 + 512 + lh * 64 + d];
            *(__bf16*)(sVt + d * 128 + ((n * 2) ^ ((d & 7) << 4))) = v;
        }
        __syncthreads();

        f32x4 acc[4][4];
        #pragma unroll
        for (int a2 = 0; a2 < 4; ++a2)
            #pragma unroll
            for (int d = 0; d < 4; ++d) acc[a2][d] = zero;
        float psum[4] = {0.f, 0.f, 0.f, 0.f};

        char* sPw = sPb + w * 4096;
        int qloc0 = sb * 256 + 64 * w;

        #pragma unroll
        for (int stp = 0; stp < 2; ++stp) {
            int kk = 32 * stp;
            f32x4 sacc[2][4];
            #pragma unroll
            for (int kt2 = 0; kt2 < 2; ++kt2) {
                int krow = kk + kt2 * 16 + l15;
                int swz = (krow & 7) << 4;
                bf16x8 af0 = *(const bf16x8*)(sK + krow * 128 + ((l4 * 16) ^ swz));
                bf16x8 af1 = *(const bf16x8*)(sK + krow * 128 + ((64 + l4 * 16) ^ swz));
                #pragma unroll
                for (int qq = 0; qq < 4; ++qq) {
                    f32x4 s = __builtin_amdgcn_mfma_f32_16x16x32_bf16(af0, qf[qq][0], zero, 0, 0, 0);
                    sacc[kt2][qq] = __builtin_amdgcn_mfma_f32_16x16x32_bf16(af1, qf[qq][1], s, 0, 0, 0);
                }
            }
            #pragma unroll
            for (int qq = 0; qq < 4; ++qq) {
                int qdv = (qloc0 + qq * 16 + l15) >> 6;
                int prow = qq * 16 + l15;
                #pragma unroll
                for (int kt2 = 0; kt2 < 2; ++kt2) {
                    int nb = kk + kt2 * 16 + l4 * 4;
                    bf16x4 pb;
                    #pragma unroll
                    for (int r = 0; r < 4; ++r) {
                        int n = nb + r;
                        float pv = (n <= qdv) ? __expf(sacc[kt2][qq][r] * 0.125f) : 0.f;
                        psum[qq] += pv;
                        pb[r] = (__bf16)pv;
                    }
                    *(bf16x4*)(sPw + prow * 64 + ((kt2 * 32 + l4 * 8) ^ ((prow & 3) << 4))) = pb;
                }
            }
            bf16x8 pa[4], bv[4];
            #pragma unroll
            for (int qq = 0; qq < 4; ++qq) {
                int prow = qq * 16 + l15;
                pa[qq] = *(const bf16x8*)(sPw + prow * 64 + ((l4 * 16) ^ ((prow & 3) << 4)));
            }
            #pragma unroll
            for (int dt = 0; dt < 4; ++dt) {
                int d = dt * 16 + l15;
                bv[dt] = *(const bf16x8*)(sVt + d * 128 + ((kk * 2 + l4 * 16) ^ ((d & 7) << 4)));
            }
            #pragma unroll
            for (int qq = 0; qq < 4; ++qq)
                #pragma unroll
                for (int dt = 0; dt < 4; ++dt)
                    acc[qq][dt] = __builtin_amdgcn_mfma_f32_16x16x32_bf16(pa[qq], bv[dt], acc[qq][dt], 0, 0, 0);
        }

        float cmb[4];
        #pragma unroll
        for (int qq = 0; qq < 4; ++qq) {
            float s = psum[qq] + __shfl_xor(psum[qq], 16);
            s += __shfl_xor(s, 32);
            cmb[qq] = 1.f / s;
        }
        #pragma unroll
        for (int qq = 0; qq < 4; ++qq) {
            #pragma unroll
            for (int r = 0; r < 4; ++r) {
                float sc = __shfl(cmb[qq], l4 * 4 + r, 64);
                size_t row = (size_t)(qbase + qq * 16 + l4 * 4 + r);
                __bf16* op = rem + row * LDIM + lh * 64 + l15;
                #pragma unroll
                for (int dt = 0; dt < 4; ++dt)
                    op[dt * 16] = (__bf16)(acc[qq][dt][r] * sc);
            }
        }
    }
}

// ---------------- host launcher ----------------
extern "C" void kernel_launch(void* const* d_in, const int* in_sizes, int n_in,
                              void* d_out, int out_size, void* d_ws, size_t ws_size,
                              hipStream_t stream) {
    (void)in_sizes; (void)n_in; (void)out_size; (void)ws_size;
    const float* x    = (const float*)d_in[0];
    const float* wq   = (const float*)d_in[1];
    const float* wk   = (const float*)d_in[2];
    const float* wv   = (const float*)d_in[3];
    const float* wgq  = (const float*)d_in[4];
    const float* wgk  = (const float*)d_in[5];
    const float* wgv  = (const float*)d_in[6];
    const float* rout = (const float*)d_in[7];
    const float* glw  = (const float*)d_in[8];
    const float* grw  = (const float*)d_in[9];
    const float* wout = (const float*)d_in[10];

    char* p = (char*)d_ws;
    auto alloc = [&](size_t bytes) {
        char* r = p;
        p += (bytes + 255) & ~(size_t)255;
        return r;
    };
    __bf16* xb    = (__bf16*)alloc((size_t)BSROWS * DMODEL * 2);
    __bf16* QKVG  = (__bf16*)alloc((size_t)BSROWS * QKVN * 2);
    __bf16* VtG   = (__bf16*)alloc((size_t)BSROWS * DMODEL * 2);
    __bf16* wcatT = (__bf16*)alloc((size_t)QKVN * DMODEL * 2);
    __bf16* woutT = (__bf16*)alloc((size_t)DMODEL * DMODEL * 2);
    __bf16* wgkvT = (__bf16*)alloc((size_t)1024 * DMODEL * 2);   // [wgkT | wgvT]
    __bf16* routT = (__bf16*)alloc((size_t)DMODEL * LDIM * 2);
    __bf16* xpool = (__bf16*)alloc((size_t)256 * DMODEL * 2);    // padded to 256 rows
    __bf16* GKVb  = (__bf16*)alloc((size_t)256 * 1024 * 2);      // [GK | GV], 256-row tile
    __bf16* localg= (__bf16*)alloc((size_t)BSROWS * DMODEL * 2);
    float*  grbuf = (float*) alloc((size_t)BSROWS * 16 * 4);
    __bf16* remb  = (__bf16*)alloc((size_t)BSROWS * LDIM * 2);
    __bf16* outpre = xb; // alias: xb dead after fused projection

    TJ8 jobs;
    jobs.j[0] = {wq,   wcatT,                 DMODEL, DMODEL};
    jobs.j[1] = {wk,   wcatT + 1024 * DMODEL, DMODEL, DMODEL};
    jobs.j[2] = {wv,   wcatT + 2048 * DMODEL, DMODEL, DMODEL};
    jobs.j[3] = {wgq,  wcatT + 3072 * DMODEL, DMODEL, LDIM};
    jobs.j[4] = {wout, woutT,                 DMODEL, DMODEL};
    jobs.j[5] = {wgk,  wgkvT,                 DMODEL, LDIM};
    jobs.j[6] = {wgv,  wgkvT + 512 * DMODEL,  DMODEL, LDIM};
    jobs.j[7] = {rout, routT,                 LDIM,   DMODEL};

    // ONE prep dispatch: cvt+pool (512) + transposes (8192) + xpool pad-zero (32)
    prep_all<<<dim3(512 + 8192 + 32), 256, 0, stream>>>(x, xb, xpool, jobs);

    // fused [Q|K|V|GQ] projection + GKV side-row (y==14) via the 8-phase 256^2 GEMM;
    // V n-tiles land transposed in VtG (packed 8B stores)
    gemm256_bf16<<<dim3(32, 15), 512, 0, stream>>>(xb, wcatT, BSROWS, QKVN, DMODEL,
                                                   QKVG, VtG, xpool, wgkvT, GKVb);

    // single fused attention dispatch (local y=0..15, latent y=16..23)
    attn_fused<<<dim3(16, 24, 2), 256, 0, stream>>>(QKVG, VtG, GKVb, glw, grw,
                                                    localg, grbuf, remb);

    // trailing GEMMs on the tail-free 128x256 pipelined template (256 blocks each)
    gemm128n<true, true><<<dim3(64, 4), 512, 0, stream>>>(remb, routT, BSROWS, DMODEL, LDIM, outpre, nullptr, localg, grbuf);
    gemm128n<false, false><<<dim3(64, 4), 512, 0, stream>>>(outpre, woutT, BSROWS, DMODEL, DMODEL, nullptr, (float*)d_out, nullptr, nullptr);
}